// Round 20
// baseline (1333.605 us; speedup 1.0000x reference)
//
#include <hip/hip_runtime.h>

#define NN 50000      // nodes
#define NE 625000     // edges
#define DD 128        // hidden dim
#define HH 8          // heads
#define DHH 16        // head dim
#define NL 4          // layers
#define FIN 64        // in channels
#define NG 64         // graphs
#define LN_EPS 1e-5f
#define NSEG 129      // PWL segments = 128 breakpoints + 1
#define NT32 1563     // ceil(NN/32)
#define NT64 782      // ceil(NN/64)
#define NT4 12500     // NN/4 (nodes per 4-wave block in k_scores_sm; exact)
#define NBS 196       // ceil(NN/256) scan blocks
#define HLP 132       // hL padded row stride (floats): +4 breaks bank conflicts

typedef __bf16 bf16x8_t __attribute__((ext_vector_type(8)));
typedef unsigned short ushort8_t __attribute__((ext_vector_type(8)));
typedef float f32x4_t __attribute__((ext_vector_type(4)));
union BF8 { ushort8_t u; bf16x8_t b; };

// ---------- helpers ----------
__device__ __forceinline__ void fma4(float4& a, float s, float4 w) {
  a.x = fmaf(s, w.x, a.x); a.y = fmaf(s, w.y, a.y);
  a.z = fmaf(s, w.z, a.z); a.w = fmaf(s, w.w, a.w);
}
__device__ __forceinline__ unsigned short f2bf(float f) {   // RNE f32->bf16
  unsigned u = __float_as_uint(f);
  unsigned r = ((u >> 16) & 1u) + 0x7FFFu;
  return (unsigned short)((u + r) >> 16);
}
__device__ __forceinline__ float bf2f(unsigned short u) {
  return __uint_as_float((unsigned)u << 16);
}

// LayerNorm 32 nodes -> swizzled bf16 LDS tile [32][128]; block = 512 threads.
__device__ __forceinline__ void ln_tile_bf32(const float* __restrict__ h, int nb,
                                             const float* __restrict__ sc,
                                             const float* __restrict__ bi,
                                             ushort* xbf) {
  int tid = threadIdx.x;
  int r = tid >> 4, l16 = tid & 15;
  int nr = nb + r; if (nr >= NN) nr = NN - 1;   // clamp: tail rows unused
  const float* hp = h + (size_t)nr * DD + l16 * 8;
  float4 a0 = *(const float4*)hp;
  float4 a1 = *(const float4*)(hp + 4);
  float sum = a0.x + a0.y + a0.z + a0.w + a1.x + a1.y + a1.z + a1.w;
  float sq  = a0.x*a0.x + a0.y*a0.y + a0.z*a0.z + a0.w*a0.w
            + a1.x*a1.x + a1.y*a1.y + a1.z*a1.z + a1.w*a1.w;
#pragma unroll
  for (int off = 8; off >= 1; off >>= 1) {
    sum += __shfl_xor(sum, off, 64);
    sq  += __shfl_xor(sq,  off, 64);
  }
  float mu   = sum * (1.0f / DD);
  float var  = sq * (1.0f / DD) - mu * mu;
  float rstd = rsqrtf(var + LN_EPS);
  int d0 = l16 * 8;
  float4 s0 = *(const float4*)(sc + d0), s1 = *(const float4*)(sc + d0 + 4);
  float4 b0 = *(const float4*)(bi + d0), b1 = *(const float4*)(bi + d0 + 4);
  ushort8_t u;
  u[0] = f2bf((a0.x - mu) * rstd * s0.x + b0.x);
  u[1] = f2bf((a0.y - mu) * rstd * s0.y + b0.y);
  u[2] = f2bf((a0.z - mu) * rstd * s0.z + b0.z);
  u[3] = f2bf((a0.w - mu) * rstd * s0.w + b0.w);
  u[4] = f2bf((a1.x - mu) * rstd * s1.x + b1.x);
  u[5] = f2bf((a1.y - mu) * rstd * s1.y + b1.y);
  u[6] = f2bf((a1.z - mu) * rstd * s1.z + b1.z);
  u[7] = f2bf((a1.w - mu) * rstd * s1.w + b1.w);
  int off = (r * 256 + l16 * 16) ^ ((r & 7) << 4);
  *(ushort8_t*)((char*)xbf + off) = u;
}

// ---------- kernels ----------
// h = x @ node_W + node_b ; 32 nodes/block, W staged in LDS.
__global__ __launch_bounds__(256) void k_node_proj(const float* __restrict__ x,
                                                   const float* __restrict__ W,
                                                   const float* __restrict__ b,
                                                   float* __restrict__ h) {
  __shared__ float Wl[FIN * DD];    // 32 KB
  __shared__ float xt[32][FIN];     // 8 KB
  int tid = threadIdx.x;
  int nb = blockIdx.x * 32;
  for (int i = tid * 4; i < FIN * DD; i += 1024)
    *(float4*)&Wl[i] = *(const float4*)(W + i);
  for (int i = tid * 4; i < 32 * FIN; i += 1024) {
    int row = i >> 6, cc = i & 63;
    int node = nb + row; if (node >= NN) node = NN - 1;
    *(float4*)&xt[row][cc] = *(const float4*)(x + (size_t)node * FIN + cc);
  }
  __syncthreads();
  int c4 = (tid & 31) * 4;
  int r0 = (tid >> 5) * 4;
  float4 bv = *(const float4*)(b + c4);
  float4 a0 = bv, a1 = bv, a2 = bv, a3 = bv;
  for (int k = 0; k < FIN; k++) {
    float4 wv = *(const float4*)&Wl[k * DD + c4];
    fma4(a0, xt[r0][k], wv);
    fma4(a1, xt[r0 + 1][k], wv);
    fma4(a2, xt[r0 + 2][k], wv);
    fma4(a3, xt[r0 + 3][k], wv);
  }
  int n0 = nb + r0;
  if (n0 < NN)     *(float4*)(h + (size_t)n0 * DD + c4) = a0;
  if (n0 + 1 < NN) *(float4*)(h + (size_t)(n0 + 1) * DD + c4) = a1;
  if (n0 + 2 < NN) *(float4*)(h + (size_t)(n0 + 2) * DD + c4) = a2;
  if (n0 + 3 < NN) *(float4*)(h + (size_t)(n0 + 3) * DD + c4) = a3;
}

// LN1 + QKV projection via swapped-operand MFMA -> bf16 q/k/v. 32 rows/block, 8 waves.
// Used only for layer 0 (layers 1..3 get qkv from k_attn_ffn stage 5).
__global__ __launch_bounds__(512) void k_ln_qkv(const float* __restrict__ h,
    const float* __restrict__ n1s_l, const float* __restrict__ n1b_l,
    const ushort* __restrict__ qkvT_l,
    const float* __restrict__ qb_l, const float* __restrict__ kb_l, const float* __restrict__ vb_l,
    ushort* __restrict__ q, ushort* __restrict__ kk, ushort* __restrict__ v) {
  __shared__ __align__(16) ushort xbf[32 * DD];
  int nb = blockIdx.x * 32;
  ln_tile_bf32(h, nb, n1s_l, n1b_l, xbf);
  __syncthreads();
  int lane = threadIdx.x & 63;
  int w = threadIdx.x >> 6;
  int g = lane >> 4, c = lane & 15;
  int xr = (c & 7) << 4;
  char* xb = (char*)xbf;
  BF8 a[2][4];
#pragma unroll
  for (int nt = 0; nt < 2; nt++)
#pragma unroll
    for (int kt = 0; kt < 4; kt++)
      a[nt][kt].u = *(ushort8_t*)(xb + (((nt * 16 + c) * 256 + kt * 64 + g * 16) ^ xr));
#pragma unroll
  for (int ti = 0; ti < 3; ti++) {
    int t = w * 3 + ti;                // 0..23
    int m = t >> 3;                    // 0=q 1=k 2=v
    int colb = (t & 7) * 16;
    const float* bias = (m == 0 ? qb_l : (m == 1 ? kb_l : vb_l));
    float4 bv = *(const float4*)(bias + colb + g * 4);
    f32x4_t acc0 = {bv.x, bv.y, bv.z, bv.w};
    f32x4_t acc1 = acc0;
    const ushort* wp = qkvT_l + (size_t)(m * DD + colb + c) * DD + g * 8;
#pragma unroll
    for (int kt = 0; kt < 4; kt++) {
      BF8 b; b.u = *(const ushort8_t*)(wp + kt * 32);
      acc0 = __builtin_amdgcn_mfma_f32_16x16x32_bf16(b.b, a[0][kt].b, acc0, 0, 0, 0);
      acc1 = __builtin_amdgcn_mfma_f32_16x16x32_bf16(b.b, a[1][kt].b, acc1, 0, 0, 0);
    }
    ushort* out = (m == 0 ? q : (m == 1 ? kk : v));
    int n0 = nb + c;
    if (n0 < NN) {
      ushort4 o; o.x = f2bf(acc0[0]); o.y = f2bf(acc0[1]); o.z = f2bf(acc0[2]); o.w = f2bf(acc0[3]);
      *(ushort4*)(out + (size_t)n0 * DD + colb + g * 4) = o;
    }
    int n1 = nb + 16 + c;
    if (n1 < NN) {
      ushort4 o; o.x = f2bf(acc1[0]); o.y = f2bf(acc1[1]); o.z = f2bf(acc1[2]); o.w = f2bf(acc1[3]);
      *(ushort4*)(out + (size_t)n1 * DD + colb + g * 4) = o;
    }
  }
}

// FUSED edge-geometry + curvature + scores + softmax, 64 lanes/node.
// r20: k_edge1 deleted — phase A computes sim/dist directly from h via tgt-CSR.
// Phase A: h[node] staged in LDS; 8-lane groups process 8 edges in flight,
//   gathering only h[src] (halves k_edge1's two-row gather volume), 3-level
//   intra-group shfl reduce -> dot/dist; dist[e] written to global (phase B
//   rereads, L2-hot; __syncthreads drains stores). Per-group online
//   (m, sum, sum*d) + flash combine across groups -> av. Max exact; sums
//   reassociated ~1e-7 (same class as r18/r19 changes — absmax unmoved).
//   Self-loop dist stays exactly 0 (sum of (a-a)^2 = 0 in any order).
// Phase B (8 heads x 8 edge lanes): raw scores -> escore + online (m,sum).
// Phase C: shfl combine. Phase D: rewrite own scores as p = expf(sc-m)*inv.
// Max subtraction stays MANDATORY (r5/r6 lesson).
__global__ __launch_bounds__(256) void k_scores_sm(const int* __restrict__ src_s,
    const int* __restrict__ rowstart_t, const int* __restrict__ eid_t,
    const ushort* __restrict__ q, const ushort* __restrict__ k,
    const float* __restrict__ h, float* __restrict__ dist,
    const float* __restrict__ bp_g,
    const float* __restrict__ slope_l, const float* __restrict__ inter_l,
    float* __restrict__ escore) {
  __shared__ float lsl[NSEG * HH], lin[NSEG * HH], bp[DD];
  __shared__ float hnd[4][DD];
  int tid = threadIdx.x;
  for (int idx = tid; idx < NSEG * HH; idx += 256) { lsl[idx] = slope_l[idx]; lin[idx] = inter_l[idx]; }
  if (tid < DD) bp[tid] = bp_g[tid];
  int wv = tid >> 6;
  int node = blockIdx.x * 4 + wv;          // grid NT4*4 == NN exactly, no tail
  int lane = tid & 63;
  ((float2*)hnd[wv])[lane] = ((const float2*)(h + (size_t)node * DD))[lane];
  __syncthreads();
  int rs = rowstart_t[node], re = rowstart_t[node + 1];
  // ---- Phase A: dot/dist per edge (8 edges in flight), online aggv stats
  int g8 = lane >> 3, j8 = lane & 7;
  float4 kn0 = *(const float4*)&hnd[wv][j8 * 16];
  float4 kn1 = *(const float4*)&hnd[wv][j8 * 16 + 4];
  float4 kn2 = *(const float4*)&hnd[wv][j8 * 16 + 8];
  float4 kn3 = *(const float4*)&hnd[wv][j8 * 16 + 12];
  float am = -3.4e38f, den = 0.f, ndv = 0.f;
  for (int i = rs + g8; i < re; i += 8) {
    int e = eid_t[i];
    int s = src_s[e];
    const float4* sp = (const float4*)(h + (size_t)s * DD + j8 * 16);
    float4 s0 = sp[0], s1 = sp[1], s2 = sp[2], s3 = sp[3];
    float dot = 0.f, sq = 0.f;
    dot = fmaf(s0.x, kn0.x, dot); dot = fmaf(s0.y, kn0.y, dot);
    dot = fmaf(s0.z, kn0.z, dot); dot = fmaf(s0.w, kn0.w, dot);
    dot = fmaf(s1.x, kn1.x, dot); dot = fmaf(s1.y, kn1.y, dot);
    dot = fmaf(s1.z, kn1.z, dot); dot = fmaf(s1.w, kn1.w, dot);
    dot = fmaf(s2.x, kn2.x, dot); dot = fmaf(s2.y, kn2.y, dot);
    dot = fmaf(s2.z, kn2.z, dot); dot = fmaf(s2.w, kn2.w, dot);
    dot = fmaf(s3.x, kn3.x, dot); dot = fmaf(s3.y, kn3.y, dot);
    dot = fmaf(s3.z, kn3.z, dot); dot = fmaf(s3.w, kn3.w, dot);
    float d;
    d = s0.x - kn0.x; sq = fmaf(d, d, sq); d = s0.y - kn0.y; sq = fmaf(d, d, sq);
    d = s0.z - kn0.z; sq = fmaf(d, d, sq); d = s0.w - kn0.w; sq = fmaf(d, d, sq);
    d = s1.x - kn1.x; sq = fmaf(d, d, sq); d = s1.y - kn1.y; sq = fmaf(d, d, sq);
    d = s1.z - kn1.z; sq = fmaf(d, d, sq); d = s1.w - kn1.w; sq = fmaf(d, d, sq);
    d = s2.x - kn2.x; sq = fmaf(d, d, sq); d = s2.y - kn2.y; sq = fmaf(d, d, sq);
    d = s2.z - kn2.z; sq = fmaf(d, d, sq); d = s2.w - kn2.w; sq = fmaf(d, d, sq);
    d = s3.x - kn3.x; sq = fmaf(d, d, sq); d = s3.y - kn3.y; sq = fmaf(d, d, sq);
    d = s3.z - kn3.z; sq = fmaf(d, d, sq); d = s3.w - kn3.w; sq = fmaf(d, d, sq);
#pragma unroll
    for (int off = 1; off <= 4; off <<= 1) {
      dot += __shfl_xor(dot, off, 64);
      sq  += __shfl_xor(sq,  off, 64);
    }
    float dd = sqrtf(sq);
    if (j8 == 0) dist[e] = dd;
    float mn = fmaxf(am, dot);           // sim = dot (BETA == 1.0)
    float r  = expf(am - mn);
    float ev = expf(dot - mn);
    den = den * r + ev;
    ndv = fmaf(ev, dd, ndv * r);
    am = mn;
  }
#pragma unroll
  for (int off = 8; off <= 32; off <<= 1) {
    float m2 = __shfl_xor(am, off, 64);
    float d2 = __shfl_xor(den, off, 64);
    float n2 = __shfl_xor(ndv, off, 64);
    float M = fmaxf(am, m2);
    float ra = expf(am - M), rb = expf(m2 - M);
    den = den * ra + d2 * rb;
    ndv = ndv * ra + n2 * rb;
    am = M;
  }
  float av = den > 0.f ? ndv / den : 0.f;
  __syncthreads();   // drain dist[] stores to L2 before phase B reads them
  // ---- Phase B: raw scores + online (m, sum)
  int hh = lane & 7;
  int eidx = lane >> 3;
  const ushort8_t* kp = (const ushort8_t*)(k + (size_t)node * DD + hh * DHH);
  ushort8_t k0 = kp[0], k1 = kp[1];
  float m = -3.4e38f, ssum = 0.f;
  for (int i = rs + eidx; i < re; i += 8) {
    int e = eid_t[i];
    int s = src_s[e];
    float dd = dist[e];
    const ushort8_t* qp = (const ushort8_t*)(q + (size_t)s * DD + hh * DHH);
    ushort8_t q0 = qp[0], q1 = qp[1];
    float curv = 1.0f - av / fmaxf(dd, 1e-6f);
    int lo = 0, hi = DD;
    while (lo < hi) { int mid = (lo + hi) >> 1; if (bp[mid] < curv) lo = mid + 1; else hi = mid; }
    float bias = fmaf(lsl[lo * HH + hh], curv, lin[lo * HH + hh]);
    float dot = 0.f;
#pragma unroll
    for (int jj = 0; jj < 8; jj++) dot = fmaf(bf2f(q0[jj]), bf2f(k0[jj]), dot);
#pragma unroll
    for (int jj = 0; jj < 8; jj++) dot = fmaf(bf2f(q1[jj]), bf2f(k1[jj]), dot);
    float sc = dot * 0.25f + bias;   // 1/sqrt(16)
    escore[e * HH + hh] = sc;
    float mn = fmaxf(m, sc);
    ssum = ssum * expf(m - mn) + expf(sc - mn);
    m = mn;
  }
  // ---- Phase C: combine (m, s) across the 8 edge-lane groups
#pragma unroll
  for (int off = 8; off <= 32; off <<= 1) {
    float m2 = __shfl_xor(m, off, 64);
    float s2 = __shfl_xor(ssum, off, 64);
    float M = fmaxf(m, m2);
    ssum = ssum * expf(m - M) + s2 * expf(m2 - M);
    m = M;
  }
  float inv = ssum > 0.f ? 1.0f / ssum : 0.f;
  // ---- Phase D: rewrite own raw scores as final probabilities
  for (int i = rs + eidx; i < re; i += 8) {
    size_t idx = (size_t)eid_t[i] * HH + hh;
    float sc = escore[idx];
    escore[idx] = expf(sc - m) * inv;
  }
}

// CSR-gather message aggregation: one wave per src node, 2 dims/lane -> bf16 out.
// escore holds final probabilities (computed in k_scores_sm phase D).
__global__ __launch_bounds__(256) void k_agg(const int* __restrict__ tgt_s,
    const int* __restrict__ rowstart,
    const float* __restrict__ escore,
    const ushort* __restrict__ v, ushort* __restrict__ aggmb) {
  int wave = (blockIdx.x * 256 + threadIdx.x) >> 6;
  int lane = threadIdx.x & 63;
  int rs = rowstart[wave], re = rowstart[wave + 1];
  int hh = lane >> 3;
  int d = lane * 2;
  float a0 = 0.f, a1 = 0.f;
  int i = rs;
  for (; i + 4 <= re; i += 4) {
    int t0 = tgt_s[i], t1 = tgt_s[i + 1], t2 = tgt_s[i + 2], t3 = tgt_s[i + 3];
    float p0 = escore[(i    ) * HH + hh];
    float p1 = escore[(i + 1) * HH + hh];
    float p2 = escore[(i + 2) * HH + hh];
    float p3 = escore[(i + 3) * HH + hh];
    ushort2 v0 = *(const ushort2*)(v + (size_t)t0 * DD + d);
    ushort2 v1 = *(const ushort2*)(v + (size_t)t1 * DD + d);
    ushort2 v2 = *(const ushort2*)(v + (size_t)t2 * DD + d);
    ushort2 v3 = *(const ushort2*)(v + (size_t)t3 * DD + d);
    a0 = fmaf(p0, bf2f(v0.x), a0); a1 = fmaf(p0, bf2f(v0.y), a1);
    a0 = fmaf(p1, bf2f(v1.x), a0); a1 = fmaf(p1, bf2f(v1.y), a1);
    a0 = fmaf(p2, bf2f(v2.x), a0); a1 = fmaf(p2, bf2f(v2.y), a1);
    a0 = fmaf(p3, bf2f(v3.x), a0); a1 = fmaf(p3, bf2f(v3.y), a1);
  }
  for (; i < re; i++) {
    int t = tgt_s[i];
    float prob = escore[i * HH + hh];
    ushort2 vv = *(const ushort2*)(v + (size_t)t * DD + d);
    a0 = fmaf(prob, bf2f(vv.x), a0);
    a1 = fmaf(prob, bf2f(vv.y), a1);
  }
  ushort2 o; o.x = f2bf(a0); o.y = f2bf(a1);
  *(ushort2*)(aggmb + (size_t)wave * DD + d) = o;
}

// FUSED: h' = h + aggm@oW + ob (LDS hL) -> LN2 -> FFN -> h = h' + FFN out,
// then (stage 5, if do_qkv) LN1(next layer) + QKV projection.
__global__ __launch_bounds__(512) void k_attn_ffn(const ushort* __restrict__ aggmb,
    const ushort* __restrict__ oT_l, const float* __restrict__ ob_l,
    const float* __restrict__ n2s_l, const float* __restrict__ n2b_l,
    const ushort* __restrict__ f1T_l, const float* __restrict__ f1b_l,
    const ushort* __restrict__ f2T_l, const float* __restrict__ f2b_l,
    float* __restrict__ h,
    int do_qkv,
    const float* __restrict__ n1s_n, const float* __restrict__ n1b_n,
    const ushort* __restrict__ qkvT_n,
    const float* __restrict__ qb_n, const float* __restrict__ kb_n, const float* __restrict__ vb_n,
    ushort* __restrict__ q, ushort* __restrict__ kk, ushort* __restrict__ v) {
  __shared__ float hL[64 * HLP];                      // 33 KB
  __shared__ __align__(16) char ubuf[64 * 128 * 2];   // 16 KB union: xbf / tbf / xbf(qkv)
  char* xb = ubuf;
  char* tb = ubuf;
  int nb = blockIdx.x * 64;
  int tid = threadIdx.x;
  int lane = tid & 63, w = tid >> 6;
  int g = lane >> 4, c = lane & 15;
  int colb = w * 16;
  int xr = (c & 7) << 4;
  // ---- Stage 1: O-projection + residual -> hL
  {
    float4 obv = *(const float4*)(ob_l + colb + g * 4);
    const ushort* wp = oT_l + (size_t)(colb + c) * DD + g * 8;
    BF8 b0, b1, b2, b3;
    b0.u = *(const ushort8_t*)(wp);
    b1.u = *(const ushort8_t*)(wp + 32);
    b2.u = *(const ushort8_t*)(wp + 64);
    b3.u = *(const ushort8_t*)(wp + 96);
#pragma unroll
    for (int nt = 0; nt < 4; nt++) {
      int node = nb + nt * 16 + c;
      int na = node < NN ? node : NN - 1;
      const ushort* ap = aggmb + (size_t)na * DD + g * 8;
      BF8 a0, a1, a2, a3;
      a0.u = *(const ushort8_t*)(ap);
      a1.u = *(const ushort8_t*)(ap + 32);
      a2.u = *(const ushort8_t*)(ap + 64);
      a3.u = *(const ushort8_t*)(ap + 96);
      f32x4_t acc = {obv.x, obv.y, obv.z, obv.w};
      acc = __builtin_amdgcn_mfma_f32_16x16x32_bf16(b0.b, a0.b, acc, 0, 0, 0);
      acc = __builtin_amdgcn_mfma_f32_16x16x32_bf16(b1.b, a1.b, acc, 0, 0, 0);
      acc = __builtin_amdgcn_mfma_f32_16x16x32_bf16(b2.b, a2.b, acc, 0, 0, 0);
      acc = __builtin_amdgcn_mfma_f32_16x16x32_bf16(b3.b, a3.b, acc, 0, 0, 0);
      float4 hv = *(const float4*)(h + (size_t)na * DD + colb + g * 4);
      hv.x += acc[0]; hv.y += acc[1]; hv.z += acc[2]; hv.w += acc[3];
      *(float4*)&hL[(nt * 16 + c) * HLP + colb + g * 4] = hv;
    }
  }
  __syncthreads();
  // ---- Stage 2: LN2 from hL -> xbf
  {
    int l16 = tid & 15;
    int d0 = l16 * 8;
    float4 s0 = *(const float4*)(n2s_l + d0), s1 = *(const float4*)(n2s_l + d0 + 4);
    float4 bb0 = *(const float4*)(n2b_l + d0), bb1 = *(const float4*)(n2b_l + d0 + 4);
#pragma unroll
    for (int p = 0; p < 2; p++) {
      int r = p * 32 + (tid >> 4);
      const float* hp = &hL[r * HLP + d0];
      float4 a0 = *(const float4*)hp;
      float4 a1 = *(const float4*)(hp + 4);
      float sum = a0.x + a0.y + a0.z + a0.w + a1.x + a1.y + a1.z + a1.w;
      float sq  = a0.x*a0.x + a0.y*a0.y + a0.z*a0.z + a0.w*a0.w
                + a1.x*a1.x + a1.y*a1.y + a1.z*a1.z + a1.w*a1.w;
#pragma unroll
      for (int off = 8; off >= 1; off >>= 1) {
        sum += __shfl_xor(sum, off, 64);
        sq  += __shfl_xor(sq,  off, 64);
      }
      float mu   = sum * (1.0f / DD);
      float var  = sq * (1.0f / DD) - mu * mu;
      float rstd = rsqrtf(var + LN_EPS);
      ushort8_t u;
      u[0] = f2bf((a0.x - mu) * rstd * s0.x + bb0.x);
      u[1] = f2bf((a0.y - mu) * rstd * s0.y + bb0.y);
      u[2] = f2bf((a0.z - mu) * rstd * s0.z + bb0.z);
      u[3] = f2bf((a0.w - mu) * rstd * s0.w + bb0.w);
      u[4] = f2bf((a1.x - mu) * rstd * s1.x + bb1.x);
      u[5] = f2bf((a1.y - mu) * rstd * s1.y + bb1.y);
      u[6] = f2bf((a1.z - mu) * rstd * s1.z + bb1.z);
      u[7] = f2bf((a1.w - mu) * rstd * s1.w + bb1.w);
      int off = (r * 256 + l16 * 16) ^ ((r & 7) << 4);
      *(ushort8_t*)(xb + off) = u;
    }
  }
  __syncthreads();
  // A-frags from xbf (registers)
  BF8 a[4][4];
#pragma unroll
  for (int nt = 0; nt < 4; nt++)
#pragma unroll
    for (int kt = 0; kt < 4; kt++)
      a[nt][kt].u = *(ushort8_t*)(xb + (((nt * 16 + c) * 256 + kt * 64 + g * 16) ^ xr));
  __syncthreads();   // xbf dead; ubuf becomes tbf
  // ---- Stage 3: FFN, 4 chunks of 128 cols (tbf row stride 256B)
  float4 bv2 = *(const float4*)(f2b_l + colb + g * 4);
  f32x4_t o0 = {bv2.x, bv2.y, bv2.z, bv2.w};
  f32x4_t o1 = o0, o2 = o0, o3 = o0;
#pragma unroll
  for (int ch = 0; ch < 4; ch++) {
    if (ch) __syncthreads();           // tbf reuse: wait for prev-chunk reads
    {
      int col = ch * 128 + w * 16;
      float4 bv = *(const float4*)(f1b_l + col + g * 4);
      f32x4_t ac0 = {bv.x, bv.y, bv.z, bv.w};
      f32x4_t ac1 = ac0, ac2 = ac0, ac3 = ac0;
      const ushort* wp = f1T_l + (size_t)(col + c) * DD + g * 8;
#pragma unroll
      for (int kt = 0; kt < 4; kt++) {
        BF8 b; b.u = *(const ushort8_t*)(wp + kt * 32);
        ac0 = __builtin_amdgcn_mfma_f32_16x16x32_bf16(b.b, a[0][kt].b, ac0, 0, 0, 0);
        ac1 = __builtin_amdgcn_mfma_f32_16x16x32_bf16(b.b, a[1][kt].b, ac1, 0, 0, 0);
        ac2 = __builtin_amdgcn_mfma_f32_16x16x32_bf16(b.b, a[2][kt].b, ac2, 0, 0, 0);
        ac3 = __builtin_amdgcn_mfma_f32_16x16x32_bf16(b.b, a[3][kt].b, ac3, 0, 0, 0);
      }
      int colL = (w * 16 + g * 4) * 2;
      {
        int row = c;
        ushort4 o4; o4.x = f2bf(fmaxf(ac0[0], 0.f)); o4.y = f2bf(fmaxf(ac0[1], 0.f));
        o4.z = f2bf(fmaxf(ac0[2], 0.f)); o4.w = f2bf(fmaxf(ac0[3], 0.f));
        *(ushort4*)(tb + ((row * 256 + colL) ^ ((row & 7) << 4))) = o4;
      }
      {
        int row = 16 + c;
        ushort4 o4; o4.x = f2bf(fmaxf(ac1[0], 0.f)); o4.y = f2bf(fmaxf(ac1[1], 0.f));
        o4.z = f2bf(fmaxf(ac1[2], 0.f)); o4.w = f2bf(fmaxf(ac1[3], 0.f));
        *(ushort4*)(tb + ((row * 256 + colL) ^ ((row & 7) << 4))) = o4;
      }
      {
        int row = 32 + c;
        ushort4 o4; o4.x = f2bf(fmaxf(ac2[0], 0.f)); o4.y = f2bf(fmaxf(ac2[1], 0.f));
        o4.z = f2bf(fmaxf(ac2[2], 0.f)); o4.w = f2bf(fmaxf(ac2[3], 0.f));
        *(ushort4*)(tb + ((row * 256 + colL) ^ ((row & 7) << 4))) = o4;
      }
      {
        int row = 48 + c;
        ushort4 o4; o4.x = f2bf(fmaxf(ac3[0], 0.f)); o4.y = f2bf(fmaxf(ac3[1], 0.f));
        o4.z = f2bf(fmaxf(ac3[2], 0.f)); o4.w = f2bf(fmaxf(ac3[3], 0.f));
        *(ushort4*)(tb + ((row * 256 + colL) ^ ((row & 7) << 4))) = o4;
      }
    }
    __syncthreads();
    const ushort* wp2 = f2T_l + (size_t)(colb + c) * 512 + ch * 128 + g * 8;
#pragma unroll
    for (int kt = 0; kt < 4; kt++) {
      BF8 b; b.u = *(const ushort8_t*)(wp2 + kt * 32);
      BF8 t0; t0.u = *(ushort8_t*)(tb + (((c) * 256 + kt * 64 + g * 16) ^ xr));
      BF8 t1; t1.u = *(ushort8_t*)(tb + (((16 + c) * 256 + kt * 64 + g * 16) ^ xr));
      BF8 t2; t2.u = *(ushort8_t*)(tb + (((32 + c) * 256 + kt * 64 + g * 16) ^ xr));
      BF8 t3; t3.u = *(ushort8_t*)(tb + (((48 + c) * 256 + kt * 64 + g * 16) ^ xr));
      o0 = __builtin_amdgcn_mfma_f32_16x16x32_bf16(b.b, t0.b, o0, 0, 0, 0);
      o1 = __builtin_amdgcn_mfma_f32_16x16x32_bf16(b.b, t1.b, o1, 0, 0, 0);
      o2 = __builtin_amdgcn_mfma_f32_16x16x32_bf16(b.b, t2.b, o2, 0, 0, 0);
      o3 = __builtin_amdgcn_mfma_f32_16x16x32_bf16(b.b, t3.b, o3, 0, 0, 0);
    }
  }
  // ---- Stage 4: final residual from hL -> global h (and back into hL for stage 5)
  {
    float* lp = &hL[c * HLP + colb + g * 4];
    float4 hv = *(const float4*)lp;
    hv.x += o0[0]; hv.y += o0[1]; hv.z += o0[2]; hv.w += o0[3];
    *(float4*)lp = hv;
    int node = nb + c;
    if (node < NN) *(float4*)(h + (size_t)node * DD + colb + g * 4) = hv;
  }
  {
    float* lp = &hL[(16 + c) * HLP + colb + g * 4];
    float4 hv = *(const float4*)lp;
    hv.x += o1[0]; hv.y += o1[1]; hv.z += o1[2]; hv.w += o1[3];
    *(float4*)lp = hv;
    int node = nb + 16 + c;
    if (node < NN) *(float4*)(h + (size_t)node * DD + colb + g * 4) = hv;
  }
  {
    float* lp = &hL[(32 + c) * HLP + colb + g * 4];
    float4 hv = *(const float4*)lp;
    hv.x += o2[0]; hv.y += o2[1]; hv.z += o2[2]; hv.w += o2[3];
    *(float4*)lp = hv;
    int node = nb + 32 + c;
    if (node < NN) *(float4*)(h + (size_t)node * DD + colb + g * 4) = hv;
  }
  {
    float* lp = &hL[(48 + c) * HLP + colb + g * 4];
    float4 hv = *(const float4*)lp;
    hv.x += o3[0]; hv.y += o3[1]; hv.z += o3[2]; hv.w += o3[3];
    *(float4*)lp = hv;
    int node = nb + 48 + c;
    if (node < NN) *(float4*)(h + (size_t)node * DD + colb + g * 4) = hv;
  }
  if (!do_qkv) return;
  __syncthreads();   // hL final visible; tbf reads done -> ubuf becomes xbf again
  // ---- Stage 5: LN1(next layer) from hL -> xbf
  {
    int l16 = tid & 15;
    int d0 = l16 * 8;
    float4 s0 = *(const float4*)(n1s_n + d0), s1 = *(const float4*)(n1s_n + d0 + 4);
    float4 bb0 = *(const float4*)(n1b_n + d0), bb1 = *(const float4*)(n1b_n + d0 + 4);
#pragma unroll
    for (int p = 0; p < 2; p++) {
      int r = p * 32 + (tid >> 4);
      const float* hp = &hL[r * HLP + d0];
      float4 a0 = *(const float4*)hp;
      float4 a1 = *(const float4*)(hp + 4);
      float sum = a0.x + a0.y + a0.z + a0.w + a1.x + a1.y + a1.z + a1.w;
      float sq  = a0.x*a0.x + a0.y*a0.y + a0.z*a0.z + a0.w*a0.w
                + a1.x*a1.x + a1.y*a1.y + a1.z*a1.z + a1.w*a1.w;
#pragma unroll
      for (int off = 8; off >= 1; off >>= 1) {
        sum += __shfl_xor(sum, off, 64);
        sq  += __shfl_xor(sq,  off, 64);
      }
      float mu   = sum * (1.0f / DD);
      float var  = sq * (1.0f / DD) - mu * mu;
      float rstd = rsqrtf(var + LN_EPS);
      ushort8_t u;
      u[0] = f2bf((a0.x - mu) * rstd * s0.x + bb0.x);
      u[1] = f2bf((a0.y - mu) * rstd * s0.y + bb0.y);
      u[2] = f2bf((a0.z - mu) * rstd * s0.z + bb0.z);
      u[3] = f2bf((a0.w - mu) * rstd * s0.w + bb0.w);
      u[4] = f2bf((a1.x - mu) * rstd * s1.x + bb1.x);
      u[5] = f2bf((a1.y - mu) * rstd * s1.y + bb1.y);
      u[6] = f2bf((a1.z - mu) * rstd * s1.z + bb1.z);
      u[7] = f2bf((a1.w - mu) * rstd * s1.w + bb1.w);
      int off = (r * 256 + l16 * 16) ^ ((r & 7) << 4);
      *(ushort8_t*)(xb + off) = u;
    }
  }
  __syncthreads();
  BF8 aq[4][4];
#pragma unroll
  for (int nt = 0; nt < 4; nt++)
#pragma unroll
    for (int kt = 0; kt < 4; kt++)
      aq[nt][kt].u = *(ushort8_t*)(xb + (((nt * 16 + c) * 256 + kt * 64 + g * 16) ^ xr));
#pragma unroll
  for (int ti = 0; ti < 3; ti++) {
    int t = w * 3 + ti;                // 0..23
    int m = t >> 3;                    // 0=q 1=k 2=v
    int colq = (t & 7) * 16;
    const float* bias = (m == 0 ? qb_n : (m == 1 ? kb_n : vb_n));
    float4 bv = *(const float4*)(bias + colq + g * 4);
    f32x4_t ac0 = {bv.x, bv.y, bv.z, bv.w};
    f32x4_t ac1 = ac0, ac2 = ac0, ac3 = ac0;
    const ushort* wp = qkvT_n + (size_t)(m * DD + colq + c) * DD + g * 8;
#pragma unroll
    for (int kt = 0; kt < 4; kt++) {
      BF8 b; b.u = *(const ushort8_t*)(wp + kt * 32);
      ac0 = __builtin_amdgcn_mfma_f32_16x16x32_bf16(b.b, aq[0][kt].b, ac0, 0, 0, 0);
      ac1 = __builtin_amdgcn_mfma_f32_16x16x32_bf16(b.b, aq[1][kt].b, ac1, 0, 0, 0);
      ac2 = __builtin_amdgcn_mfma_f32_16x16x32_bf16(b.b, aq[2][kt].b, ac2, 0, 0, 0);
      ac3 = __builtin_amdgcn_mfma_f32_16x16x32_bf16(b.b, aq[3][kt].b, ac3, 0, 0, 0);
    }
    ushort* out = (m == 0 ? q : (m == 1 ? kk : v));
    {
      int node = nb + c;
      if (node < NN) {
        ushort4 o; o.x = f2bf(ac0[0]); o.y = f2bf(ac0[1]); o.z = f2bf(ac0[2]); o.w = f2bf(ac0[3]);
        *(ushort4*)(out + (size_t)node * DD + colq + g * 4) = o;
      }
    }
    {
      int node = nb + 16 + c;
      if (node < NN) {
        ushort4 o; o.x = f2bf(ac1[0]); o.y = f2bf(ac1[1]); o.z = f2bf(ac1[2]); o.w = f2bf(ac1[3]);
        *(ushort4*)(out + (size_t)node * DD + colq + g * 4) = o;
      }
    }
    {
      int node = nb + 32 + c;
      if (node < NN) {
        ushort4 o; o.x = f2bf(ac2[0]); o.y = f2bf(ac2[1]); o.z = f2bf(ac2[2]); o.w = f2bf(ac2[3]);
        *(ushort4*)(out + (size_t)node * DD + colq + g * 4) = o;
      }
    }
    {
      int node = nb + 48 + c;
      if (node < NN) {
        ushort4 o; o.x = f2bf(ac3[0]); o.y = f2bf(ac3[1]); o.z = f2bf(ac3[2]); o.w = f2bf(ac3[3]);
        *(ushort4*)(out + (size_t)node * DD + colq + g * 4) = o;
      }
    }
  }
}

// ---------- once-per-call setup kernels ----------
template <int K, int C>
__global__ void k_wt(const float* __restrict__ W, ushort* __restrict__ WT, int nm, int dstride) {
  int idx = blockIdx.x * 256 + threadIdx.x;
  if (idx >= K * C * nm) return;
  int mi = idx / (K * C), rem = idx - mi * (K * C);
  int cc = rem / K, kk2 = rem - cc * K;
  WT[(size_t)mi * dstride + cc * K + kk2] = f2bf(W[(size_t)mi * K * C + (size_t)kk2 * C + cc]);
}

__global__ void k_hist(const int* __restrict__ idxs, int* __restrict__ cnt) {
  int e = blockIdx.x * 256 + threadIdx.x;
  if (e < NE) atomicAdd(cnt + idxs[e], 1);
}

__global__ __launch_bounds__(256) void k_scan_blk(const int* __restrict__ cnt, int* __restrict__ bsum) {
  __shared__ int red[256];
  int tid = threadIdx.x;
  int idx = blockIdx.x * 256 + tid;
  red[tid] = (idx < NN) ? cnt[idx] : 0;
  __syncthreads();
  for (int off = 128; off >= 1; off >>= 1) {
    if (tid < off) red[tid] += red[tid + off];
    __syncthreads();
  }
  if (tid == 0) bsum[blockIdx.x] = red[0];
}

__global__ __launch_bounds__(256) void k_scan_top(const int* __restrict__ bsum,
                                                  int* __restrict__ boff, int* __restrict__ rowstart) {
  __shared__ int ps[256];
  int t = threadIdx.x;
  int v = (t < NBS) ? bsum[t] : 0;
  ps[t] = v;
  __syncthreads();
  for (int off = 1; off < 256; off <<= 1) {
    int x = (t >= off) ? ps[t - off] : 0;
    __syncthreads();
    ps[t] += x;
    __syncthreads();
  }
  boff[t] = ps[t] - v;                 // exclusive prefix of block sums
  if (t == 255) rowstart[NN] = ps[255];
}

__global__ __launch_bounds__(256) void k_scan_fin(const int* __restrict__ cnt,
                                                  const int* __restrict__ boff, int* __restrict__ rowstart) {
  __shared__ int ps[256];
  int t = threadIdx.x;
  int idx = blockIdx.x * 256 + t;
  int v = (idx < NN) ? cnt[idx] : 0;
  ps[t] = v;
  __syncthreads();
  for (int off = 1; off < 256; off <<= 1) {
    int x = (t >= off) ? ps[t - off] : 0;
    __syncthreads();
    ps[t] += x;
    __syncthreads();
  }
  if (idx < NN) rowstart[idx] = boff[blockIdx.x] + ps[t] - v;
}

__global__ void k_fill(const int* __restrict__ src, const int* __restrict__ tgt,
                       const int* __restrict__ rowstart,
                       int* __restrict__ cur, int* __restrict__ src_s, int* __restrict__ tgt_s) {
  int e = blockIdx.x * 256 + threadIdx.x;
  if (e >= NE) return;
  int s = src[e];
  int p = atomicAdd(cur + s, 1);
  int pos = rowstart[s] + p;
  src_s[pos] = s;
  tgt_s[pos] = tgt[e];
}

__global__ void k_fill_t(const int* __restrict__ tgt_s, const int* __restrict__ rowstart_t,
                         int* __restrict__ cur_t, int* __restrict__ eid_t) {
  int i = blockIdx.x * 256 + threadIdx.x;
  if (i >= NE) return;
  int t = tgt_s[i];
  int p = atomicAdd(cur_t + t, 1);
  eid_t[rowstart_t[t] + p] = i;
}

__global__ __launch_bounds__(64) void k_mbias_par(const float* __restrict__ cW2, const float* __restrict__ cb2,
                                                  const float* __restrict__ bW, const float* __restrict__ bb,
                                                  float* __restrict__ M, float* __restrict__ base) {
  int bid = blockIdx.x;
  int l = bid >> 7, d = bid & 127;
  int lane = threadIdx.x;
  int hh = lane >> 3, j0 = lane & 7;
  const float* bWl = bW + (size_t)l * DD * HH;
  float acc = 0.f;
#pragma unroll
  for (int t = 0; t < 16; t++) {
    int k = j0 + t * 8;
    acc = fmaf(cW2[d * DD + k], bWl[k * HH + hh], acc);
  }
#pragma unroll
  for (int off = 1; off <= 4; off <<= 1) acc += __shfl_xor(acc, off, 64);
  if (j0 == 0) M[(size_t)l * DD * HH + d * HH + hh] = acc;
  if (d == 0) {
    float bacc = 0.f;
#pragma unroll
    for (int t = 0; t < 16; t++) {
      int k = j0 + t * 8;
      bacc = fmaf(cb2[k], bWl[k * HH + hh], bacc);
    }
#pragma unroll
    for (int off = 1; off <= 4; off <<= 1) bacc += __shfl_xor(bacc, off, 64);
    if (j0 == 0) base[l * HH + hh] = bacc + bb[l * HH + hh];
  }
}

__global__ __launch_bounds__(128) void k_bp(const float* __restrict__ cW1, const float* __restrict__ cb1,
                                            float* __restrict__ bpg, int* __restrict__ posg) {
  __shared__ float x[DD], bp[DD];
  int tid = threadIdx.x;
  float c1v = cW1[tid], cbv = cb1[tid];
  x[tid] = (c1v == 0.f) ? __builtin_inff() : (-cbv / c1v);
  __syncthreads();
  float xv = x[tid]; int p = 0;
  for (int j = 0; j < DD; j++) {
    float xj = x[j];
    if (xj < xv || (xj == xv && j < tid)) p++;
  }
  bp[p] = xv;
  posg[tid] = p;
  __syncthreads();
  bpg[tid] = bp[tid];
}

__global__ __launch_bounds__(64) void k_pwl_tab(const float* __restrict__ cW1, const float* __restrict__ cb1,
    const int* __restrict__ posg, const float* __restrict__ Mb, const float* __restrict__ basel,
    float* __restrict__ slopeg, float* __restrict__ interg) {
  int bid = blockIdx.x;
  int l = bid / NSEG, s = bid - l * NSEG;
  int lane = threadIdx.x;
  int hh = lane >> 3, j0 = lane & 7;
  const float* M = Mb + (size_t)l * DD * HH;
  float sl = 0.f, in = 0.f;
#pragma unroll
  for (int t = 0; t < 16; t++) {
    int d = j0 + t * 8;
    float cv = cW1[d], cbv = cb1[d];
    int p = posg[d];
    bool act = (cv == 0.f) ? (cbv > 0.f) : ((cv > 0.f) ? (p < s) : (p >= s));
    float m = act ? M[d * HH + hh] : 0.f;
    sl = fmaf(cv, m, sl);
    in = fmaf(cbv, m, in);
  }
#pragma unroll
  for (int off = 1; off <= 4; off <<= 1) {
    sl += __shfl_xor(sl, off, 64);
    in += __shfl_xor(in, off, 64);
  }
  if (j0 == 0) {
    size_t o = (size_t)l * NSEG * HH + s * HH + hh;
    slopeg[o] = sl;
    interg[o] = in + basel[l * HH + hh];
  }
}

__global__ void k_bounds(const int* __restrict__ batch, int* __restrict__ gstart, int* __restrict__ gend) {
  int n = blockIdx.x * 256 + threadIdx.x;
  if (n >= NN) return;
  int b = batch[n];
  if (n == 0 || batch[n - 1] != b) gstart[b] = n;
  if (n == NN - 1 || batch[n + 1] != b) gend[b] = n + 1;
}

__global__ __launch_bounds__(256) void k_pool_part(const float* __restrict__ h,
    const int* __restrict__ batch, float* __restrict__ gpool) {
  int tid = threadIdx.x;
  int d = tid & 127, sub = tid >> 7;
  int n0 = blockIdx.x * 256;
  int nend = n0 + 256; if (nend > NN) nend = NN;
  float run = 0.f; int gcur = -1;
  for (int n = n0 + sub; n < nend; n += 2) {
    int g = batch[n];
    if (g != gcur) {
      if (gcur >= 0) atomicAdd(gpool + (size_t)gcur * DD + d, run);
      run = 0.f; gcur = g;
    }
    run += h[(size_t)n * DD + d];
  }
  if (gcur >= 0) atomicAdd(gpool + (size_t)gcur * DD + d, run);
}

__global__ __launch_bounds__(256) void k_head(const float* __restrict__ gpool,
    const int* __restrict__ gstart, const int* __restrict__ gend,
    const float* __restrict__ W1, const float* __restrict__ b1,
    const float* __restrict__ W2, const float* __restrict__ b2, float* __restrict__ out) {
  __shared__ float mid[NG * 64];
  int tid = threadIdx.x;
  for (int idx = tid; idx < NG * 64; idx += 256) {
    int g = idx >> 6, j = idx & 63;
    int cnt = gend[g] - gstart[g]; if (cnt < 1) cnt = 1;
    float rc = 1.0f / (float)cnt;
    float acc = 0.f;
    for (int d = 0; d < DD; d++) acc = fmaf(gpool[g * DD + d], W1[d * 64 + j], acc);
    mid[idx] = fmaxf(fmaf(acc, rc, b1[j]), 0.f);
  }
  __syncthreads();
  if (tid < NG) {
    float acc = b2[0];
    for (int j = 0; j < 64; j++) acc = fmaf(mid[tid * 64 + j], W2[j], acc);
    out[tid] = acc;
  }
}

// ---------- launch ----------
extern "C" void kernel_launch(void* const* d_in, const int* in_sizes, int n_in,
                              void* d_out, int out_size, void* d_ws, size_t ws_size,
                              hipStream_t stream) {
  const float* x      = (const float*)d_in[0];
  const int*   ei     = (const int*)d_in[1];
  const int*   batch  = (const int*)d_in[2];
  const float* node_W = (const float*)d_in[3];
  const float* node_b = (const float*)d_in[4];
  const float* cW1    = (const float*)d_in[5];
  const float* cb1    = (const float*)d_in[6];
  const float* cW2    = (const float*)d_in[7];
  const float* cb2    = (const float*)d_in[8];
  const float* qW     = (const float*)d_in[9];
  const float* qb     = (const float*)d_in[10];
  const float* kW     = (const float*)d_in[11];
  const float* kb     = (const float*)d_in[12];
  const float* vW     = (const float*)d_in[13];
  const float* vb     = (const float*)d_in[14];
  const float* oW     = (const float*)d_in[15];
  const float* ob     = (const float*)d_in[16];
  const float* bW     = (const float*)d_in[17];
  const float* bb     = (const float*)d_in[18];
  const float* f1W    = (const float*)d_in[19];
  const float* f1b    = (const float*)d_in[20];
  const float* f2W    = (const float*)d_in[21];
  const float* f2b    = (const float*)d_in[22];
  const float* n1s    = (const float*)d_in[23];
  const float* n1b    = (const float*)d_in[24];
  const float* n2s    = (const float*)d_in[25];
  const float* n2b    = (const float*)d_in[26];
  const float* outW1  = (const float*)d_in[27];
  const float* outb1  = (const float*)d_in[28];
  const float* outW2  = (const float*)d_in[29];
  const float* outb2  = (const float*)d_in[30];

  const int* src = ei;
  const int* tgt = ei + NE;

  char* wp = (char*)d_ws;
  auto alloc = [&](size_t bytes) { void* p = (void*)wp; wp += (bytes + 255) & ~(size_t)255; return p; };
  float*    h       = (float*)alloc((size_t)NN * DD * 4);
  ushort*   q       = (ushort*)alloc((size_t)NN * DD * 2);
  ushort*   kk      = (ushort*)alloc((size_t)NN * DD * 2);
  ushort*   v       = (ushort*)alloc((size_t)NN * DD * 2);
  ushort*   aggmb   = (ushort*)alloc((size_t)NN * DD * 2);
  float*    dist    = (float*)alloc((size_t)NE * 4);
  float*    escore  = (float*)alloc((size_t)NE * HH * 4);
  float*    Mb      = (float*)alloc((size_t)NL * DD * HH * 4);
  float*    basel   = (float*)alloc((size_t)NL * HH * 4);
  float*    bpg     = (float*)alloc((size_t)DD * 4);
  int*      posg    = (int*)alloc((size_t)DD * 4);
  float*    slopeg  = (float*)alloc((size_t)NL * NSEG * HH * 4);
  float*    interg  = (float*)alloc((size_t)NL * NSEG * HH * 4);
  int*      rowstart= (int*)alloc((size_t)(NN + 1) * 4);
  int*      rowstart_t = (int*)alloc((size_t)(NN + 1) * 4);
  int*      eid_t   = (int*)alloc((size_t)NE * 4);
  int*      src_s   = (int*)alloc((size_t)NE * 4);
  int*      tgt_s   = (int*)alloc((size_t)NE * 4);
  int*      cnt     = (int*)alloc((size_t)NN * 4);
  int*      cur     = (int*)alloc((size_t)NN * 4);
  int*      cnt_t   = (int*)alloc((size_t)NN * 4);
  int*      cur_t   = (int*)alloc((size_t)NN * 4);
  int*      bsum    = (int*)alloc((size_t)NBS * 4);
  int*      boff    = (int*)alloc((size_t)256 * 4);
  int*      gstart  = (int*)alloc((size_t)NG * 4);
  int*      gend    = (int*)alloc((size_t)NG * 4);
  float*    gpool   = (float*)alloc((size_t)NG * DD * 4);
  ushort*   qkvT    = (ushort*)alloc((size_t)NL * 3 * DD * DD * 2);
  ushort*   oT      = (ushort*)alloc((size_t)NL * DD * DD * 2);
  ushort*   f1T     = (ushort*)alloc((size_t)NL * DD * 512 * 2);
  ushort*   f2T     = (ushort*)alloc((size_t)NL * 512 * DD * 2);
  (void)in_sizes; (void)n_in; (void)out_size; (void)ws_size;

  // once-per-call setup
  hipMemsetAsync(cnt, 0, NN * 4, stream);
  hipMemsetAsync(cur, 0, NN * 4, stream);
  hipMemsetAsync(cnt_t, 0, NN * 4, stream);
  hipMemsetAsync(cur_t, 0, NN * 4, stream);
  hipMemsetAsync(gstart, 0, NG * 4, stream);
  hipMemsetAsync(gend, 0, NG * 4, stream);
  hipMemsetAsync(gpool, 0, NG * DD * 4, stream);
  // src-CSR (edge sort) and tgt-CSR (incoming-edge lists)
  k_hist<<<(NE + 255) / 256, 256, 0, stream>>>(src, cnt);
  k_scan_blk<<<NBS, 256, 0, stream>>>(cnt, bsum);
  k_scan_top<<<1, 256, 0, stream>>>(bsum, boff, rowstart);
  k_scan_fin<<<NBS, 256, 0, stream>>>(cnt, boff, rowstart);
  k_fill<<<(NE + 255) / 256, 256, 0, stream>>>(src, tgt, rowstart, cur, src_s, tgt_s);
  k_hist<<<(NE + 255) / 256, 256, 0, stream>>>(tgt, cnt_t);
  k_scan_blk<<<NBS, 256, 0, stream>>>(cnt_t, bsum);
  k_scan_top<<<1, 256, 0, stream>>>(bsum, boff, rowstart_t);
  k_scan_fin<<<NBS, 256, 0, stream>>>(cnt_t, boff, rowstart_t);
  k_fill_t<<<(NE + 255) / 256, 256, 0, stream>>>(tgt_s, rowstart_t, cur_t, eid_t);
  k_mbias_par<<<NL * DD, 64, 0, stream>>>(cW2, cb2, bW, bb, Mb, basel);
  k_bp<<<1, 128, 0, stream>>>(cW1, cb1, bpg, posg);
  k_pwl_tab<<<NL * NSEG, 64, 0, stream>>>(cW1, cb1, posg, Mb, basel, slopeg, interg);
  k_bounds<<<(NN + 255) / 256, 256, 0, stream>>>(batch, gstart, gend);
  // bf16-transposed weights
  k_wt<DD, DD><<<(NL * DD * DD + 255) / 256, 256, 0, stream>>>(qW, qkvT,               NL, 3 * DD * DD);
  k_wt<DD, DD><<<(NL * DD * DD + 255) / 256, 256, 0, stream>>>(kW, qkvT + DD * DD,     NL, 3 * DD * DD);
  k_wt<DD, DD><<<(NL * DD * DD + 255) / 256, 256, 0, stream>>>(vW, qkvT + 2 * DD * DD, NL, 3 * DD * DD);
  k_wt<DD, DD><<<(NL * DD * DD + 255) / 256, 256, 0, stream>>>(oW, oT, NL, DD * DD);
  k_wt<DD, 512><<<(NL * DD * 512 + 255) / 256, 256, 0, stream>>>(f1W, f1T, NL, DD * 512);
  k_wt<512, DD><<<(NL * DD * 512 + 255) / 256, 256, 0, stream>>>(f2W, f2T, NL, DD * 512);
  k_node_proj<<<NT32, 256, 0, stream>>>(x, node_W, node_b, h);
  // layer-0 qkv from standalone LN1+QKV
  k_ln_qkv<<<NT32, 512, 0, stream>>>(h, n1s, n1b, qkvT, qb, kb, vb, q, kk, v);

  for (int l = 0; l < NL; l++) {
    k_scores_sm<<<NT4, 256, 0, stream>>>(src_s, rowstart_t, eid_t, q, kk,
        h, dist, bpg,
        slopeg + (size_t)l * NSEG * HH, interg + (size_t)l * NSEG * HH,
        escore);
    k_agg<<<NN / 4, 256, 0, stream>>>(tgt_s, rowstart, escore, v, aggmb);
    int ln = l < NL - 1 ? l + 1 : l;   // next-layer params (unused when do_qkv=0)
    k_attn_ffn<<<NT64, 512, 0, stream>>>(aggmb, oT + (size_t)l * DD * DD, ob + l * DD,
        n2s + l * DD, n2b + l * DD,
        f1T + (size_t)l * DD * 512, f1b + (size_t)l * 4 * DD,
        f2T + (size_t)l * 512 * DD, f2b + l * DD, h,
        (l < NL - 1) ? 1 : 0,
        n1s + ln * DD, n1b + ln * DD,
        qkvT + (size_t)ln * 3 * DD * DD,
        qb + ln * DD, kb + ln * DD, vb + ln * DD,
        q, kk, v);
  }
  k_pool_part<<<(NN + 255) / 256, 256, 0, stream>>>(h, batch, gpool);
  k_head<<<1, 256, 0, stream>>>(gpool, gstart, gend, outW1, outb1, outW2, outb2, (float*)d_out);
}

// Round 21
// 1310.143 us; speedup vs baseline: 1.0179x; 1.0179x over previous
//
#include <hip/hip_runtime.h>

#define NN 50000      // nodes
#define NE 625000     // edges
#define DD 128        // hidden dim
#define HH 8          // heads
#define DHH 16        // head dim
#define NL 4          // layers
#define FIN 64        // in channels
#define NG 64         // graphs
#define LN_EPS 1e-5f
#define NSEG 129      // PWL segments = 128 breakpoints + 1
#define NT32 1563     // ceil(NN/32)
#define NT64 782      // ceil(NN/64)
#define NT4 12500     // NN/4 (nodes per 4-wave block in k_scores_sm)
#define NBS 196       // ceil(NN/256) scan blocks
#define HLP 132       // hL padded row stride (floats): +4 breaks bank conflicts

typedef __bf16 bf16x8_t __attribute__((ext_vector_type(8)));
typedef unsigned short ushort8_t __attribute__((ext_vector_type(8)));
typedef float f32x4_t __attribute__((ext_vector_type(4)));
union BF8 { ushort8_t u; bf16x8_t b; };

// ---------- helpers ----------
__device__ __forceinline__ void fma4(float4& a, float s, float4 w) {
  a.x = fmaf(s, w.x, a.x); a.y = fmaf(s, w.y, a.y);
  a.z = fmaf(s, w.z, a.z); a.w = fmaf(s, w.w, a.w);
}
__device__ __forceinline__ unsigned short f2bf(float f) {   // RNE f32->bf16
  unsigned u = __float_as_uint(f);
  unsigned r = ((u >> 16) & 1u) + 0x7FFFu;
  return (unsigned short)((u + r) >> 16);
}
__device__ __forceinline__ float bf2f(unsigned short u) {
  return __uint_as_float((unsigned)u << 16);
}

// LayerNorm 32 nodes -> swizzled bf16 LDS tile [32][128]; block = 512 threads.
__device__ __forceinline__ void ln_tile_bf32(const float* __restrict__ h, int nb,
                                             const float* __restrict__ sc,
                                             const float* __restrict__ bi,
                                             ushort* xbf) {
  int tid = threadIdx.x;
  int r = tid >> 4, l16 = tid & 15;
  int nr = nb + r; if (nr >= NN) nr = NN - 1;   // clamp: tail rows unused
  const float* hp = h + (size_t)nr * DD + l16 * 8;
  float4 a0 = *(const float4*)hp;
  float4 a1 = *(const float4*)(hp + 4);
  float sum = a0.x + a0.y + a0.z + a0.w + a1.x + a1.y + a1.z + a1.w;
  float sq  = a0.x*a0.x + a0.y*a0.y + a0.z*a0.z + a0.w*a0.w
            + a1.x*a1.x + a1.y*a1.y + a1.z*a1.z + a1.w*a1.w;
#pragma unroll
  for (int off = 8; off >= 1; off >>= 1) {
    sum += __shfl_xor(sum, off, 64);
    sq  += __shfl_xor(sq,  off, 64);
  }
  float mu   = sum * (1.0f / DD);
  float var  = sq * (1.0f / DD) - mu * mu;
  float rstd = rsqrtf(var + LN_EPS);
  int d0 = l16 * 8;
  float4 s0 = *(const float4*)(sc + d0), s1 = *(const float4*)(sc + d0 + 4);
  float4 b0 = *(const float4*)(bi + d0), b1 = *(const float4*)(bi + d0 + 4);
  ushort8_t u;
  u[0] = f2bf((a0.x - mu) * rstd * s0.x + b0.x);
  u[1] = f2bf((a0.y - mu) * rstd * s0.y + b0.y);
  u[2] = f2bf((a0.z - mu) * rstd * s0.z + b0.z);
  u[3] = f2bf((a0.w - mu) * rstd * s0.w + b0.w);
  u[4] = f2bf((a1.x - mu) * rstd * s1.x + b1.x);
  u[5] = f2bf((a1.y - mu) * rstd * s1.y + b1.y);
  u[6] = f2bf((a1.z - mu) * rstd * s1.z + b1.z);
  u[7] = f2bf((a1.w - mu) * rstd * s1.w + b1.w);
  int off = (r * 256 + l16 * 16) ^ ((r & 7) << 4);
  *(ushort8_t*)((char*)xbf + off) = u;
}

// ---------- kernels ----------
// h = x @ node_W + node_b ; 32 nodes/block, W staged in LDS.
__global__ __launch_bounds__(256) void k_node_proj(const float* __restrict__ x,
                                                   const float* __restrict__ W,
                                                   const float* __restrict__ b,
                                                   float* __restrict__ h) {
  __shared__ float Wl[FIN * DD];    // 32 KB
  __shared__ float xt[32][FIN];     // 8 KB
  int tid = threadIdx.x;
  int nb = blockIdx.x * 32;
  for (int i = tid * 4; i < FIN * DD; i += 1024)
    *(float4*)&Wl[i] = *(const float4*)(W + i);
  for (int i = tid * 4; i < 32 * FIN; i += 1024) {
    int row = i >> 6, cc = i & 63;
    int node = nb + row; if (node >= NN) node = NN - 1;
    *(float4*)&xt[row][cc] = *(const float4*)(x + (size_t)node * FIN + cc);
  }
  __syncthreads();
  int c4 = (tid & 31) * 4;
  int r0 = (tid >> 5) * 4;
  float4 bv = *(const float4*)(b + c4);
  float4 a0 = bv, a1 = bv, a2 = bv, a3 = bv;
  for (int k = 0; k < FIN; k++) {
    float4 wv = *(const float4*)&Wl[k * DD + c4];
    fma4(a0, xt[r0][k], wv);
    fma4(a1, xt[r0 + 1][k], wv);
    fma4(a2, xt[r0 + 2][k], wv);
    fma4(a3, xt[r0 + 3][k], wv);
  }
  int n0 = nb + r0;
  if (n0 < NN)     *(float4*)(h + (size_t)n0 * DD + c4) = a0;
  if (n0 + 1 < NN) *(float4*)(h + (size_t)(n0 + 1) * DD + c4) = a1;
  if (n0 + 2 < NN) *(float4*)(h + (size_t)(n0 + 2) * DD + c4) = a2;
  if (n0 + 3 < NN) *(float4*)(h + (size_t)(n0 + 3) * DD + c4) = a3;
}

// per sorted edge: sim (dot), dist (norm) in fp32. r21: 8 lanes/edge (was 16) —
// 64B/lane contiguous per row, 3-level shfl; same bytes, denser vector issue.
// Reassociation of dot/sq (~1e-7) is the class r18-r20 absorbed; self-loop
// dist stays exactly 0.
__global__ __launch_bounds__(256) void k_edge1(const int* __restrict__ src_s, const int* __restrict__ tgt_s,
                                               const float* __restrict__ h, float* __restrict__ sim,
                                               float* __restrict__ dist) {
  int gid = blockIdx.x * 256 + threadIdx.x;
  int e = gid >> 3;
  if (e >= NE) return;
  int j = gid & 7;
  int s = src_s[e], t = tgt_s[e];
  const float4* ap = (const float4*)(h + (size_t)s * DD + j * 16);
  const float4* bp = (const float4*)(h + (size_t)t * DD + j * 16);
  float4 a0 = ap[0], a1 = ap[1], a2 = ap[2], a3 = ap[3];
  float4 b0 = bp[0], b1 = bp[1], b2 = bp[2], b3 = bp[3];
  float dot = 0.f, sq = 0.f;
  dot = fmaf(a0.x, b0.x, dot); dot = fmaf(a0.y, b0.y, dot);
  dot = fmaf(a0.z, b0.z, dot); dot = fmaf(a0.w, b0.w, dot);
  dot = fmaf(a1.x, b1.x, dot); dot = fmaf(a1.y, b1.y, dot);
  dot = fmaf(a1.z, b1.z, dot); dot = fmaf(a1.w, b1.w, dot);
  dot = fmaf(a2.x, b2.x, dot); dot = fmaf(a2.y, b2.y, dot);
  dot = fmaf(a2.z, b2.z, dot); dot = fmaf(a2.w, b2.w, dot);
  dot = fmaf(a3.x, b3.x, dot); dot = fmaf(a3.y, b3.y, dot);
  dot = fmaf(a3.z, b3.z, dot); dot = fmaf(a3.w, b3.w, dot);
  float d;
  d = a0.x - b0.x; sq = fmaf(d, d, sq); d = a0.y - b0.y; sq = fmaf(d, d, sq);
  d = a0.z - b0.z; sq = fmaf(d, d, sq); d = a0.w - b0.w; sq = fmaf(d, d, sq);
  d = a1.x - b1.x; sq = fmaf(d, d, sq); d = a1.y - b1.y; sq = fmaf(d, d, sq);
  d = a1.z - b1.z; sq = fmaf(d, d, sq); d = a1.w - b1.w; sq = fmaf(d, d, sq);
  d = a2.x - b2.x; sq = fmaf(d, d, sq); d = a2.y - b2.y; sq = fmaf(d, d, sq);
  d = a2.z - b2.z; sq = fmaf(d, d, sq); d = a2.w - b2.w; sq = fmaf(d, d, sq);
  d = a3.x - b3.x; sq = fmaf(d, d, sq); d = a3.y - b3.y; sq = fmaf(d, d, sq);
  d = a3.z - b3.z; sq = fmaf(d, d, sq); d = a3.w - b3.w; sq = fmaf(d, d, sq);
#pragma unroll
  for (int off = 4; off >= 1; off >>= 1) {
    dot += __shfl_xor(dot, off, 64);
    sq  += __shfl_xor(sq,  off, 64);
  }
  if (j == 0) {
    sim[e]  = dot;                  // BETA == 1.0
    dist[e] = sqrtf(sq);
  }
}

// LN1 + QKV projection via swapped-operand MFMA -> bf16 q/k/v. 32 rows/block, 8 waves.
// Used only for layer 0 (layers 1..3 get qkv from k_attn_ffn stage 5).
__global__ __launch_bounds__(512) void k_ln_qkv(const float* __restrict__ h,
    const float* __restrict__ n1s_l, const float* __restrict__ n1b_l,
    const ushort* __restrict__ qkvT_l,
    const float* __restrict__ qb_l, const float* __restrict__ kb_l, const float* __restrict__ vb_l,
    ushort* __restrict__ q, ushort* __restrict__ kk, ushort* __restrict__ v) {
  __shared__ __align__(16) ushort xbf[32 * DD];
  int nb = blockIdx.x * 32;
  ln_tile_bf32(h, nb, n1s_l, n1b_l, xbf);
  __syncthreads();
  int lane = threadIdx.x & 63;
  int w = threadIdx.x >> 6;
  int g = lane >> 4, c = lane & 15;
  int xr = (c & 7) << 4;
  char* xb = (char*)xbf;
  BF8 a[2][4];
#pragma unroll
  for (int nt = 0; nt < 2; nt++)
#pragma unroll
    for (int kt = 0; kt < 4; kt++)
      a[nt][kt].u = *(ushort8_t*)(xb + (((nt * 16 + c) * 256 + kt * 64 + g * 16) ^ xr));
#pragma unroll
  for (int ti = 0; ti < 3; ti++) {
    int t = w * 3 + ti;                // 0..23
    int m = t >> 3;                    // 0=q 1=k 2=v
    int colb = (t & 7) * 16;
    const float* bias = (m == 0 ? qb_l : (m == 1 ? kb_l : vb_l));
    float4 bv = *(const float4*)(bias + colb + g * 4);
    f32x4_t acc0 = {bv.x, bv.y, bv.z, bv.w};
    f32x4_t acc1 = acc0;
    const ushort* wp = qkvT_l + (size_t)(m * DD + colb + c) * DD + g * 8;
#pragma unroll
    for (int kt = 0; kt < 4; kt++) {
      BF8 b; b.u = *(const ushort8_t*)(wp + kt * 32);
      acc0 = __builtin_amdgcn_mfma_f32_16x16x32_bf16(b.b, a[0][kt].b, acc0, 0, 0, 0);
      acc1 = __builtin_amdgcn_mfma_f32_16x16x32_bf16(b.b, a[1][kt].b, acc1, 0, 0, 0);
    }
    ushort* out = (m == 0 ? q : (m == 1 ? kk : v));
    int n0 = nb + c;
    if (n0 < NN) {
      ushort4 o; o.x = f2bf(acc0[0]); o.y = f2bf(acc0[1]); o.z = f2bf(acc0[2]); o.w = f2bf(acc0[3]);
      *(ushort4*)(out + (size_t)n0 * DD + colb + g * 4) = o;
    }
    int n1 = nb + 16 + c;
    if (n1 < NN) {
      ushort4 o; o.x = f2bf(acc1[0]); o.y = f2bf(acc1[1]); o.z = f2bf(acc1[2]); o.w = f2bf(acc1[3]);
      *(ushort4*)(out + (size_t)n1 * DD + colb + g * 4) = o;
    }
  }
}

// FUSED curvature + scores + softmax, 64 lanes/node.
// Phase A (all 64 lanes): aggv from sim/dist via stride-64 gathers + shfl trees.
// Phase B (8 heads x 8 edge lanes): raw scores -> escore + online (m,sum).
// Phase C: shfl combine over edge-lane groups.
// Phase D: each lane rewrites ITS OWN raw scores as p = expf(sc-m)*inv.
// Max subtraction stays MANDATORY (r5/r6 lesson).
__global__ __launch_bounds__(256) void k_scores_sm(const int* __restrict__ src_s,
    const int* __restrict__ rowstart_t, const int* __restrict__ eid_t,
    const ushort* __restrict__ q, const ushort* __restrict__ k,
    const float* __restrict__ sim, const float* __restrict__ dist,
    const float* __restrict__ bp_g,
    const float* __restrict__ slope_l, const float* __restrict__ inter_l,
    float* __restrict__ escore) {
  __shared__ float lsl[NSEG * HH], lin[NSEG * HH], bp[DD];
  int tid = threadIdx.x;
  for (int idx = tid; idx < NSEG * HH; idx += 256) { lsl[idx] = slope_l[idx]; lin[idx] = inter_l[idx]; }
  if (tid < DD) bp[tid] = bp_g[tid];
  __syncthreads();
  int node = blockIdx.x * 4 + (tid >> 6);
  if (node >= NN) return;
  int lane = tid & 63;
  int rs = rowstart_t[node], re = rowstart_t[node + 1];
  // ---- Phase A: aggv (all 64 lanes)
  float msim = -3.4e38f;
  for (int i = rs + lane; i < re; i += 64) msim = fmaxf(msim, sim[eid_t[i]]);
#pragma unroll
  for (int off = 1; off <= 32; off <<= 1) msim = fmaxf(msim, __shfl_xor(msim, off, 64));
  float den = 0.f, nd = 0.f;
  for (int i = rs + lane; i < re; i += 64) {
    int e = eid_t[i];
    float ev = expf(sim[e] - msim);
    den += ev;
    nd = fmaf(ev, dist[e], nd);
  }
#pragma unroll
  for (int off = 1; off <= 32; off <<= 1) {
    den += __shfl_xor(den, off, 64);
    nd  += __shfl_xor(nd,  off, 64);
  }
  float av = den > 0.f ? nd / den : 0.f;
  // ---- Phase B: raw scores + online (m, sum)
  int hh = lane & 7;
  int eidx = lane >> 3;
  const ushort8_t* kp = (const ushort8_t*)(k + (size_t)node * DD + hh * DHH);
  ushort8_t k0 = kp[0], k1 = kp[1];
  float m = -3.4e38f, ssum = 0.f;
  for (int i = rs + eidx; i < re; i += 8) {
    int e = eid_t[i];
    int s = src_s[e];
    float dd = dist[e];
    const ushort8_t* qp = (const ushort8_t*)(q + (size_t)s * DD + hh * DHH);
    ushort8_t q0 = qp[0], q1 = qp[1];
    float curv = 1.0f - av / fmaxf(dd, 1e-6f);
    int lo = 0, hi = DD;
    while (lo < hi) { int mid = (lo + hi) >> 1; if (bp[mid] < curv) lo = mid + 1; else hi = mid; }
    float bias = fmaf(lsl[lo * HH + hh], curv, lin[lo * HH + hh]);
    float dot = 0.f;
#pragma unroll
    for (int jj = 0; jj < 8; jj++) dot = fmaf(bf2f(q0[jj]), bf2f(k0[jj]), dot);
#pragma unroll
    for (int jj = 0; jj < 8; jj++) dot = fmaf(bf2f(q1[jj]), bf2f(k1[jj]), dot);
    float sc = dot * 0.25f + bias;   // 1/sqrt(16)
    escore[e * HH + hh] = sc;
    float mn = fmaxf(m, sc);
    ssum = ssum * expf(m - mn) + expf(sc - mn);
    m = mn;
  }
  // ---- Phase C: combine (m, s) across the 8 edge-lane groups
#pragma unroll
  for (int off = 8; off <= 32; off <<= 1) {
    float m2 = __shfl_xor(m, off, 64);
    float s2 = __shfl_xor(ssum, off, 64);
    float M = fmaxf(m, m2);
    ssum = ssum * expf(m - M) + s2 * expf(m2 - M);
    m = M;
  }
  float inv = ssum > 0.f ? 1.0f / ssum : 0.f;
  // ---- Phase D: rewrite own raw scores as final probabilities
  for (int i = rs + eidx; i < re; i += 8) {
    size_t idx = (size_t)eid_t[i] * HH + hh;
    float sc = escore[idx];
    escore[idx] = expf(sc - m) * inv;
  }
}

// CSR-gather message aggregation: one wave per src node, 2 dims/lane -> bf16 out.
// escore holds final probabilities (computed in k_scores_sm phase D).
__global__ __launch_bounds__(256) void k_agg(const int* __restrict__ tgt_s,
    const int* __restrict__ rowstart,
    const float* __restrict__ escore,
    const ushort* __restrict__ v, ushort* __restrict__ aggmb) {
  int wave = (blockIdx.x * 256 + threadIdx.x) >> 6;
  int lane = threadIdx.x & 63;
  int rs = rowstart[wave], re = rowstart[wave + 1];
  int hh = lane >> 3;
  int d = lane * 2;
  float a0 = 0.f, a1 = 0.f;
  int i = rs;
  for (; i + 4 <= re; i += 4) {
    int t0 = tgt_s[i], t1 = tgt_s[i + 1], t2 = tgt_s[i + 2], t3 = tgt_s[i + 3];
    float p0 = escore[(i    ) * HH + hh];
    float p1 = escore[(i + 1) * HH + hh];
    float p2 = escore[(i + 2) * HH + hh];
    float p3 = escore[(i + 3) * HH + hh];
    ushort2 v0 = *(const ushort2*)(v + (size_t)t0 * DD + d);
    ushort2 v1 = *(const ushort2*)(v + (size_t)t1 * DD + d);
    ushort2 v2 = *(const ushort2*)(v + (size_t)t2 * DD + d);
    ushort2 v3 = *(const ushort2*)(v + (size_t)t3 * DD + d);
    a0 = fmaf(p0, bf2f(v0.x), a0); a1 = fmaf(p0, bf2f(v0.y), a1);
    a0 = fmaf(p1, bf2f(v1.x), a0); a1 = fmaf(p1, bf2f(v1.y), a1);
    a0 = fmaf(p2, bf2f(v2.x), a0); a1 = fmaf(p2, bf2f(v2.y), a1);
    a0 = fmaf(p3, bf2f(v3.x), a0); a1 = fmaf(p3, bf2f(v3.y), a1);
  }
  for (; i < re; i++) {
    int t = tgt_s[i];
    float prob = escore[i * HH + hh];
    ushort2 vv = *(const ushort2*)(v + (size_t)t * DD + d);
    a0 = fmaf(prob, bf2f(vv.x), a0);
    a1 = fmaf(prob, bf2f(vv.y), a1);
  }
  ushort2 o; o.x = f2bf(a0); o.y = f2bf(a1);
  *(ushort2*)(aggmb + (size_t)wave * DD + d) = o;
}

// FUSED: h' = h + aggm@oW + ob (LDS hL) -> LN2 -> FFN -> h = h' + FFN out,
// then (stage 5, if do_qkv) LN1(next layer) + QKV projection.
__global__ __launch_bounds__(512) void k_attn_ffn(const ushort* __restrict__ aggmb,
    const ushort* __restrict__ oT_l, const float* __restrict__ ob_l,
    const float* __restrict__ n2s_l, const float* __restrict__ n2b_l,
    const ushort* __restrict__ f1T_l, const float* __restrict__ f1b_l,
    const ushort* __restrict__ f2T_l, const float* __restrict__ f2b_l,
    float* __restrict__ h,
    int do_qkv,
    const float* __restrict__ n1s_n, const float* __restrict__ n1b_n,
    const ushort* __restrict__ qkvT_n,
    const float* __restrict__ qb_n, const float* __restrict__ kb_n, const float* __restrict__ vb_n,
    ushort* __restrict__ q, ushort* __restrict__ kk, ushort* __restrict__ v) {
  __shared__ float hL[64 * HLP];                      // 33 KB
  __shared__ __align__(16) char ubuf[64 * 128 * 2];   // 16 KB union: xbf / tbf / xbf(qkv)
  char* xb = ubuf;
  char* tb = ubuf;
  int nb = blockIdx.x * 64;
  int tid = threadIdx.x;
  int lane = tid & 63, w = tid >> 6;
  int g = lane >> 4, c = lane & 15;
  int colb = w * 16;
  int xr = (c & 7) << 4;
  // ---- Stage 1: O-projection + residual -> hL
  {
    float4 obv = *(const float4*)(ob_l + colb + g * 4);
    const ushort* wp = oT_l + (size_t)(colb + c) * DD + g * 8;
    BF8 b0, b1, b2, b3;
    b0.u = *(const ushort8_t*)(wp);
    b1.u = *(const ushort8_t*)(wp + 32);
    b2.u = *(const ushort8_t*)(wp + 64);
    b3.u = *(const ushort8_t*)(wp + 96);
#pragma unroll
    for (int nt = 0; nt < 4; nt++) {
      int node = nb + nt * 16 + c;
      int na = node < NN ? node : NN - 1;
      const ushort* ap = aggmb + (size_t)na * DD + g * 8;
      BF8 a0, a1, a2, a3;
      a0.u = *(const ushort8_t*)(ap);
      a1.u = *(const ushort8_t*)(ap + 32);
      a2.u = *(const ushort8_t*)(ap + 64);
      a3.u = *(const ushort8_t*)(ap + 96);
      f32x4_t acc = {obv.x, obv.y, obv.z, obv.w};
      acc = __builtin_amdgcn_mfma_f32_16x16x32_bf16(b0.b, a0.b, acc, 0, 0, 0);
      acc = __builtin_amdgcn_mfma_f32_16x16x32_bf16(b1.b, a1.b, acc, 0, 0, 0);
      acc = __builtin_amdgcn_mfma_f32_16x16x32_bf16(b2.b, a2.b, acc, 0, 0, 0);
      acc = __builtin_amdgcn_mfma_f32_16x16x32_bf16(b3.b, a3.b, acc, 0, 0, 0);
      float4 hv = *(const float4*)(h + (size_t)na * DD + colb + g * 4);
      hv.x += acc[0]; hv.y += acc[1]; hv.z += acc[2]; hv.w += acc[3];
      *(float4*)&hL[(nt * 16 + c) * HLP + colb + g * 4] = hv;
    }
  }
  __syncthreads();
  // ---- Stage 2: LN2 from hL -> xbf
  {
    int l16 = tid & 15;
    int d0 = l16 * 8;
    float4 s0 = *(const float4*)(n2s_l + d0), s1 = *(const float4*)(n2s_l + d0 + 4);
    float4 bb0 = *(const float4*)(n2b_l + d0), bb1 = *(const float4*)(n2b_l + d0 + 4);
#pragma unroll
    for (int p = 0; p < 2; p++) {
      int r = p * 32 + (tid >> 4);
      const float* hp = &hL[r * HLP + d0];
      float4 a0 = *(const float4*)hp;
      float4 a1 = *(const float4*)(hp + 4);
      float sum = a0.x + a0.y + a0.z + a0.w + a1.x + a1.y + a1.z + a1.w;
      float sq  = a0.x*a0.x + a0.y*a0.y + a0.z*a0.z + a0.w*a0.w
                + a1.x*a1.x + a1.y*a1.y + a1.z*a1.z + a1.w*a1.w;
#pragma unroll
      for (int off = 8; off >= 1; off >>= 1) {
        sum += __shfl_xor(sum, off, 64);
        sq  += __shfl_xor(sq,  off, 64);
      }
      float mu   = sum * (1.0f / DD);
      float var  = sq * (1.0f / DD) - mu * mu;
      float rstd = rsqrtf(var + LN_EPS);
      ushort8_t u;
      u[0] = f2bf((a0.x - mu) * rstd * s0.x + bb0.x);
      u[1] = f2bf((a0.y - mu) * rstd * s0.y + bb0.y);
      u[2] = f2bf((a0.z - mu) * rstd * s0.z + bb0.z);
      u[3] = f2bf((a0.w - mu) * rstd * s0.w + bb0.w);
      u[4] = f2bf((a1.x - mu) * rstd * s1.x + bb1.x);
      u[5] = f2bf((a1.y - mu) * rstd * s1.y + bb1.y);
      u[6] = f2bf((a1.z - mu) * rstd * s1.z + bb1.z);
      u[7] = f2bf((a1.w - mu) * rstd * s1.w + bb1.w);
      int off = (r * 256 + l16 * 16) ^ ((r & 7) << 4);
      *(ushort8_t*)(xb + off) = u;
    }
  }
  __syncthreads();
  // A-frags from xbf (registers)
  BF8 a[4][4];
#pragma unroll
  for (int nt = 0; nt < 4; nt++)
#pragma unroll
    for (int kt = 0; kt < 4; kt++)
      a[nt][kt].u = *(ushort8_t*)(xb + (((nt * 16 + c) * 256 + kt * 64 + g * 16) ^ xr));
  __syncthreads();   // xbf dead; ubuf becomes tbf
  // ---- Stage 3: FFN, 4 chunks of 128 cols (tbf row stride 256B)
  float4 bv2 = *(const float4*)(f2b_l + colb + g * 4);
  f32x4_t o0 = {bv2.x, bv2.y, bv2.z, bv2.w};
  f32x4_t o1 = o0, o2 = o0, o3 = o0;
#pragma unroll
  for (int ch = 0; ch < 4; ch++) {
    if (ch) __syncthreads();           // tbf reuse: wait for prev-chunk reads
    {
      int col = ch * 128 + w * 16;
      float4 bv = *(const float4*)(f1b_l + col + g * 4);
      f32x4_t ac0 = {bv.x, bv.y, bv.z, bv.w};
      f32x4_t ac1 = ac0, ac2 = ac0, ac3 = ac0;
      const ushort* wp = f1T_l + (size_t)(col + c) * DD + g * 8;
#pragma unroll
      for (int kt = 0; kt < 4; kt++) {
        BF8 b; b.u = *(const ushort8_t*)(wp + kt * 32);
        ac0 = __builtin_amdgcn_mfma_f32_16x16x32_bf16(b.b, a[0][kt].b, ac0, 0, 0, 0);
        ac1 = __builtin_amdgcn_mfma_f32_16x16x32_bf16(b.b, a[1][kt].b, ac1, 0, 0, 0);
        ac2 = __builtin_amdgcn_mfma_f32_16x16x32_bf16(b.b, a[2][kt].b, ac2, 0, 0, 0);
        ac3 = __builtin_amdgcn_mfma_f32_16x16x32_bf16(b.b, a[3][kt].b, ac3, 0, 0, 0);
      }
      int colL = (w * 16 + g * 4) * 2;
      {
        int row = c;
        ushort4 o4; o4.x = f2bf(fmaxf(ac0[0], 0.f)); o4.y = f2bf(fmaxf(ac0[1], 0.f));
        o4.z = f2bf(fmaxf(ac0[2], 0.f)); o4.w = f2bf(fmaxf(ac0[3], 0.f));
        *(ushort4*)(tb + ((row * 256 + colL) ^ ((row & 7) << 4))) = o4;
      }
      {
        int row = 16 + c;
        ushort4 o4; o4.x = f2bf(fmaxf(ac1[0], 0.f)); o4.y = f2bf(fmaxf(ac1[1], 0.f));
        o4.z = f2bf(fmaxf(ac1[2], 0.f)); o4.w = f2bf(fmaxf(ac1[3], 0.f));
        *(ushort4*)(tb + ((row * 256 + colL) ^ ((row & 7) << 4))) = o4;
      }
      {
        int row = 32 + c;
        ushort4 o4; o4.x = f2bf(fmaxf(ac2[0], 0.f)); o4.y = f2bf(fmaxf(ac2[1], 0.f));
        o4.z = f2bf(fmaxf(ac2[2], 0.f)); o4.w = f2bf(fmaxf(ac2[3], 0.f));
        *(ushort4*)(tb + ((row * 256 + colL) ^ ((row & 7) << 4))) = o4;
      }
      {
        int row = 48 + c;
        ushort4 o4; o4.x = f2bf(fmaxf(ac3[0], 0.f)); o4.y = f2bf(fmaxf(ac3[1], 0.f));
        o4.z = f2bf(fmaxf(ac3[2], 0.f)); o4.w = f2bf(fmaxf(ac3[3], 0.f));
        *(ushort4*)(tb + ((row * 256 + colL) ^ ((row & 7) << 4))) = o4;
      }
    }
    __syncthreads();
    const ushort* wp2 = f2T_l + (size_t)(colb + c) * 512 + ch * 128 + g * 8;
#pragma unroll
    for (int kt = 0; kt < 4; kt++) {
      BF8 b; b.u = *(const ushort8_t*)(wp2 + kt * 32);
      BF8 t0; t0.u = *(ushort8_t*)(tb + (((c) * 256 + kt * 64 + g * 16) ^ xr));
      BF8 t1; t1.u = *(ushort8_t*)(tb + (((16 + c) * 256 + kt * 64 + g * 16) ^ xr));
      BF8 t2; t2.u = *(ushort8_t*)(tb + (((32 + c) * 256 + kt * 64 + g * 16) ^ xr));
      BF8 t3; t3.u = *(ushort8_t*)(tb + (((48 + c) * 256 + kt * 64 + g * 16) ^ xr));
      o0 = __builtin_amdgcn_mfma_f32_16x16x32_bf16(b.b, t0.b, o0, 0, 0, 0);
      o1 = __builtin_amdgcn_mfma_f32_16x16x32_bf16(b.b, t1.b, o1, 0, 0, 0);
      o2 = __builtin_amdgcn_mfma_f32_16x16x32_bf16(b.b, t2.b, o2, 0, 0, 0);
      o3 = __builtin_amdgcn_mfma_f32_16x16x32_bf16(b.b, t3.b, o3, 0, 0, 0);
    }
  }
  // ---- Stage 4: final residual from hL -> global h (and back into hL for stage 5)
  {
    float* lp = &hL[c * HLP + colb + g * 4];
    float4 hv = *(const float4*)lp;
    hv.x += o0[0]; hv.y += o0[1]; hv.z += o0[2]; hv.w += o0[3];
    *(float4*)lp = hv;
    int node = nb + c;
    if (node < NN) *(float4*)(h + (size_t)node * DD + colb + g * 4) = hv;
  }
  {
    float* lp = &hL[(16 + c) * HLP + colb + g * 4];
    float4 hv = *(const float4*)lp;
    hv.x += o1[0]; hv.y += o1[1]; hv.z += o1[2]; hv.w += o1[3];
    *(float4*)lp = hv;
    int node = nb + 16 + c;
    if (node < NN) *(float4*)(h + (size_t)node * DD + colb + g * 4) = hv;
  }
  {
    float* lp = &hL[(32 + c) * HLP + colb + g * 4];
    float4 hv = *(const float4*)lp;
    hv.x += o2[0]; hv.y += o2[1]; hv.z += o2[2]; hv.w += o2[3];
    *(float4*)lp = hv;
    int node = nb + 32 + c;
    if (node < NN) *(float4*)(h + (size_t)node * DD + colb + g * 4) = hv;
  }
  {
    float* lp = &hL[(48 + c) * HLP + colb + g * 4];
    float4 hv = *(const float4*)lp;
    hv.x += o3[0]; hv.y += o3[1]; hv.z += o3[2]; hv.w += o3[3];
    *(float4*)lp = hv;
    int node = nb + 48 + c;
    if (node < NN) *(float4*)(h + (size_t)node * DD + colb + g * 4) = hv;
  }
  if (!do_qkv) return;
  __syncthreads();   // hL final visible; tbf reads done -> ubuf becomes xbf again
  // ---- Stage 5: LN1(next layer) from hL -> xbf
  {
    int l16 = tid & 15;
    int d0 = l16 * 8;
    float4 s0 = *(const float4*)(n1s_n + d0), s1 = *(const float4*)(n1s_n + d0 + 4);
    float4 bb0 = *(const float4*)(n1b_n + d0), bb1 = *(const float4*)(n1b_n + d0 + 4);
#pragma unroll
    for (int p = 0; p < 2; p++) {
      int r = p * 32 + (tid >> 4);
      const float* hp = &hL[r * HLP + d0];
      float4 a0 = *(const float4*)hp;
      float4 a1 = *(const float4*)(hp + 4);
      float sum = a0.x + a0.y + a0.z + a0.w + a1.x + a1.y + a1.z + a1.w;
      float sq  = a0.x*a0.x + a0.y*a0.y + a0.z*a0.z + a0.w*a0.w
                + a1.x*a1.x + a1.y*a1.y + a1.z*a1.z + a1.w*a1.w;
#pragma unroll
      for (int off = 8; off >= 1; off >>= 1) {
        sum += __shfl_xor(sum, off, 64);
        sq  += __shfl_xor(sq,  off, 64);
      }
      float mu   = sum * (1.0f / DD);
      float var  = sq * (1.0f / DD) - mu * mu;
      float rstd = rsqrtf(var + LN_EPS);
      ushort8_t u;
      u[0] = f2bf((a0.x - mu) * rstd * s0.x + bb0.x);
      u[1] = f2bf((a0.y - mu) * rstd * s0.y + bb0.y);
      u[2] = f2bf((a0.z - mu) * rstd * s0.z + bb0.z);
      u[3] = f2bf((a0.w - mu) * rstd * s0.w + bb0.w);
      u[4] = f2bf((a1.x - mu) * rstd * s1.x + bb1.x);
      u[5] = f2bf((a1.y - mu) * rstd * s1.y + bb1.y);
      u[6] = f2bf((a1.z - mu) * rstd * s1.z + bb1.z);
      u[7] = f2bf((a1.w - mu) * rstd * s1.w + bb1.w);
      int off = (r * 256 + l16 * 16) ^ ((r & 7) << 4);
      *(ushort8_t*)(xb + off) = u;
    }
  }
  __syncthreads();
  BF8 aq[4][4];
#pragma unroll
  for (int nt = 0; nt < 4; nt++)
#pragma unroll
    for (int kt = 0; kt < 4; kt++)
      aq[nt][kt].u = *(ushort8_t*)(xb + (((nt * 16 + c) * 256 + kt * 64 + g * 16) ^ xr));
#pragma unroll
  for (int ti = 0; ti < 3; ti++) {
    int t = w * 3 + ti;                // 0..23
    int m = t >> 3;                    // 0=q 1=k 2=v
    int colq = (t & 7) * 16;
    const float* bias = (m == 0 ? qb_n : (m == 1 ? kb_n : vb_n));
    float4 bv = *(const float4*)(bias + colq + g * 4);
    f32x4_t ac0 = {bv.x, bv.y, bv.z, bv.w};
    f32x4_t ac1 = ac0, ac2 = ac0, ac3 = ac0;
    const ushort* wp = qkvT_n + (size_t)(m * DD + colq + c) * DD + g * 8;
#pragma unroll
    for (int kt = 0; kt < 4; kt++) {
      BF8 b; b.u = *(const ushort8_t*)(wp + kt * 32);
      ac0 = __builtin_amdgcn_mfma_f32_16x16x32_bf16(b.b, aq[0][kt].b, ac0, 0, 0, 0);
      ac1 = __builtin_amdgcn_mfma_f32_16x16x32_bf16(b.b, aq[1][kt].b, ac1, 0, 0, 0);
      ac2 = __builtin_amdgcn_mfma_f32_16x16x32_bf16(b.b, aq[2][kt].b, ac2, 0, 0, 0);
      ac3 = __builtin_amdgcn_mfma_f32_16x16x32_bf16(b.b, aq[3][kt].b, ac3, 0, 0, 0);
    }
    ushort* out = (m == 0 ? q : (m == 1 ? kk : v));
    {
      int node = nb + c;
      if (node < NN) {
        ushort4 o; o.x = f2bf(ac0[0]); o.y = f2bf(ac0[1]); o.z = f2bf(ac0[2]); o.w = f2bf(ac0[3]);
        *(ushort4*)(out + (size_t)node * DD + colq + g * 4) = o;
      }
    }
    {
      int node = nb + 16 + c;
      if (node < NN) {
        ushort4 o; o.x = f2bf(ac1[0]); o.y = f2bf(ac1[1]); o.z = f2bf(ac1[2]); o.w = f2bf(ac1[3]);
        *(ushort4*)(out + (size_t)node * DD + colq + g * 4) = o;
      }
    }
    {
      int node = nb + 32 + c;
      if (node < NN) {
        ushort4 o; o.x = f2bf(ac2[0]); o.y = f2bf(ac2[1]); o.z = f2bf(ac2[2]); o.w = f2bf(ac2[3]);
        *(ushort4*)(out + (size_t)node * DD + colq + g * 4) = o;
      }
    }
    {
      int node = nb + 48 + c;
      if (node < NN) {
        ushort4 o; o.x = f2bf(ac3[0]); o.y = f2bf(ac3[1]); o.z = f2bf(ac3[2]); o.w = f2bf(ac3[3]);
        *(ushort4*)(out + (size_t)node * DD + colq + g * 4) = o;
      }
    }
  }
}

// ---------- once-per-call setup kernels ----------
template <int K, int C>
__global__ void k_wt(const float* __restrict__ W, ushort* __restrict__ WT, int nm, int dstride) {
  int idx = blockIdx.x * 256 + threadIdx.x;
  if (idx >= K * C * nm) return;
  int mi = idx / (K * C), rem = idx - mi * (K * C);
  int cc = rem / K, kk2 = rem - cc * K;
  WT[(size_t)mi * dstride + cc * K + kk2] = f2bf(W[(size_t)mi * K * C + (size_t)kk2 * C + cc]);
}

__global__ void k_hist(const int* __restrict__ idxs, int* __restrict__ cnt) {
  int e = blockIdx.x * 256 + threadIdx.x;
  if (e < NE) atomicAdd(cnt + idxs[e], 1);
}

__global__ __launch_bounds__(256) void k_scan_blk(const int* __restrict__ cnt, int* __restrict__ bsum) {
  __shared__ int red[256];
  int tid = threadIdx.x;
  int idx = blockIdx.x * 256 + tid;
  red[tid] = (idx < NN) ? cnt[idx] : 0;
  __syncthreads();
  for (int off = 128; off >= 1; off >>= 1) {
    if (tid < off) red[tid] += red[tid + off];
    __syncthreads();
  }
  if (tid == 0) bsum[blockIdx.x] = red[0];
}

__global__ __launch_bounds__(256) void k_scan_top(const int* __restrict__ bsum,
                                                  int* __restrict__ boff, int* __restrict__ rowstart) {
  __shared__ int ps[256];
  int t = threadIdx.x;
  int v = (t < NBS) ? bsum[t] : 0;
  ps[t] = v;
  __syncthreads();
  for (int off = 1; off < 256; off <<= 1) {
    int x = (t >= off) ? ps[t - off] : 0;
    __syncthreads();
    ps[t] += x;
    __syncthreads();
  }
  boff[t] = ps[t] - v;                 // exclusive prefix of block sums
  if (t == 255) rowstart[NN] = ps[255];
}

__global__ __launch_bounds__(256) void k_scan_fin(const int* __restrict__ cnt,
                                                  const int* __restrict__ boff, int* __restrict__ rowstart) {
  __shared__ int ps[256];
  int t = threadIdx.x;
  int idx = blockIdx.x * 256 + t;
  int v = (idx < NN) ? cnt[idx] : 0;
  ps[t] = v;
  __syncthreads();
  for (int off = 1; off < 256; off <<= 1) {
    int x = (t >= off) ? ps[t - off] : 0;
    __syncthreads();
    ps[t] += x;
    __syncthreads();
  }
  if (idx < NN) rowstart[idx] = boff[blockIdx.x] + ps[t] - v;
}

__global__ void k_fill(const int* __restrict__ src, const int* __restrict__ tgt,
                       const int* __restrict__ rowstart,
                       int* __restrict__ cur, int* __restrict__ src_s, int* __restrict__ tgt_s) {
  int e = blockIdx.x * 256 + threadIdx.x;
  if (e >= NE) return;
  int s = src[e];
  int p = atomicAdd(cur + s, 1);
  int pos = rowstart[s] + p;
  src_s[pos] = s;
  tgt_s[pos] = tgt[e];
}

__global__ void k_fill_t(const int* __restrict__ tgt_s, const int* __restrict__ rowstart_t,
                         int* __restrict__ cur_t, int* __restrict__ eid_t) {
  int i = blockIdx.x * 256 + threadIdx.x;
  if (i >= NE) return;
  int t = tgt_s[i];
  int p = atomicAdd(cur_t + t, 1);
  eid_t[rowstart_t[t] + p] = i;
}

__global__ __launch_bounds__(64) void k_mbias_par(const float* __restrict__ cW2, const float* __restrict__ cb2,
                                                  const float* __restrict__ bW, const float* __restrict__ bb,
                                                  float* __restrict__ M, float* __restrict__ base) {
  int bid = blockIdx.x;
  int l = bid >> 7, d = bid & 127;
  int lane = threadIdx.x;
  int hh = lane >> 3, j0 = lane & 7;
  const float* bWl = bW + (size_t)l * DD * HH;
  float acc = 0.f;
#pragma unroll
  for (int t = 0; t < 16; t++) {
    int k = j0 + t * 8;
    acc = fmaf(cW2[d * DD + k], bWl[k * HH + hh], acc);
  }
#pragma unroll
  for (int off = 1; off <= 4; off <<= 1) acc += __shfl_xor(acc, off, 64);
  if (j0 == 0) M[(size_t)l * DD * HH + d * HH + hh] = acc;
  if (d == 0) {
    float bacc = 0.f;
#pragma unroll
    for (int t = 0; t < 16; t++) {
      int k = j0 + t * 8;
      bacc = fmaf(cb2[k], bWl[k * HH + hh], bacc);
    }
#pragma unroll
    for (int off = 1; off <= 4; off <<= 1) bacc += __shfl_xor(bacc, off, 64);
    if (j0 == 0) base[l * HH + hh] = bacc + bb[l * HH + hh];
  }
}

__global__ __launch_bounds__(128) void k_bp(const float* __restrict__ cW1, const float* __restrict__ cb1,
                                            float* __restrict__ bpg, int* __restrict__ posg) {
  __shared__ float x[DD], bp[DD];
  int tid = threadIdx.x;
  float c1v = cW1[tid], cbv = cb1[tid];
  x[tid] = (c1v == 0.f) ? __builtin_inff() : (-cbv / c1v);
  __syncthreads();
  float xv = x[tid]; int p = 0;
  for (int j = 0; j < DD; j++) {
    float xj = x[j];
    if (xj < xv || (xj == xv && j < tid)) p++;
  }
  bp[p] = xv;
  posg[tid] = p;
  __syncthreads();
  bpg[tid] = bp[tid];
}

__global__ __launch_bounds__(64) void k_pwl_tab(const float* __restrict__ cW1, const float* __restrict__ cb1,
    const int* __restrict__ posg, const float* __restrict__ Mb, const float* __restrict__ basel,
    float* __restrict__ slopeg, float* __restrict__ interg) {
  int bid = blockIdx.x;
  int l = bid / NSEG, s = bid - l * NSEG;
  int lane = threadIdx.x;
  int hh = lane >> 3, j0 = lane & 7;
  const float* M = Mb + (size_t)l * DD * HH;
  float sl = 0.f, in = 0.f;
#pragma unroll
  for (int t = 0; t < 16; t++) {
    int d = j0 + t * 8;
    float cv = cW1[d], cbv = cb1[d];
    int p = posg[d];
    bool act = (cv == 0.f) ? (cbv > 0.f) : ((cv > 0.f) ? (p < s) : (p >= s));
    float m = act ? M[d * HH + hh] : 0.f;
    sl = fmaf(cv, m, sl);
    in = fmaf(cbv, m, in);
  }
#pragma unroll
  for (int off = 1; off <= 4; off <<= 1) {
    sl += __shfl_xor(sl, off, 64);
    in += __shfl_xor(in, off, 64);
  }
  if (j0 == 0) {
    size_t o = (size_t)l * NSEG * HH + s * HH + hh;
    slopeg[o] = sl;
    interg[o] = in + basel[l * HH + hh];
  }
}

__global__ void k_bounds(const int* __restrict__ batch, int* __restrict__ gstart, int* __restrict__ gend) {
  int n = blockIdx.x * 256 + threadIdx.x;
  if (n >= NN) return;
  int b = batch[n];
  if (n == 0 || batch[n - 1] != b) gstart[b] = n;
  if (n == NN - 1 || batch[n + 1] != b) gend[b] = n + 1;
}

__global__ __launch_bounds__(256) void k_pool_part(const float* __restrict__ h,
    const int* __restrict__ batch, float* __restrict__ gpool) {
  int tid = threadIdx.x;
  int d = tid & 127, sub = tid >> 7;
  int n0 = blockIdx.x * 256;
  int nend = n0 + 256; if (nend > NN) nend = NN;
  float run = 0.f; int gcur = -1;
  for (int n = n0 + sub; n < nend; n += 2) {
    int g = batch[n];
    if (g != gcur) {
      if (gcur >= 0) atomicAdd(gpool + (size_t)gcur * DD + d, run);
      run = 0.f; gcur = g;
    }
    run += h[(size_t)n * DD + d];
  }
  if (gcur >= 0) atomicAdd(gpool + (size_t)gcur * DD + d, run);
}

__global__ __launch_bounds__(256) void k_head(const float* __restrict__ gpool,
    const int* __restrict__ gstart, const int* __restrict__ gend,
    const float* __restrict__ W1, const float* __restrict__ b1,
    const float* __restrict__ W2, const float* __restrict__ b2, float* __restrict__ out) {
  __shared__ float mid[NG * 64];
  int tid = threadIdx.x;
  for (int idx = tid; idx < NG * 64; idx += 256) {
    int g = idx >> 6, j = idx & 63;
    int cnt = gend[g] - gstart[g]; if (cnt < 1) cnt = 1;
    float rc = 1.0f / (float)cnt;
    float acc = 0.f;
    for (int d = 0; d < DD; d++) acc = fmaf(gpool[g * DD + d], W1[d * 64 + j], acc);
    mid[idx] = fmaxf(fmaf(acc, rc, b1[j]), 0.f);
  }
  __syncthreads();
  if (tid < NG) {
    float acc = b2[0];
    for (int j = 0; j < 64; j++) acc = fmaf(mid[tid * 64 + j], W2[j], acc);
    out[tid] = acc;
  }
}

// ---------- launch ----------
extern "C" void kernel_launch(void* const* d_in, const int* in_sizes, int n_in,
                              void* d_out, int out_size, void* d_ws, size_t ws_size,
                              hipStream_t stream) {
  const float* x      = (const float*)d_in[0];
  const int*   ei     = (const int*)d_in[1];
  const int*   batch  = (const int*)d_in[2];
  const float* node_W = (const float*)d_in[3];
  const float* node_b = (const float*)d_in[4];
  const float* cW1    = (const float*)d_in[5];
  const float* cb1    = (const float*)d_in[6];
  const float* cW2    = (const float*)d_in[7];
  const float* cb2    = (const float*)d_in[8];
  const float* qW     = (const float*)d_in[9];
  const float* qb     = (const float*)d_in[10];
  const float* kW     = (const float*)d_in[11];
  const float* kb     = (const float*)d_in[12];
  const float* vW     = (const float*)d_in[13];
  const float* vb     = (const float*)d_in[14];
  const float* oW     = (const float*)d_in[15];
  const float* ob     = (const float*)d_in[16];
  const float* bW     = (const float*)d_in[17];
  const float* bb     = (const float*)d_in[18];
  const float* f1W    = (const float*)d_in[19];
  const float* f1b    = (const float*)d_in[20];
  const float* f2W    = (const float*)d_in[21];
  const float* f2b    = (const float*)d_in[22];
  const float* n1s    = (const float*)d_in[23];
  const float* n1b    = (const float*)d_in[24];
  const float* n2s    = (const float*)d_in[25];
  const float* n2b    = (const float*)d_in[26];
  const float* outW1  = (const float*)d_in[27];
  const float* outb1  = (const float*)d_in[28];
  const float* outW2  = (const float*)d_in[29];
  const float* outb2  = (const float*)d_in[30];

  const int* src = ei;
  const int* tgt = ei + NE;

  char* wp = (char*)d_ws;
  auto alloc = [&](size_t bytes) { void* p = (void*)wp; wp += (bytes + 255) & ~(size_t)255; return p; };
  float*    h       = (float*)alloc((size_t)NN * DD * 4);
  ushort*   q       = (ushort*)alloc((size_t)NN * DD * 2);
  ushort*   kk      = (ushort*)alloc((size_t)NN * DD * 2);
  ushort*   v       = (ushort*)alloc((size_t)NN * DD * 2);
  ushort*   aggmb   = (ushort*)alloc((size_t)NN * DD * 2);
  float*    sim     = (float*)alloc((size_t)NE * 4);
  float*    dist    = (float*)alloc((size_t)NE * 4);
  float*    escore  = (float*)alloc((size_t)NE * HH * 4);
  float*    Mb      = (float*)alloc((size_t)NL * DD * HH * 4);
  float*    basel   = (float*)alloc((size_t)NL * HH * 4);
  float*    bpg     = (float*)alloc((size_t)DD * 4);
  int*      posg    = (int*)alloc((size_t)DD * 4);
  float*    slopeg  = (float*)alloc((size_t)NL * NSEG * HH * 4);
  float*    interg  = (float*)alloc((size_t)NL * NSEG * HH * 4);
  int*      rowstart= (int*)alloc((size_t)(NN + 1) * 4);
  int*      rowstart_t = (int*)alloc((size_t)(NN + 1) * 4);
  int*      eid_t   = (int*)alloc((size_t)NE * 4);
  int*      src_s   = (int*)alloc((size_t)NE * 4);
  int*      tgt_s   = (int*)alloc((size_t)NE * 4);
  int*      cnt     = (int*)alloc((size_t)NN * 4);
  int*      cur     = (int*)alloc((size_t)NN * 4);
  int*      cnt_t   = (int*)alloc((size_t)NN * 4);
  int*      cur_t   = (int*)alloc((size_t)NN * 4);
  int*      bsum    = (int*)alloc((size_t)NBS * 4);
  int*      boff    = (int*)alloc((size_t)256 * 4);
  int*      gstart  = (int*)alloc((size_t)NG * 4);
  int*      gend    = (int*)alloc((size_t)NG * 4);
  float*    gpool   = (float*)alloc((size_t)NG * DD * 4);
  ushort*   qkvT    = (ushort*)alloc((size_t)NL * 3 * DD * DD * 2);
  ushort*   oT      = (ushort*)alloc((size_t)NL * DD * DD * 2);
  ushort*   f1T     = (ushort*)alloc((size_t)NL * DD * 512 * 2);
  ushort*   f2T     = (ushort*)alloc((size_t)NL * 512 * DD * 2);
  (void)in_sizes; (void)n_in; (void)out_size; (void)ws_size;

  // once-per-call setup
  hipMemsetAsync(cnt, 0, NN * 4, stream);
  hipMemsetAsync(cur, 0, NN * 4, stream);
  hipMemsetAsync(cnt_t, 0, NN * 4, stream);
  hipMemsetAsync(cur_t, 0, NN * 4, stream);
  hipMemsetAsync(gstart, 0, NG * 4, stream);
  hipMemsetAsync(gend, 0, NG * 4, stream);
  hipMemsetAsync(gpool, 0, NG * DD * 4, stream);
  // src-CSR (edge sort) and tgt-CSR (incoming-edge lists)
  k_hist<<<(NE + 255) / 256, 256, 0, stream>>>(src, cnt);
  k_scan_blk<<<NBS, 256, 0, stream>>>(cnt, bsum);
  k_scan_top<<<1, 256, 0, stream>>>(bsum, boff, rowstart);
  k_scan_fin<<<NBS, 256, 0, stream>>>(cnt, boff, rowstart);
  k_fill<<<(NE + 255) / 256, 256, 0, stream>>>(src, tgt, rowstart, cur, src_s, tgt_s);
  k_hist<<<(NE + 255) / 256, 256, 0, stream>>>(tgt, cnt_t);
  k_scan_blk<<<NBS, 256, 0, stream>>>(cnt_t, bsum);
  k_scan_top<<<1, 256, 0, stream>>>(bsum, boff, rowstart_t);
  k_scan_fin<<<NBS, 256, 0, stream>>>(cnt_t, boff, rowstart_t);
  k_fill_t<<<(NE + 255) / 256, 256, 0, stream>>>(tgt_s, rowstart_t, cur_t, eid_t);
  k_mbias_par<<<NL * DD, 64, 0, stream>>>(cW2, cb2, bW, bb, Mb, basel);
  k_bp<<<1, 128, 0, stream>>>(cW1, cb1, bpg, posg);
  k_pwl_tab<<<NL * NSEG, 64, 0, stream>>>(cW1, cb1, posg, Mb, basel, slopeg, interg);
  k_bounds<<<(NN + 255) / 256, 256, 0, stream>>>(batch, gstart, gend);
  // bf16-transposed weights
  k_wt<DD, DD><<<(NL * DD * DD + 255) / 256, 256, 0, stream>>>(qW, qkvT,               NL, 3 * DD * DD);
  k_wt<DD, DD><<<(NL * DD * DD + 255) / 256, 256, 0, stream>>>(kW, qkvT + DD * DD,     NL, 3 * DD * DD);
  k_wt<DD, DD><<<(NL * DD * DD + 255) / 256, 256, 0, stream>>>(vW, qkvT + 2 * DD * DD, NL, 3 * DD * DD);
  k_wt<DD, DD><<<(NL * DD * DD + 255) / 256, 256, 0, stream>>>(oW, oT, NL, DD * DD);
  k_wt<DD, 512><<<(NL * DD * 512 + 255) / 256, 256, 0, stream>>>(f1W, f1T, NL, DD * 512);
  k_wt<512, DD><<<(NL * DD * 512 + 255) / 256, 256, 0, stream>>>(f2W, f2T, NL, DD * 512);
  k_node_proj<<<NT32, 256, 0, stream>>>(x, node_W, node_b, h);
  // layer-0 qkv from standalone LN1+QKV
  k_ln_qkv<<<NT32, 512, 0, stream>>>(h, n1s, n1b, qkvT, qb, kb, vb, q, kk, v);

  for (int l = 0; l < NL; l++) {
    k_edge1<<<(NE * 8 + 255) / 256, 256, 0, stream>>>(src_s, tgt_s, h, sim, dist);
    k_scores_sm<<<NT4, 256, 0, stream>>>(src_s, rowstart_t, eid_t, q, kk,
        sim, dist, bpg,
        slopeg + (size_t)l * NSEG * HH, interg + (size_t)l * NSEG * HH,
        escore);
    k_agg<<<NN / 4, 256, 0, stream>>>(tgt_s, rowstart, escore, v, aggmb);
    int ln = l < NL - 1 ? l + 1 : l;   // next-layer params (unused when do_qkv=0)
    k_attn_ffn<<<NT64, 512, 0, stream>>>(aggmb, oT + (size_t)l * DD * DD, ob + l * DD,
        n2s + l * DD, n2b + l * DD,
        f1T + (size_t)l * DD * 512, f1b + (size_t)l * 4 * DD,
        f2T + (size_t)l * 512 * DD, f2b + l * DD, h,
        (l < NL - 1) ? 1 : 0,
        n1s + ln * DD, n1b + ln * DD,
        qkvT + (size_t)ln * 3 * DD * DD,
        qb + ln * DD, kb + ln * DD, vb + ln * DD,
        q, kk, v);
  }
  k_pool_part<<<(NN + 255) / 256, 256, 0, stream>>>(h, batch, gpool);
  k_head<<<1, 256, 0, stream>>>(gpool, gstart, gend, outW1, outb1, outW2, outb2, (float*)d_out);
}

// Round 22
// 1278.813 us; speedup vs baseline: 1.0428x; 1.0245x over previous
//
#include <hip/hip_runtime.h>

#define NN 50000      // nodes
#define NE 625000     // edges
#define DD 128        // hidden dim
#define HH 8          // heads
#define DHH 16        // head dim
#define NL 4          // layers
#define FIN 64        // in channels
#define NG 64         // graphs
#define LN_EPS 1e-5f
#define NSEG 129      // PWL segments = 128 breakpoints + 1
#define NT32 1563     // ceil(NN/32)
#define NT64 782      // ceil(NN/64)
#define NT4 12500     // NN/4 (nodes per 4-wave block in k_scores_sm)
#define NBS 196       // ceil(NN/256) scan blocks
#define HLP 132       // hL padded row stride (floats): +4 breaks bank conflicts

typedef __bf16 bf16x8_t __attribute__((ext_vector_type(8)));
typedef unsigned short ushort8_t __attribute__((ext_vector_type(8)));
typedef float f32x4_t __attribute__((ext_vector_type(4)));
union BF8 { ushort8_t u; bf16x8_t b; };

// ---------- helpers ----------
__device__ __forceinline__ void fma4(float4& a, float s, float4 w) {
  a.x = fmaf(s, w.x, a.x); a.y = fmaf(s, w.y, a.y);
  a.z = fmaf(s, w.z, a.z); a.w = fmaf(s, w.w, a.w);
}
__device__ __forceinline__ unsigned short f2bf(float f) {   // RNE f32->bf16
  unsigned u = __float_as_uint(f);
  unsigned r = ((u >> 16) & 1u) + 0x7FFFu;
  return (unsigned short)((u + r) >> 16);
}
__device__ __forceinline__ float bf2f(unsigned short u) {
  return __uint_as_float((unsigned)u << 16);
}

// LayerNorm 32 nodes -> swizzled bf16 LDS tile [32][128]; block = 512 threads.
__device__ __forceinline__ void ln_tile_bf32(const float* __restrict__ h, int nb,
                                             const float* __restrict__ sc,
                                             const float* __restrict__ bi,
                                             ushort* xbf) {
  int tid = threadIdx.x;
  int r = tid >> 4, l16 = tid & 15;
  int nr = nb + r; if (nr >= NN) nr = NN - 1;   // clamp: tail rows unused
  const float* hp = h + (size_t)nr * DD + l16 * 8;
  float4 a0 = *(const float4*)hp;
  float4 a1 = *(const float4*)(hp + 4);
  float sum = a0.x + a0.y + a0.z + a0.w + a1.x + a1.y + a1.z + a1.w;
  float sq  = a0.x*a0.x + a0.y*a0.y + a0.z*a0.z + a0.w*a0.w
            + a1.x*a1.x + a1.y*a1.y + a1.z*a1.z + a1.w*a1.w;
#pragma unroll
  for (int off = 8; off >= 1; off >>= 1) {
    sum += __shfl_xor(sum, off, 64);
    sq  += __shfl_xor(sq,  off, 64);
  }
  float mu   = sum * (1.0f / DD);
  float var  = sq * (1.0f / DD) - mu * mu;
  float rstd = rsqrtf(var + LN_EPS);
  int d0 = l16 * 8;
  float4 s0 = *(const float4*)(sc + d0), s1 = *(const float4*)(sc + d0 + 4);
  float4 b0 = *(const float4*)(bi + d0), b1 = *(const float4*)(bi + d0 + 4);
  ushort8_t u;
  u[0] = f2bf((a0.x - mu) * rstd * s0.x + b0.x);
  u[1] = f2bf((a0.y - mu) * rstd * s0.y + b0.y);
  u[2] = f2bf((a0.z - mu) * rstd * s0.z + b0.z);
  u[3] = f2bf((a0.w - mu) * rstd * s0.w + b0.w);
  u[4] = f2bf((a1.x - mu) * rstd * s1.x + b1.x);
  u[5] = f2bf((a1.y - mu) * rstd * s1.y + b1.y);
  u[6] = f2bf((a1.z - mu) * rstd * s1.z + b1.z);
  u[7] = f2bf((a1.w - mu) * rstd * s1.w + b1.w);
  int off = (r * 256 + l16 * 16) ^ ((r & 7) << 4);
  *(ushort8_t*)((char*)xbf + off) = u;
}

// ---------- kernels ----------
// h = x @ node_W + node_b ; 32 nodes/block, W staged in LDS.
__global__ __launch_bounds__(256) void k_node_proj(const float* __restrict__ x,
                                                   const float* __restrict__ W,
                                                   const float* __restrict__ b,
                                                   float* __restrict__ h) {
  __shared__ float Wl[FIN * DD];    // 32 KB
  __shared__ float xt[32][FIN];     // 8 KB
  int tid = threadIdx.x;
  int nb = blockIdx.x * 32;
  for (int i = tid * 4; i < FIN * DD; i += 1024)
    *(float4*)&Wl[i] = *(const float4*)(W + i);
  for (int i = tid * 4; i < 32 * FIN; i += 1024) {
    int row = i >> 6, cc = i & 63;
    int node = nb + row; if (node >= NN) node = NN - 1;
    *(float4*)&xt[row][cc] = *(const float4*)(x + (size_t)node * FIN + cc);
  }
  __syncthreads();
  int c4 = (tid & 31) * 4;
  int r0 = (tid >> 5) * 4;
  float4 bv = *(const float4*)(b + c4);
  float4 a0 = bv, a1 = bv, a2 = bv, a3 = bv;
  for (int k = 0; k < FIN; k++) {
    float4 wv = *(const float4*)&Wl[k * DD + c4];
    fma4(a0, xt[r0][k], wv);
    fma4(a1, xt[r0 + 1][k], wv);
    fma4(a2, xt[r0 + 2][k], wv);
    fma4(a3, xt[r0 + 3][k], wv);
  }
  int n0 = nb + r0;
  if (n0 < NN)     *(float4*)(h + (size_t)n0 * DD + c4) = a0;
  if (n0 + 1 < NN) *(float4*)(h + (size_t)(n0 + 1) * DD + c4) = a1;
  if (n0 + 2 < NN) *(float4*)(h + (size_t)(n0 + 2) * DD + c4) = a2;
  if (n0 + 3 < NN) *(float4*)(h + (size_t)(n0 + 3) * DD + c4) = a3;
}

// per sorted edge: sim (dot), dist (norm) in fp32. 8 lanes/edge.
__global__ __launch_bounds__(256) void k_edge1(const int* __restrict__ src_s, const int* __restrict__ tgt_s,
                                               const float* __restrict__ h, float* __restrict__ sim,
                                               float* __restrict__ dist) {
  int gid = blockIdx.x * 256 + threadIdx.x;
  int e = gid >> 3;
  if (e >= NE) return;
  int j = gid & 7;
  int s = src_s[e], t = tgt_s[e];
  const float4* ap = (const float4*)(h + (size_t)s * DD + j * 16);
  const float4* bp = (const float4*)(h + (size_t)t * DD + j * 16);
  float4 a0 = ap[0], a1 = ap[1], a2 = ap[2], a3 = ap[3];
  float4 b0 = bp[0], b1 = bp[1], b2 = bp[2], b3 = bp[3];
  float dot = 0.f, sq = 0.f;
  dot = fmaf(a0.x, b0.x, dot); dot = fmaf(a0.y, b0.y, dot);
  dot = fmaf(a0.z, b0.z, dot); dot = fmaf(a0.w, b0.w, dot);
  dot = fmaf(a1.x, b1.x, dot); dot = fmaf(a1.y, b1.y, dot);
  dot = fmaf(a1.z, b1.z, dot); dot = fmaf(a1.w, b1.w, dot);
  dot = fmaf(a2.x, b2.x, dot); dot = fmaf(a2.y, b2.y, dot);
  dot = fmaf(a2.z, b2.z, dot); dot = fmaf(a2.w, b2.w, dot);
  dot = fmaf(a3.x, b3.x, dot); dot = fmaf(a3.y, b3.y, dot);
  dot = fmaf(a3.z, b3.z, dot); dot = fmaf(a3.w, b3.w, dot);
  float d;
  d = a0.x - b0.x; sq = fmaf(d, d, sq); d = a0.y - b0.y; sq = fmaf(d, d, sq);
  d = a0.z - b0.z; sq = fmaf(d, d, sq); d = a0.w - b0.w; sq = fmaf(d, d, sq);
  d = a1.x - b1.x; sq = fmaf(d, d, sq); d = a1.y - b1.y; sq = fmaf(d, d, sq);
  d = a1.z - b1.z; sq = fmaf(d, d, sq); d = a1.w - b1.w; sq = fmaf(d, d, sq);
  d = a2.x - b2.x; sq = fmaf(d, d, sq); d = a2.y - b2.y; sq = fmaf(d, d, sq);
  d = a2.z - b2.z; sq = fmaf(d, d, sq); d = a2.w - b2.w; sq = fmaf(d, d, sq);
  d = a3.x - b3.x; sq = fmaf(d, d, sq); d = a3.y - b3.y; sq = fmaf(d, d, sq);
  d = a3.z - b3.z; sq = fmaf(d, d, sq); d = a3.w - b3.w; sq = fmaf(d, d, sq);
#pragma unroll
  for (int off = 4; off >= 1; off >>= 1) {
    dot += __shfl_xor(dot, off, 64);
    sq  += __shfl_xor(sq,  off, 64);
  }
  if (j == 0) {
    sim[e]  = dot;                  // BETA == 1.0
    dist[e] = sqrtf(sq);
  }
}

// LN1 + QKV projection via swapped-operand MFMA -> bf16 q/k/v. 32 rows/block, 8 waves.
// Used only for layer 0 (layers 1..3 get qkv from k_attn_ffn stage 5).
__global__ __launch_bounds__(512) void k_ln_qkv(const float* __restrict__ h,
    const float* __restrict__ n1s_l, const float* __restrict__ n1b_l,
    const ushort* __restrict__ qkvT_l,
    const float* __restrict__ qb_l, const float* __restrict__ kb_l, const float* __restrict__ vb_l,
    ushort* __restrict__ q, ushort* __restrict__ kk, ushort* __restrict__ v) {
  __shared__ __align__(16) ushort xbf[32 * DD];
  int nb = blockIdx.x * 32;
  ln_tile_bf32(h, nb, n1s_l, n1b_l, xbf);
  __syncthreads();
  int lane = threadIdx.x & 63;
  int w = threadIdx.x >> 6;
  int g = lane >> 4, c = lane & 15;
  int xr = (c & 7) << 4;
  char* xb = (char*)xbf;
  BF8 a[2][4];
#pragma unroll
  for (int nt = 0; nt < 2; nt++)
#pragma unroll
    for (int kt = 0; kt < 4; kt++)
      a[nt][kt].u = *(ushort8_t*)(xb + (((nt * 16 + c) * 256 + kt * 64 + g * 16) ^ xr));
#pragma unroll
  for (int ti = 0; ti < 3; ti++) {
    int t = w * 3 + ti;                // 0..23
    int m = t >> 3;                    // 0=q 1=k 2=v
    int colb = (t & 7) * 16;
    const float* bias = (m == 0 ? qb_l : (m == 1 ? kb_l : vb_l));
    float4 bv = *(const float4*)(bias + colb + g * 4);
    f32x4_t acc0 = {bv.x, bv.y, bv.z, bv.w};
    f32x4_t acc1 = acc0;
    const ushort* wp = qkvT_l + (size_t)(m * DD + colb + c) * DD + g * 8;
#pragma unroll
    for (int kt = 0; kt < 4; kt++) {
      BF8 b; b.u = *(const ushort8_t*)(wp + kt * 32);
      acc0 = __builtin_amdgcn_mfma_f32_16x16x32_bf16(b.b, a[0][kt].b, acc0, 0, 0, 0);
      acc1 = __builtin_amdgcn_mfma_f32_16x16x32_bf16(b.b, a[1][kt].b, acc1, 0, 0, 0);
    }
    ushort* out = (m == 0 ? q : (m == 1 ? kk : v));
    int n0 = nb + c;
    if (n0 < NN) {
      ushort4 o; o.x = f2bf(acc0[0]); o.y = f2bf(acc0[1]); o.z = f2bf(acc0[2]); o.w = f2bf(acc0[3]);
      *(ushort4*)(out + (size_t)n0 * DD + colb + g * 4) = o;
    }
    int n1 = nb + 16 + c;
    if (n1 < NN) {
      ushort4 o; o.x = f2bf(acc1[0]); o.y = f2bf(acc1[1]); o.z = f2bf(acc1[2]); o.w = f2bf(acc1[3]);
      *(ushort4*)(out + (size_t)n1 * DD + colb + g * 4) = o;
    }
  }
}

// FUSED curvature + scores + softmax, 64 lanes/node.
// Phase A (all 64 lanes): aggv from sim/dist via stride-64 gathers + shfl trees.
// Phase B (8 heads x 8 edge lanes): raw scores -> escore + online (m,sum).
// Phase C: shfl combine over edge-lane groups.
// Phase D: each lane rewrites ITS OWN raw scores as p = expf(sc-m)*inv.
// Max subtraction stays MANDATORY (r5/r6 lesson).
__global__ __launch_bounds__(256) void k_scores_sm(const int* __restrict__ src_s,
    const int* __restrict__ rowstart_t, const int* __restrict__ eid_t,
    const ushort* __restrict__ q, const ushort* __restrict__ k,
    const float* __restrict__ sim, const float* __restrict__ dist,
    const float* __restrict__ bp_g,
    const float* __restrict__ slope_l, const float* __restrict__ inter_l,
    float* __restrict__ escore) {
  __shared__ float lsl[NSEG * HH], lin[NSEG * HH], bp[DD];
  int tid = threadIdx.x;
  for (int idx = tid; idx < NSEG * HH; idx += 256) { lsl[idx] = slope_l[idx]; lin[idx] = inter_l[idx]; }
  if (tid < DD) bp[tid] = bp_g[tid];
  __syncthreads();
  int node = blockIdx.x * 4 + (tid >> 6);
  if (node >= NN) return;
  int lane = tid & 63;
  int rs = rowstart_t[node], re = rowstart_t[node + 1];
  // ---- Phase A: aggv (all 64 lanes)
  float msim = -3.4e38f;
  for (int i = rs + lane; i < re; i += 64) msim = fmaxf(msim, sim[eid_t[i]]);
#pragma unroll
  for (int off = 1; off <= 32; off <<= 1) msim = fmaxf(msim, __shfl_xor(msim, off, 64));
  float den = 0.f, nd = 0.f;
  for (int i = rs + lane; i < re; i += 64) {
    int e = eid_t[i];
    float ev = expf(sim[e] - msim);
    den += ev;
    nd = fmaf(ev, dist[e], nd);
  }
#pragma unroll
  for (int off = 1; off <= 32; off <<= 1) {
    den += __shfl_xor(den, off, 64);
    nd  += __shfl_xor(nd,  off, 64);
  }
  float av = den > 0.f ? nd / den : 0.f;
  // ---- Phase B: raw scores + online (m, sum)
  int hh = lane & 7;
  int eidx = lane >> 3;
  const ushort8_t* kp = (const ushort8_t*)(k + (size_t)node * DD + hh * DHH);
  ushort8_t k0 = kp[0], k1 = kp[1];
  float m = -3.4e38f, ssum = 0.f;
  for (int i = rs + eidx; i < re; i += 8) {
    int e = eid_t[i];
    int s = src_s[e];
    float dd = dist[e];
    const ushort8_t* qp = (const ushort8_t*)(q + (size_t)s * DD + hh * DHH);
    ushort8_t q0 = qp[0], q1 = qp[1];
    float curv = 1.0f - av / fmaxf(dd, 1e-6f);
    int lo = 0, hi = DD;
    while (lo < hi) { int mid = (lo + hi) >> 1; if (bp[mid] < curv) lo = mid + 1; else hi = mid; }
    float bias = fmaf(lsl[lo * HH + hh], curv, lin[lo * HH + hh]);
    float dot = 0.f;
#pragma unroll
    for (int jj = 0; jj < 8; jj++) dot = fmaf(bf2f(q0[jj]), bf2f(k0[jj]), dot);
#pragma unroll
    for (int jj = 0; jj < 8; jj++) dot = fmaf(bf2f(q1[jj]), bf2f(k1[jj]), dot);
    float sc = dot * 0.25f + bias;   // 1/sqrt(16)
    escore[e * HH + hh] = sc;
    float mn = fmaxf(m, sc);
    ssum = ssum * expf(m - mn) + expf(sc - mn);
    m = mn;
  }
  // ---- Phase C: combine (m, s) across the 8 edge-lane groups
#pragma unroll
  for (int off = 8; off <= 32; off <<= 1) {
    float m2 = __shfl_xor(m, off, 64);
    float s2 = __shfl_xor(ssum, off, 64);
    float M = fmaxf(m, m2);
    ssum = ssum * expf(m - M) + s2 * expf(m2 - M);
    m = M;
  }
  float inv = ssum > 0.f ? 1.0f / ssum : 0.f;
  // ---- Phase D: rewrite own raw scores as final probabilities
  for (int i = rs + eidx; i < re; i += 8) {
    size_t idx = (size_t)eid_t[i] * HH + hh;
    float sc = escore[idx];
    escore[idx] = expf(sc - m) * inv;
  }
}

// CSR-gather message aggregation: one wave per src node, 2 dims/lane -> bf16 out.
// escore holds final probabilities (computed in k_scores_sm phase D).
__global__ __launch_bounds__(256) void k_agg(const int* __restrict__ tgt_s,
    const int* __restrict__ rowstart,
    const float* __restrict__ escore,
    const ushort* __restrict__ v, ushort* __restrict__ aggmb) {
  int wave = (blockIdx.x * 256 + threadIdx.x) >> 6;
  int lane = threadIdx.x & 63;
  int rs = rowstart[wave], re = rowstart[wave + 1];
  int hh = lane >> 3;
  int d = lane * 2;
  float a0 = 0.f, a1 = 0.f;
  int i = rs;
  for (; i + 4 <= re; i += 4) {
    int t0 = tgt_s[i], t1 = tgt_s[i + 1], t2 = tgt_s[i + 2], t3 = tgt_s[i + 3];
    float p0 = escore[(i    ) * HH + hh];
    float p1 = escore[(i + 1) * HH + hh];
    float p2 = escore[(i + 2) * HH + hh];
    float p3 = escore[(i + 3) * HH + hh];
    ushort2 v0 = *(const ushort2*)(v + (size_t)t0 * DD + d);
    ushort2 v1 = *(const ushort2*)(v + (size_t)t1 * DD + d);
    ushort2 v2 = *(const ushort2*)(v + (size_t)t2 * DD + d);
    ushort2 v3 = *(const ushort2*)(v + (size_t)t3 * DD + d);
    a0 = fmaf(p0, bf2f(v0.x), a0); a1 = fmaf(p0, bf2f(v0.y), a1);
    a0 = fmaf(p1, bf2f(v1.x), a0); a1 = fmaf(p1, bf2f(v1.y), a1);
    a0 = fmaf(p2, bf2f(v2.x), a0); a1 = fmaf(p2, bf2f(v2.y), a1);
    a0 = fmaf(p3, bf2f(v3.x), a0); a1 = fmaf(p3, bf2f(v3.y), a1);
  }
  for (; i < re; i++) {
    int t = tgt_s[i];
    float prob = escore[i * HH + hh];
    ushort2 vv = *(const ushort2*)(v + (size_t)t * DD + d);
    a0 = fmaf(prob, bf2f(vv.x), a0);
    a1 = fmaf(prob, bf2f(vv.y), a1);
  }
  ushort2 o; o.x = f2bf(a0); o.y = f2bf(a1);
  *(ushort2*)(aggmb + (size_t)wave * DD + d) = o;
}

// FUSED: h' = h + aggm@oW + ob (LDS hL) -> LN2 -> FFN -> h = h' + FFN out,
// then (stage 5, if do_qkv) LN1(next layer) + QKV projection.
__global__ __launch_bounds__(512) void k_attn_ffn(const ushort* __restrict__ aggmb,
    const ushort* __restrict__ oT_l, const float* __restrict__ ob_l,
    const float* __restrict__ n2s_l, const float* __restrict__ n2b_l,
    const ushort* __restrict__ f1T_l, const float* __restrict__ f1b_l,
    const ushort* __restrict__ f2T_l, const float* __restrict__ f2b_l,
    float* __restrict__ h,
    int do_qkv,
    const float* __restrict__ n1s_n, const float* __restrict__ n1b_n,
    const ushort* __restrict__ qkvT_n,
    const float* __restrict__ qb_n, const float* __restrict__ kb_n, const float* __restrict__ vb_n,
    ushort* __restrict__ q, ushort* __restrict__ kk, ushort* __restrict__ v) {
  __shared__ float hL[64 * HLP];                      // 33 KB
  __shared__ __align__(16) char ubuf[64 * 128 * 2];   // 16 KB union: xbf / tbf / xbf(qkv)
  char* xb = ubuf;
  char* tb = ubuf;
  int nb = blockIdx.x * 64;
  int tid = threadIdx.x;
  int lane = tid & 63, w = tid >> 6;
  int g = lane >> 4, c = lane & 15;
  int colb = w * 16;
  int xr = (c & 7) << 4;
  // ---- Stage 1: O-projection + residual -> hL
  {
    float4 obv = *(const float4*)(ob_l + colb + g * 4);
    const ushort* wp = oT_l + (size_t)(colb + c) * DD + g * 8;
    BF8 b0, b1, b2, b3;
    b0.u = *(const ushort8_t*)(wp);
    b1.u = *(const ushort8_t*)(wp + 32);
    b2.u = *(const ushort8_t*)(wp + 64);
    b3.u = *(const ushort8_t*)(wp + 96);
#pragma unroll
    for (int nt = 0; nt < 4; nt++) {
      int node = nb + nt * 16 + c;
      int na = node < NN ? node : NN - 1;
      const ushort* ap = aggmb + (size_t)na * DD + g * 8;
      BF8 a0, a1, a2, a3;
      a0.u = *(const ushort8_t*)(ap);
      a1.u = *(const ushort8_t*)(ap + 32);
      a2.u = *(const ushort8_t*)(ap + 64);
      a3.u = *(const ushort8_t*)(ap + 96);
      f32x4_t acc = {obv.x, obv.y, obv.z, obv.w};
      acc = __builtin_amdgcn_mfma_f32_16x16x32_bf16(b0.b, a0.b, acc, 0, 0, 0);
      acc = __builtin_amdgcn_mfma_f32_16x16x32_bf16(b1.b, a1.b, acc, 0, 0, 0);
      acc = __builtin_amdgcn_mfma_f32_16x16x32_bf16(b2.b, a2.b, acc, 0, 0, 0);
      acc = __builtin_amdgcn_mfma_f32_16x16x32_bf16(b3.b, a3.b, acc, 0, 0, 0);
      float4 hv = *(const float4*)(h + (size_t)na * DD + colb + g * 4);
      hv.x += acc[0]; hv.y += acc[1]; hv.z += acc[2]; hv.w += acc[3];
      *(float4*)&hL[(nt * 16 + c) * HLP + colb + g * 4] = hv;
    }
  }
  __syncthreads();
  // ---- Stage 2: LN2 from hL -> xbf
  {
    int l16 = tid & 15;
    int d0 = l16 * 8;
    float4 s0 = *(const float4*)(n2s_l + d0), s1 = *(const float4*)(n2s_l + d0 + 4);
    float4 bb0 = *(const float4*)(n2b_l + d0), bb1 = *(const float4*)(n2b_l + d0 + 4);
#pragma unroll
    for (int p = 0; p < 2; p++) {
      int r = p * 32 + (tid >> 4);
      const float* hp = &hL[r * HLP + d0];
      float4 a0 = *(const float4*)hp;
      float4 a1 = *(const float4*)(hp + 4);
      float sum = a0.x + a0.y + a0.z + a0.w + a1.x + a1.y + a1.z + a1.w;
      float sq  = a0.x*a0.x + a0.y*a0.y + a0.z*a0.z + a0.w*a0.w
                + a1.x*a1.x + a1.y*a1.y + a1.z*a1.z + a1.w*a1.w;
#pragma unroll
      for (int off = 8; off >= 1; off >>= 1) {
        sum += __shfl_xor(sum, off, 64);
        sq  += __shfl_xor(sq,  off, 64);
      }
      float mu   = sum * (1.0f / DD);
      float var  = sq * (1.0f / DD) - mu * mu;
      float rstd = rsqrtf(var + LN_EPS);
      ushort8_t u;
      u[0] = f2bf((a0.x - mu) * rstd * s0.x + bb0.x);
      u[1] = f2bf((a0.y - mu) * rstd * s0.y + bb0.y);
      u[2] = f2bf((a0.z - mu) * rstd * s0.z + bb0.z);
      u[3] = f2bf((a0.w - mu) * rstd * s0.w + bb0.w);
      u[4] = f2bf((a1.x - mu) * rstd * s1.x + bb1.x);
      u[5] = f2bf((a1.y - mu) * rstd * s1.y + bb1.y);
      u[6] = f2bf((a1.z - mu) * rstd * s1.z + bb1.z);
      u[7] = f2bf((a1.w - mu) * rstd * s1.w + bb1.w);
      int off = (r * 256 + l16 * 16) ^ ((r & 7) << 4);
      *(ushort8_t*)(xb + off) = u;
    }
  }
  __syncthreads();
  // A-frags from xbf (registers)
  BF8 a[4][4];
#pragma unroll
  for (int nt = 0; nt < 4; nt++)
#pragma unroll
    for (int kt = 0; kt < 4; kt++)
      a[nt][kt].u = *(ushort8_t*)(xb + (((nt * 16 + c) * 256 + kt * 64 + g * 16) ^ xr));
  __syncthreads();   // xbf dead; ubuf becomes tbf
  // ---- Stage 3: FFN, 4 chunks of 128 cols (tbf row stride 256B)
  float4 bv2 = *(const float4*)(f2b_l + colb + g * 4);
  f32x4_t o0 = {bv2.x, bv2.y, bv2.z, bv2.w};
  f32x4_t o1 = o0, o2 = o0, o3 = o0;
#pragma unroll
  for (int ch = 0; ch < 4; ch++) {
    if (ch) __syncthreads();           // tbf reuse: wait for prev-chunk reads
    {
      int col = ch * 128 + w * 16;
      float4 bv = *(const float4*)(f1b_l + col + g * 4);
      f32x4_t ac0 = {bv.x, bv.y, bv.z, bv.w};
      f32x4_t ac1 = ac0, ac2 = ac0, ac3 = ac0;
      const ushort* wp = f1T_l + (size_t)(col + c) * DD + g * 8;
#pragma unroll
      for (int kt = 0; kt < 4; kt++) {
        BF8 b; b.u = *(const ushort8_t*)(wp + kt * 32);
        ac0 = __builtin_amdgcn_mfma_f32_16x16x32_bf16(b.b, a[0][kt].b, ac0, 0, 0, 0);
        ac1 = __builtin_amdgcn_mfma_f32_16x16x32_bf16(b.b, a[1][kt].b, ac1, 0, 0, 0);
        ac2 = __builtin_amdgcn_mfma_f32_16x16x32_bf16(b.b, a[2][kt].b, ac2, 0, 0, 0);
        ac3 = __builtin_amdgcn_mfma_f32_16x16x32_bf16(b.b, a[3][kt].b, ac3, 0, 0, 0);
      }
      int colL = (w * 16 + g * 4) * 2;
      {
        int row = c;
        ushort4 o4; o4.x = f2bf(fmaxf(ac0[0], 0.f)); o4.y = f2bf(fmaxf(ac0[1], 0.f));
        o4.z = f2bf(fmaxf(ac0[2], 0.f)); o4.w = f2bf(fmaxf(ac0[3], 0.f));
        *(ushort4*)(tb + ((row * 256 + colL) ^ ((row & 7) << 4))) = o4;
      }
      {
        int row = 16 + c;
        ushort4 o4; o4.x = f2bf(fmaxf(ac1[0], 0.f)); o4.y = f2bf(fmaxf(ac1[1], 0.f));
        o4.z = f2bf(fmaxf(ac1[2], 0.f)); o4.w = f2bf(fmaxf(ac1[3], 0.f));
        *(ushort4*)(tb + ((row * 256 + colL) ^ ((row & 7) << 4))) = o4;
      }
      {
        int row = 32 + c;
        ushort4 o4; o4.x = f2bf(fmaxf(ac2[0], 0.f)); o4.y = f2bf(fmaxf(ac2[1], 0.f));
        o4.z = f2bf(fmaxf(ac2[2], 0.f)); o4.w = f2bf(fmaxf(ac2[3], 0.f));
        *(ushort4*)(tb + ((row * 256 + colL) ^ ((row & 7) << 4))) = o4;
      }
      {
        int row = 48 + c;
        ushort4 o4; o4.x = f2bf(fmaxf(ac3[0], 0.f)); o4.y = f2bf(fmaxf(ac3[1], 0.f));
        o4.z = f2bf(fmaxf(ac3[2], 0.f)); o4.w = f2bf(fmaxf(ac3[3], 0.f));
        *(ushort4*)(tb + ((row * 256 + colL) ^ ((row & 7) << 4))) = o4;
      }
    }
    __syncthreads();
    const ushort* wp2 = f2T_l + (size_t)(colb + c) * 512 + ch * 128 + g * 8;
#pragma unroll
    for (int kt = 0; kt < 4; kt++) {
      BF8 b; b.u = *(const ushort8_t*)(wp2 + kt * 32);
      BF8 t0; t0.u = *(ushort8_t*)(tb + (((c) * 256 + kt * 64 + g * 16) ^ xr));
      BF8 t1; t1.u = *(ushort8_t*)(tb + (((16 + c) * 256 + kt * 64 + g * 16) ^ xr));
      BF8 t2; t2.u = *(ushort8_t*)(tb + (((32 + c) * 256 + kt * 64 + g * 16) ^ xr));
      BF8 t3; t3.u = *(ushort8_t*)(tb + (((48 + c) * 256 + kt * 64 + g * 16) ^ xr));
      o0 = __builtin_amdgcn_mfma_f32_16x16x32_bf16(b.b, t0.b, o0, 0, 0, 0);
      o1 = __builtin_amdgcn_mfma_f32_16x16x32_bf16(b.b, t1.b, o1, 0, 0, 0);
      o2 = __builtin_amdgcn_mfma_f32_16x16x32_bf16(b.b, t2.b, o2, 0, 0, 0);
      o3 = __builtin_amdgcn_mfma_f32_16x16x32_bf16(b.b, t3.b, o3, 0, 0, 0);
    }
  }
  // ---- Stage 4: final residual from hL -> global h (and back into hL for stage 5)
  {
    float* lp = &hL[c * HLP + colb + g * 4];
    float4 hv = *(const float4*)lp;
    hv.x += o0[0]; hv.y += o0[1]; hv.z += o0[2]; hv.w += o0[3];
    *(float4*)lp = hv;
    int node = nb + c;
    if (node < NN) *(float4*)(h + (size_t)node * DD + colb + g * 4) = hv;
  }
  {
    float* lp = &hL[(16 + c) * HLP + colb + g * 4];
    float4 hv = *(const float4*)lp;
    hv.x += o1[0]; hv.y += o1[1]; hv.z += o1[2]; hv.w += o1[3];
    *(float4*)lp = hv;
    int node = nb + 16 + c;
    if (node < NN) *(float4*)(h + (size_t)node * DD + colb + g * 4) = hv;
  }
  {
    float* lp = &hL[(32 + c) * HLP + colb + g * 4];
    float4 hv = *(const float4*)lp;
    hv.x += o2[0]; hv.y += o2[1]; hv.z += o2[2]; hv.w += o2[3];
    *(float4*)lp = hv;
    int node = nb + 32 + c;
    if (node < NN) *(float4*)(h + (size_t)node * DD + colb + g * 4) = hv;
  }
  {
    float* lp = &hL[(48 + c) * HLP + colb + g * 4];
    float4 hv = *(const float4*)lp;
    hv.x += o3[0]; hv.y += o3[1]; hv.z += o3[2]; hv.w += o3[3];
    *(float4*)lp = hv;
    int node = nb + 48 + c;
    if (node < NN) *(float4*)(h + (size_t)node * DD + colb + g * 4) = hv;
  }
  if (!do_qkv) return;
  __syncthreads();   // hL final visible; tbf reads done -> ubuf becomes xbf again
  // ---- Stage 5: LN1(next layer) from hL -> xbf
  {
    int l16 = tid & 15;
    int d0 = l16 * 8;
    float4 s0 = *(const float4*)(n1s_n + d0), s1 = *(const float4*)(n1s_n + d0 + 4);
    float4 bb0 = *(const float4*)(n1b_n + d0), bb1 = *(const float4*)(n1b_n + d0 + 4);
#pragma unroll
    for (int p = 0; p < 2; p++) {
      int r = p * 32 + (tid >> 4);
      const float* hp = &hL[r * HLP + d0];
      float4 a0 = *(const float4*)hp;
      float4 a1 = *(const float4*)(hp + 4);
      float sum = a0.x + a0.y + a0.z + a0.w + a1.x + a1.y + a1.z + a1.w;
      float sq  = a0.x*a0.x + a0.y*a0.y + a0.z*a0.z + a0.w*a0.w
                + a1.x*a1.x + a1.y*a1.y + a1.z*a1.z + a1.w*a1.w;
#pragma unroll
      for (int off = 8; off >= 1; off >>= 1) {
        sum += __shfl_xor(sum, off, 64);
        sq  += __shfl_xor(sq,  off, 64);
      }
      float mu   = sum * (1.0f / DD);
      float var  = sq * (1.0f / DD) - mu * mu;
      float rstd = rsqrtf(var + LN_EPS);
      ushort8_t u;
      u[0] = f2bf((a0.x - mu) * rstd * s0.x + bb0.x);
      u[1] = f2bf((a0.y - mu) * rstd * s0.y + bb0.y);
      u[2] = f2bf((a0.z - mu) * rstd * s0.z + bb0.z);
      u[3] = f2bf((a0.w - mu) * rstd * s0.w + bb0.w);
      u[4] = f2bf((a1.x - mu) * rstd * s1.x + bb1.x);
      u[5] = f2bf((a1.y - mu) * rstd * s1.y + bb1.y);
      u[6] = f2bf((a1.z - mu) * rstd * s1.z + bb1.z);
      u[7] = f2bf((a1.w - mu) * rstd * s1.w + bb1.w);
      int off = (r * 256 + l16 * 16) ^ ((r & 7) << 4);
      *(ushort8_t*)(xb + off) = u;
    }
  }
  __syncthreads();
  BF8 aq[4][4];
#pragma unroll
  for (int nt = 0; nt < 4; nt++)
#pragma unroll
    for (int kt = 0; kt < 4; kt++)
      aq[nt][kt].u = *(ushort8_t*)(xb + (((nt * 16 + c) * 256 + kt * 64 + g * 16) ^ xr));
#pragma unroll
  for (int ti = 0; ti < 3; ti++) {
    int t = w * 3 + ti;                // 0..23
    int m = t >> 3;                    // 0=q 1=k 2=v
    int colq = (t & 7) * 16;
    const float* bias = (m == 0 ? qb_n : (m == 1 ? kb_n : vb_n));
    float4 bv = *(const float4*)(bias + colq + g * 4);
    f32x4_t ac0 = {bv.x, bv.y, bv.z, bv.w};
    f32x4_t ac1 = ac0, ac2 = ac0, ac3 = ac0;
    const ushort* wp = qkvT_n + (size_t)(m * DD + colq + c) * DD + g * 8;
#pragma unroll
    for (int kt = 0; kt < 4; kt++) {
      BF8 b; b.u = *(const ushort8_t*)(wp + kt * 32);
      ac0 = __builtin_amdgcn_mfma_f32_16x16x32_bf16(b.b, aq[0][kt].b, ac0, 0, 0, 0);
      ac1 = __builtin_amdgcn_mfma_f32_16x16x32_bf16(b.b, aq[1][kt].b, ac1, 0, 0, 0);
      ac2 = __builtin_amdgcn_mfma_f32_16x16x32_bf16(b.b, aq[2][kt].b, ac2, 0, 0, 0);
      ac3 = __builtin_amdgcn_mfma_f32_16x16x32_bf16(b.b, aq[3][kt].b, ac3, 0, 0, 0);
    }
    ushort* out = (m == 0 ? q : (m == 1 ? kk : v));
    {
      int node = nb + c;
      if (node < NN) {
        ushort4 o; o.x = f2bf(ac0[0]); o.y = f2bf(ac0[1]); o.z = f2bf(ac0[2]); o.w = f2bf(ac0[3]);
        *(ushort4*)(out + (size_t)node * DD + colq + g * 4) = o;
      }
    }
    {
      int node = nb + 16 + c;
      if (node < NN) {
        ushort4 o; o.x = f2bf(ac1[0]); o.y = f2bf(ac1[1]); o.z = f2bf(ac1[2]); o.w = f2bf(ac1[3]);
        *(ushort4*)(out + (size_t)node * DD + colq + g * 4) = o;
      }
    }
    {
      int node = nb + 32 + c;
      if (node < NN) {
        ushort4 o; o.x = f2bf(ac2[0]); o.y = f2bf(ac2[1]); o.z = f2bf(ac2[2]); o.w = f2bf(ac2[3]);
        *(ushort4*)(out + (size_t)node * DD + colq + g * 4) = o;
      }
    }
    {
      int node = nb + 48 + c;
      if (node < NN) {
        ushort4 o; o.x = f2bf(ac3[0]); o.y = f2bf(ac3[1]); o.z = f2bf(ac3[2]); o.w = f2bf(ac3[3]);
        *(ushort4*)(out + (size_t)node * DD + colq + g * 4) = o;
      }
    }
  }
}

// ---------- once-per-call setup kernels (r22: consolidated) ----------
// One kernel zeroes all scratch buffers (replaces 7 hipMemsetAsync dispatches).
__global__ __launch_bounds__(256) void k_zero(int* __restrict__ cnt, int* __restrict__ cur,
                                              int* __restrict__ cnt_t, int* __restrict__ cur_t,
                                              int* __restrict__ gstart, int* __restrict__ gend,
                                              float* __restrict__ gpool) {
  int i = blockIdx.x * 256 + threadIdx.x;
  if (i < NN) { cnt[i] = 0; cur[i] = 0; cnt_t[i] = 0; cur_t[i] = 0; }
  if (i < NG) { gstart[i] = 0; gend[i] = 0; }
  if (i < NG * DD) gpool[i] = 0.f;
}

// Both histograms in one edge pass (tgt histogram is permutation-invariant,
// so using the UNSORTED tgt array gives identical counts).
__global__ void k_hist2(const int* __restrict__ src, const int* __restrict__ tgt,
                        int* __restrict__ cnt, int* __restrict__ cnt_t) {
  int e = blockIdx.x * 256 + threadIdx.x;
  if (e < NE) {
    atomicAdd(cnt + src[e], 1);
    atomicAdd(cnt_t + tgt[e], 1);
  }
}

// Fused scans: blocks [0,NBS) handle cnt->bsum, [NBS,2*NBS) handle cnt_t->bsum_t.
__global__ __launch_bounds__(256) void k_scan_blk2(const int* __restrict__ cnt,
                                                   const int* __restrict__ cnt_t,
                                                   int* __restrict__ bsum, int* __restrict__ bsum_t) {
  __shared__ int red[256];
  int arr = blockIdx.x >= NBS ? 1 : 0;
  int b = blockIdx.x - arr * NBS;
  const int* c = arr ? cnt_t : cnt;
  int* bs = arr ? bsum_t : bsum;
  int tid = threadIdx.x;
  int idx = b * 256 + tid;
  red[tid] = (idx < NN) ? c[idx] : 0;
  __syncthreads();
  for (int off = 128; off >= 1; off >>= 1) {
    if (tid < off) red[tid] += red[tid + off];
    __syncthreads();
  }
  if (tid == 0) bs[b] = red[0];
}

__global__ __launch_bounds__(256) void k_scan_top2(const int* __restrict__ bsum,
                                                   const int* __restrict__ bsum_t,
                                                   int* __restrict__ boff, int* __restrict__ boff_t,
                                                   int* __restrict__ rowstart, int* __restrict__ rowstart_t) {
  __shared__ int ps[256];
  int arr = blockIdx.x;
  const int* bs = arr ? bsum_t : bsum;
  int* bo = arr ? boff_t : boff;
  int* rsN = arr ? rowstart_t : rowstart;
  int t = threadIdx.x;
  int v = (t < NBS) ? bs[t] : 0;
  ps[t] = v;
  __syncthreads();
  for (int off = 1; off < 256; off <<= 1) {
    int x = (t >= off) ? ps[t - off] : 0;
    __syncthreads();
    ps[t] += x;
    __syncthreads();
  }
  bo[t] = ps[t] - v;                 // exclusive prefix of block sums
  if (t == 255) rsN[NN] = ps[255];
}

__global__ __launch_bounds__(256) void k_scan_fin2(const int* __restrict__ cnt,
                                                   const int* __restrict__ cnt_t,
                                                   const int* __restrict__ boff, const int* __restrict__ boff_t,
                                                   int* __restrict__ rowstart, int* __restrict__ rowstart_t) {
  __shared__ int ps[256];
  int arr = blockIdx.x >= NBS ? 1 : 0;
  int b = blockIdx.x - arr * NBS;
  const int* c = arr ? cnt_t : cnt;
  const int* bo = arr ? boff_t : boff;
  int* rs = arr ? rowstart_t : rowstart;
  int t = threadIdx.x;
  int idx = b * 256 + t;
  int v = (idx < NN) ? c[idx] : 0;
  ps[t] = v;
  __syncthreads();
  for (int off = 1; off < 256; off <<= 1) {
    int x = (t >= off) ? ps[t - off] : 0;
    __syncthreads();
    ps[t] += x;
    __syncthreads();
  }
  if (idx < NN) rs[idx] = bo[b] + ps[t] - v;
}

// scatter edges into src-sorted order (all per-edge arrays use sorted index)
__global__ void k_fill(const int* __restrict__ src, const int* __restrict__ tgt,
                       const int* __restrict__ rowstart,
                       int* __restrict__ cur, int* __restrict__ src_s, int* __restrict__ tgt_s) {
  int e = blockIdx.x * 256 + threadIdx.x;
  if (e >= NE) return;
  int s = src[e];
  int p = atomicAdd(cur + s, 1);
  int pos = rowstart[s] + p;
  src_s[pos] = s;
  tgt_s[pos] = tgt[e];
}

// tgt-CSR: list of src-sorted edge ids per tgt node
__global__ void k_fill_t(const int* __restrict__ tgt_s, const int* __restrict__ rowstart_t,
                         int* __restrict__ cur_t, int* __restrict__ eid_t) {
  int i = blockIdx.x * 256 + threadIdx.x;
  if (i >= NE) return;
  int t = tgt_s[i];
  int p = atomicAdd(cur_t + t, 1);
  eid_t[rowstart_t[t] + p] = i;
}

// All six weight transposes (fp32 [K][C] -> bf16 [C][K]) in one launch.
// Per-element computation identical to the old k_wt template instances.
__device__ __forceinline__ void wt_one(const float* __restrict__ W, ushort* __restrict__ WT,
                                       int idx, int K, int C, int dstride) {
  int mi = idx / (K * C), rem = idx - mi * (K * C);
  int cc = rem / K, kk2 = rem - cc * K;
  WT[(size_t)mi * dstride + cc * K + kk2] = f2bf(W[(size_t)mi * K * C + (size_t)kk2 * C + cc]);
}
__global__ __launch_bounds__(256) void k_wt_all(const float* __restrict__ qW, const float* __restrict__ kW,
                                                const float* __restrict__ vW, const float* __restrict__ oW,
                                                const float* __restrict__ f1W, const float* __restrict__ f2W,
                                                ushort* __restrict__ qkvT, ushort* __restrict__ oT,
                                                ushort* __restrict__ f1T, ushort* __restrict__ f2T) {
  int idx = blockIdx.x * 256 + threadIdx.x;
  const int SZ1 = NL * DD * DD;      // 65536
  const int SZF = NL * DD * 512;     // 262144
  if (idx < SZ1) { wt_one(qW, qkvT, idx, DD, DD, 3 * DD * DD); return; }
  idx -= SZ1;
  if (idx < SZ1) { wt_one(kW, qkvT + DD * DD, idx, DD, DD, 3 * DD * DD); return; }
  idx -= SZ1;
  if (idx < SZ1) { wt_one(vW, qkvT + 2 * DD * DD, idx, DD, DD, 3 * DD * DD); return; }
  idx -= SZ1;
  if (idx < SZ1) { wt_one(oW, oT, idx, DD, DD, DD * DD); return; }
  idx -= SZ1;
  if (idx < SZF) { wt_one(f1W, f1T, idx, DD, 512, DD * 512); return; }
  idx -= SZF;
  if (idx < SZF) { wt_one(f2W, f2T, idx, 512, DD, 512 * DD); return; }
}

// M[l][d][hh] = Sum_k cW2[d][k]*bW[l][k][hh]. Wave-parallel: one block per (l,d).
__global__ __launch_bounds__(64) void k_mbias_par(const float* __restrict__ cW2, const float* __restrict__ cb2,
                                                  const float* __restrict__ bW, const float* __restrict__ bb,
                                                  float* __restrict__ M, float* __restrict__ base) {
  int bid = blockIdx.x;
  int l = bid >> 7, d = bid & 127;
  int lane = threadIdx.x;
  int hh = lane >> 3, j0 = lane & 7;
  const float* bWl = bW + (size_t)l * DD * HH;
  float acc = 0.f;
#pragma unroll
  for (int t = 0; t < 16; t++) {
    int k = j0 + t * 8;
    acc = fmaf(cW2[d * DD + k], bWl[k * HH + hh], acc);
  }
#pragma unroll
  for (int off = 1; off <= 4; off <<= 1) acc += __shfl_xor(acc, off, 64);
  if (j0 == 0) M[(size_t)l * DD * HH + d * HH + hh] = acc;
  if (d == 0) {
    float bacc = 0.f;
#pragma unroll
    for (int t = 0; t < 16; t++) {
      int k = j0 + t * 8;
      bacc = fmaf(cb2[k], bWl[k * HH + hh], bacc);
    }
#pragma unroll
    for (int off = 1; off <= 4; off <<= 1) bacc += __shfl_xor(bacc, off, 64);
    if (j0 == 0) base[l * HH + hh] = bacc + bb[l * HH + hh];
  }
}

// sorted breakpoints + ranks — cW1/cb1 are layer-INDEPENDENT, computed once.
__global__ __launch_bounds__(128) void k_bp(const float* __restrict__ cW1, const float* __restrict__ cb1,
                                            float* __restrict__ bpg, int* __restrict__ posg) {
  __shared__ float x[DD], bp[DD];
  int tid = threadIdx.x;
  float c1v = cW1[tid], cbv = cb1[tid];
  x[tid] = (c1v == 0.f) ? __builtin_inff() : (-cbv / c1v);
  __syncthreads();
  float xv = x[tid]; int p = 0;
  for (int j = 0; j < DD; j++) {
    float xj = x[j];
    if (xj < xv || (xj == xv && j < tid)) p++;
  }
  bp[p] = xv;
  posg[tid] = p;
  __syncthreads();
  bpg[tid] = bp[tid];
}

// PWL table, wave-parallel: one block per (l, segment).
__global__ __launch_bounds__(64) void k_pwl_tab(const float* __restrict__ cW1, const float* __restrict__ cb1,
    const int* __restrict__ posg, const float* __restrict__ Mb, const float* __restrict__ basel,
    float* __restrict__ slopeg, float* __restrict__ interg) {
  int bid = blockIdx.x;
  int l = bid / NSEG, s = bid - l * NSEG;
  int lane = threadIdx.x;
  int hh = lane >> 3, j0 = lane & 7;
  const float* M = Mb + (size_t)l * DD * HH;
  float sl = 0.f, in = 0.f;
#pragma unroll
  for (int t = 0; t < 16; t++) {
    int d = j0 + t * 8;
    float cv = cW1[d], cbv = cb1[d];
    int p = posg[d];
    bool act = (cv == 0.f) ? (cbv > 0.f) : ((cv > 0.f) ? (p < s) : (p >= s));
    float m = act ? M[d * HH + hh] : 0.f;
    sl = fmaf(cv, m, sl);
    in = fmaf(cbv, m, in);
  }
#pragma unroll
  for (int off = 1; off <= 4; off <<= 1) {
    sl += __shfl_xor(sl, off, 64);
    in += __shfl_xor(in, off, 64);
  }
  if (j0 == 0) {
    size_t o = (size_t)l * NSEG * HH + s * HH + hh;
    slopeg[o] = sl;
    interg[o] = in + basel[l * HH + hh];
  }
}

__global__ void k_bounds(const int* __restrict__ batch, int* __restrict__ gstart, int* __restrict__ gend) {
  int n = blockIdx.x * 256 + threadIdx.x;
  if (n >= NN) return;
  int b = batch[n];
  if (n == 0 || batch[n - 1] != b) gstart[b] = n;
  if (n == NN - 1 || batch[n + 1] != b) gend[b] = n + 1;
}

// parallel pool: 256 nodes/block, running sums flushed at graph boundaries
__global__ __launch_bounds__(256) void k_pool_part(const float* __restrict__ h,
    const int* __restrict__ batch, float* __restrict__ gpool) {
  int tid = threadIdx.x;
  int d = tid & 127, sub = tid >> 7;
  int n0 = blockIdx.x * 256;
  int nend = n0 + 256; if (nend > NN) nend = NN;
  float run = 0.f; int gcur = -1;
  for (int n = n0 + sub; n < nend; n += 2) {
    int g = batch[n];
    if (g != gcur) {
      if (gcur >= 0) atomicAdd(gpool + (size_t)gcur * DD + d, run);
      run = 0.f; gcur = g;
    }
    run += h[(size_t)n * DD + d];
  }
  if (gcur >= 0) atomicAdd(gpool + (size_t)gcur * DD + d, run);
}

__global__ __launch_bounds__(256) void k_head(const float* __restrict__ gpool,
    const int* __restrict__ gstart, const int* __restrict__ gend,
    const float* __restrict__ W1, const float* __restrict__ b1,
    const float* __restrict__ W2, const float* __restrict__ b2, float* __restrict__ out) {
  __shared__ float mid[NG * 64];
  int tid = threadIdx.x;
  for (int idx = tid; idx < NG * 64; idx += 256) {
    int g = idx >> 6, j = idx & 63;
    int cnt = gend[g] - gstart[g]; if (cnt < 1) cnt = 1;
    float rc = 1.0f / (float)cnt;
    float acc = 0.f;
    for (int d = 0; d < DD; d++) acc = fmaf(gpool[g * DD + d], W1[d * 64 + j], acc);
    mid[idx] = fmaxf(fmaf(acc, rc, b1[j]), 0.f);
  }
  __syncthreads();
  if (tid < NG) {
    float acc = b2[0];
    for (int j = 0; j < 64; j++) acc = fmaf(mid[tid * 64 + j], W2[j], acc);
    out[tid] = acc;
  }
}

// ---------- launch ----------
extern "C" void kernel_launch(void* const* d_in, const int* in_sizes, int n_in,
                              void* d_out, int out_size, void* d_ws, size_t ws_size,
                              hipStream_t stream) {
  const float* x      = (const float*)d_in[0];
  const int*   ei     = (const int*)d_in[1];
  const int*   batch  = (const int*)d_in[2];
  const float* node_W = (const float*)d_in[3];
  const float* node_b = (const float*)d_in[4];
  const float* cW1    = (const float*)d_in[5];
  const float* cb1    = (const float*)d_in[6];
  const float* cW2    = (const float*)d_in[7];
  const float* cb2    = (const float*)d_in[8];
  const float* qW     = (const float*)d_in[9];
  const float* qb     = (const float*)d_in[10];
  const float* kW     = (const float*)d_in[11];
  const float* kb     = (const float*)d_in[12];
  const float* vW     = (const float*)d_in[13];
  const float* vb     = (const float*)d_in[14];
  const float* oW     = (const float*)d_in[15];
  const float* ob     = (const float*)d_in[16];
  const float* bW     = (const float*)d_in[17];
  const float* bb     = (const float*)d_in[18];
  const float* f1W    = (const float*)d_in[19];
  const float* f1b    = (const float*)d_in[20];
  const float* f2W    = (const float*)d_in[21];
  const float* f2b    = (const float*)d_in[22];
  const float* n1s    = (const float*)d_in[23];
  const float* n1b    = (const float*)d_in[24];
  const float* n2s    = (const float*)d_in[25];
  const float* n2b    = (const float*)d_in[26];
  const float* outW1  = (const float*)d_in[27];
  const float* outb1  = (const float*)d_in[28];
  const float* outW2  = (const float*)d_in[29];
  const float* outb2  = (const float*)d_in[30];

  const int* src = ei;
  const int* tgt = ei + NE;

  char* wp = (char*)d_ws;
  auto alloc = [&](size_t bytes) { void* p = (void*)wp; wp += (bytes + 255) & ~(size_t)255; return p; };
  float*    h       = (float*)alloc((size_t)NN * DD * 4);
  ushort*   q       = (ushort*)alloc((size_t)NN * DD * 2);
  ushort*   kk      = (ushort*)alloc((size_t)NN * DD * 2);
  ushort*   v       = (ushort*)alloc((size_t)NN * DD * 2);
  ushort*   aggmb   = (ushort*)alloc((size_t)NN * DD * 2);
  float*    sim     = (float*)alloc((size_t)NE * 4);
  float*    dist    = (float*)alloc((size_t)NE * 4);
  float*    escore  = (float*)alloc((size_t)NE * HH * 4);
  float*    Mb      = (float*)alloc((size_t)NL * DD * HH * 4);
  float*    basel   = (float*)alloc((size_t)NL * HH * 4);
  float*    bpg     = (float*)alloc((size_t)DD * 4);
  int*      posg    = (int*)alloc((size_t)DD * 4);
  float*    slopeg  = (float*)alloc((size_t)NL * NSEG * HH * 4);
  float*    interg  = (float*)alloc((size_t)NL * NSEG * HH * 4);
  int*      rowstart= (int*)alloc((size_t)(NN + 1) * 4);
  int*      rowstart_t = (int*)alloc((size_t)(NN + 1) * 4);
  int*      eid_t   = (int*)alloc((size_t)NE * 4);
  int*      src_s   = (int*)alloc((size_t)NE * 4);
  int*      tgt_s   = (int*)alloc((size_t)NE * 4);
  int*      cnt     = (int*)alloc((size_t)NN * 4);
  int*      cur     = (int*)alloc((size_t)NN * 4);
  int*      cnt_t   = (int*)alloc((size_t)NN * 4);
  int*      cur_t   = (int*)alloc((size_t)NN * 4);
  int*      bsum    = (int*)alloc((size_t)NBS * 4);
  int*      bsum_t  = (int*)alloc((size_t)NBS * 4);
  int*      boff    = (int*)alloc((size_t)256 * 4);
  int*      boff_t  = (int*)alloc((size_t)256 * 4);
  int*      gstart  = (int*)alloc((size_t)NG * 4);
  int*      gend    = (int*)alloc((size_t)NG * 4);
  float*    gpool   = (float*)alloc((size_t)NG * DD * 4);
  ushort*   qkvT    = (ushort*)alloc((size_t)NL * 3 * DD * DD * 2);
  ushort*   oT      = (ushort*)alloc((size_t)NL * DD * DD * 2);
  ushort*   f1T     = (ushort*)alloc((size_t)NL * DD * 512 * 2);
  ushort*   f2T     = (ushort*)alloc((size_t)NL * 512 * DD * 2);
  (void)in_sizes; (void)n_in; (void)out_size; (void)ws_size;

  // once-per-call setup (consolidated: 14 dispatches, was 29)
  k_zero<<<NBS, 256, 0, stream>>>(cnt, cur, cnt_t, cur_t, gstart, gend, gpool);
  k_hist2<<<(NE + 255) / 256, 256, 0, stream>>>(src, tgt, cnt, cnt_t);
  k_scan_blk2<<<2 * NBS, 256, 0, stream>>>(cnt, cnt_t, bsum, bsum_t);
  k_scan_top2<<<2, 256, 0, stream>>>(bsum, bsum_t, boff, boff_t, rowstart, rowstart_t);
  k_scan_fin2<<<2 * NBS, 256, 0, stream>>>(cnt, cnt_t, boff, boff_t, rowstart, rowstart_t);
  k_fill<<<(NE + 255) / 256, 256, 0, stream>>>(src, tgt, rowstart, cur, src_s, tgt_s);
  k_fill_t<<<(NE + 255) / 256, 256, 0, stream>>>(tgt_s, rowstart_t, cur_t, eid_t);
  k_mbias_par<<<NL * DD, 64, 0, stream>>>(cW2, cb2, bW, bb, Mb, basel);
  k_bp<<<1, 128, 0, stream>>>(cW1, cb1, bpg, posg);
  k_pwl_tab<<<NL * NSEG, 64, 0, stream>>>(cW1, cb1, posg, Mb, basel, slopeg, interg);
  k_bounds<<<(NN + 255) / 256, 256, 0, stream>>>(batch, gstart, gend);
  k_wt_all<<<(4 * NL * DD * DD + 2 * NL * DD * 512 + 255) / 256, 256, 0, stream>>>(
      qW, kW, vW, oW, f1W, f2W, qkvT, oT, f1T, f2T);
  k_node_proj<<<NT32, 256, 0, stream>>>(x, node_W, node_b, h);
  // layer-0 qkv from standalone LN1+QKV
  k_ln_qkv<<<NT32, 512, 0, stream>>>(h, n1s, n1b, qkvT, qb, kb, vb, q, kk, v);

  for (int l = 0; l < NL; l++) {
    k_edge1<<<(NE * 8 + 255) / 256, 256, 0, stream>>>(src_s, tgt_s, h, sim, dist);
    k_scores_sm<<<NT4, 256, 0, stream>>>(src_s, rowstart_t, eid_t, q, kk,
        sim, dist, bpg,
        slopeg + (size_t)l * NSEG * HH, interg + (size_t)l * NSEG * HH,
        escore);
    k_agg<<<NN / 4, 256, 0, stream>>>(tgt_s, rowstart, escore, v, aggmb);
    int ln = l < NL - 1 ? l + 1 : l;   // next-layer params (unused when do_qkv=0)
    k_attn_ffn<<<NT64, 512, 0, stream>>>(aggmb, oT + (size_t)l * DD * DD, ob + l * DD,
        n2s + l * DD, n2b + l * DD,
        f1T + (size_t)l * DD * 512, f1b + (size_t)l * 4 * DD,
        f2T + (size_t)l * 512 * DD, f2b + l * DD, h,
        (l < NL - 1) ? 1 : 0,
        n1s + ln * DD, n1b + ln * DD,
        qkvT + (size_t)ln * 3 * DD * DD,
        qb + ln * DD, kb + ln * DD, vb + ln * DD,
        q, kk, v);
  }
  k_pool_part<<<(NN + 255) / 256, 256, 0, stream>>>(h, batch, gpool);
  k_head<<<1, 256, 0, stream>>>(gpool, gstart, gend, outW1, outb1, outW2, outb2, (float*)d_out);
}

// Round 23
// 1271.140 us; speedup vs baseline: 1.0491x; 1.0060x over previous
//
#include <hip/hip_runtime.h>

#define NN 50000      // nodes
#define NE 625000     // edges
#define DD 128        // hidden dim
#define HH 8          // heads
#define DHH 16        // head dim
#define NL 4          // layers
#define FIN 64        // in channels
#define NG 64         // graphs
#define LN_EPS 1e-5f
#define NSEG 129      // PWL segments = 128 breakpoints + 1
#define NT32 1563     // ceil(NN/32)
#define NT4 12500     // NN/4 (nodes per 4-wave block in k_scores_sm)
#define NBS 196       // ceil(NN/256) scan blocks
#define HLP 132       // hL padded row stride (floats): +4 breaks bank conflicts

typedef __bf16 bf16x8_t __attribute__((ext_vector_type(8)));
typedef unsigned short ushort8_t __attribute__((ext_vector_type(8)));
typedef float f32x4_t __attribute__((ext_vector_type(4)));
union BF8 { ushort8_t u; bf16x8_t b; };

// ---------- helpers ----------
__device__ __forceinline__ void fma4(float4& a, float s, float4 w) {
  a.x = fmaf(s, w.x, a.x); a.y = fmaf(s, w.y, a.y);
  a.z = fmaf(s, w.z, a.z); a.w = fmaf(s, w.w, a.w);
}
__device__ __forceinline__ unsigned short f2bf(float f) {   // RNE f32->bf16
  unsigned u = __float_as_uint(f);
  unsigned r = ((u >> 16) & 1u) + 0x7FFFu;
  return (unsigned short)((u + r) >> 16);
}
__device__ __forceinline__ float bf2f(unsigned short u) {
  return __uint_as_float((unsigned)u << 16);
}

// LayerNorm 32 nodes -> swizzled bf16 LDS tile [32][128]; block = 512 threads.
__device__ __forceinline__ void ln_tile_bf32(const float* __restrict__ h, int nb,
                                             const float* __restrict__ sc,
                                             const float* __restrict__ bi,
                                             ushort* xbf) {
  int tid = threadIdx.x;
  int r = tid >> 4, l16 = tid & 15;
  int nr = nb + r; if (nr >= NN) nr = NN - 1;   // clamp: tail rows unused
  const float* hp = h + (size_t)nr * DD + l16 * 8;
  float4 a0 = *(const float4*)hp;
  float4 a1 = *(const float4*)(hp + 4);
  float sum = a0.x + a0.y + a0.z + a0.w + a1.x + a1.y + a1.z + a1.w;
  float sq  = a0.x*a0.x + a0.y*a0.y + a0.z*a0.z + a0.w*a0.w
            + a1.x*a1.x + a1.y*a1.y + a1.z*a1.z + a1.w*a1.w;
#pragma unroll
  for (int off = 8; off >= 1; off >>= 1) {
    sum += __shfl_xor(sum, off, 64);
    sq  += __shfl_xor(sq,  off, 64);
  }
  float mu   = sum * (1.0f / DD);
  float var  = sq * (1.0f / DD) - mu * mu;
  float rstd = rsqrtf(var + LN_EPS);
  int d0 = l16 * 8;
  float4 s0 = *(const float4*)(sc + d0), s1 = *(const float4*)(sc + d0 + 4);
  float4 b0 = *(const float4*)(bi + d0), b1 = *(const float4*)(bi + d0 + 4);
  ushort8_t u;
  u[0] = f2bf((a0.x - mu) * rstd * s0.x + b0.x);
  u[1] = f2bf((a0.y - mu) * rstd * s0.y + b0.y);
  u[2] = f2bf((a0.z - mu) * rstd * s0.z + b0.z);
  u[3] = f2bf((a0.w - mu) * rstd * s0.w + b0.w);
  u[4] = f2bf((a1.x - mu) * rstd * s1.x + b1.x);
  u[5] = f2bf((a1.y - mu) * rstd * s1.y + b1.y);
  u[6] = f2bf((a1.z - mu) * rstd * s1.z + b1.z);
  u[7] = f2bf((a1.w - mu) * rstd * s1.w + b1.w);
  int off = (r * 256 + l16 * 16) ^ ((r & 7) << 4);
  *(ushort8_t*)((char*)xbf + off) = u;
}

// ---------- kernels ----------
// h = x @ node_W + node_b ; 32 nodes/block, W staged in LDS.
__global__ __launch_bounds__(256) void k_node_proj(const float* __restrict__ x,
                                                   const float* __restrict__ W,
                                                   const float* __restrict__ b,
                                                   float* __restrict__ h) {
  __shared__ float Wl[FIN * DD];    // 32 KB
  __shared__ float xt[32][FIN];     // 8 KB
  int tid = threadIdx.x;
  int nb = blockIdx.x * 32;
  for (int i = tid * 4; i < FIN * DD; i += 1024)
    *(float4*)&Wl[i] = *(const float4*)(W + i);
  for (int i = tid * 4; i < 32 * FIN; i += 1024) {
    int row = i >> 6, cc = i & 63;
    int node = nb + row; if (node >= NN) node = NN - 1;
    *(float4*)&xt[row][cc] = *(const float4*)(x + (size_t)node * FIN + cc);
  }
  __syncthreads();
  int c4 = (tid & 31) * 4;
  int r0 = (tid >> 5) * 4;
  float4 bv = *(const float4*)(b + c4);
  float4 a0 = bv, a1 = bv, a2 = bv, a3 = bv;
  for (int k = 0; k < FIN; k++) {
    float4 wv = *(const float4*)&Wl[k * DD + c4];
    fma4(a0, xt[r0][k], wv);
    fma4(a1, xt[r0 + 1][k], wv);
    fma4(a2, xt[r0 + 2][k], wv);
    fma4(a3, xt[r0 + 3][k], wv);
  }
  int n0 = nb + r0;
  if (n0 < NN)     *(float4*)(h + (size_t)n0 * DD + c4) = a0;
  if (n0 + 1 < NN) *(float4*)(h + (size_t)(n0 + 1) * DD + c4) = a1;
  if (n0 + 2 < NN) *(float4*)(h + (size_t)(n0 + 2) * DD + c4) = a2;
  if (n0 + 3 < NN) *(float4*)(h + (size_t)(n0 + 3) * DD + c4) = a3;
}

// per sorted edge: sim (dot), dist (norm) in fp32. 8 lanes/edge.
__global__ __launch_bounds__(256) void k_edge1(const int* __restrict__ src_s, const int* __restrict__ tgt_s,
                                               const float* __restrict__ h, float* __restrict__ sim,
                                               float* __restrict__ dist) {
  int gid = blockIdx.x * 256 + threadIdx.x;
  int e = gid >> 3;
  if (e >= NE) return;
  int j = gid & 7;
  int s = src_s[e], t = tgt_s[e];
  const float4* ap = (const float4*)(h + (size_t)s * DD + j * 16);
  const float4* bp = (const float4*)(h + (size_t)t * DD + j * 16);
  float4 a0 = ap[0], a1 = ap[1], a2 = ap[2], a3 = ap[3];
  float4 b0 = bp[0], b1 = bp[1], b2 = bp[2], b3 = bp[3];
  float dot = 0.f, sq = 0.f;
  dot = fmaf(a0.x, b0.x, dot); dot = fmaf(a0.y, b0.y, dot);
  dot = fmaf(a0.z, b0.z, dot); dot = fmaf(a0.w, b0.w, dot);
  dot = fmaf(a1.x, b1.x, dot); dot = fmaf(a1.y, b1.y, dot);
  dot = fmaf(a1.z, b1.z, dot); dot = fmaf(a1.w, b1.w, dot);
  dot = fmaf(a2.x, b2.x, dot); dot = fmaf(a2.y, b2.y, dot);
  dot = fmaf(a2.z, b2.z, dot); dot = fmaf(a2.w, b2.w, dot);
  dot = fmaf(a3.x, b3.x, dot); dot = fmaf(a3.y, b3.y, dot);
  dot = fmaf(a3.z, b3.z, dot); dot = fmaf(a3.w, b3.w, dot);
  float d;
  d = a0.x - b0.x; sq = fmaf(d, d, sq); d = a0.y - b0.y; sq = fmaf(d, d, sq);
  d = a0.z - b0.z; sq = fmaf(d, d, sq); d = a0.w - b0.w; sq = fmaf(d, d, sq);
  d = a1.x - b1.x; sq = fmaf(d, d, sq); d = a1.y - b1.y; sq = fmaf(d, d, sq);
  d = a1.z - b1.z; sq = fmaf(d, d, sq); d = a1.w - b1.w; sq = fmaf(d, d, sq);
  d = a2.x - b2.x; sq = fmaf(d, d, sq); d = a2.y - b2.y; sq = fmaf(d, d, sq);
  d = a2.z - b2.z; sq = fmaf(d, d, sq); d = a2.w - b2.w; sq = fmaf(d, d, sq);
  d = a3.x - b3.x; sq = fmaf(d, d, sq); d = a3.y - b3.y; sq = fmaf(d, d, sq);
  d = a3.z - b3.z; sq = fmaf(d, d, sq); d = a3.w - b3.w; sq = fmaf(d, d, sq);
#pragma unroll
  for (int off = 4; off >= 1; off >>= 1) {
    dot += __shfl_xor(dot, off, 64);
    sq  += __shfl_xor(sq,  off, 64);
  }
  if (j == 0) {
    sim[e]  = dot;                  // BETA == 1.0
    dist[e] = sqrtf(sq);
  }
}

// LN1 + QKV projection via swapped-operand MFMA -> bf16 q/k/v. 32 rows/block, 8 waves.
// Used only for layer 0 (layers 1..3 get qkv from k_attn_ffn stage 5).
__global__ __launch_bounds__(512) void k_ln_qkv(const float* __restrict__ h,
    const float* __restrict__ n1s_l, const float* __restrict__ n1b_l,
    const ushort* __restrict__ qkvT_l,
    const float* __restrict__ qb_l, const float* __restrict__ kb_l, const float* __restrict__ vb_l,
    ushort* __restrict__ q, ushort* __restrict__ kk, ushort* __restrict__ v) {
  __shared__ __align__(16) ushort xbf[32 * DD];
  int nb = blockIdx.x * 32;
  ln_tile_bf32(h, nb, n1s_l, n1b_l, xbf);
  __syncthreads();
  int lane = threadIdx.x & 63;
  int w = threadIdx.x >> 6;
  int g = lane >> 4, c = lane & 15;
  int xr = (c & 7) << 4;
  char* xb = (char*)xbf;
  BF8 a[2][4];
#pragma unroll
  for (int nt = 0; nt < 2; nt++)
#pragma unroll
    for (int kt = 0; kt < 4; kt++)
      a[nt][kt].u = *(ushort8_t*)(xb + (((nt * 16 + c) * 256 + kt * 64 + g * 16) ^ xr));
#pragma unroll
  for (int ti = 0; ti < 3; ti++) {
    int t = w * 3 + ti;                // 0..23
    int m = t >> 3;                    // 0=q 1=k 2=v
    int colb = (t & 7) * 16;
    const float* bias = (m == 0 ? qb_l : (m == 1 ? kb_l : vb_l));
    float4 bv = *(const float4*)(bias + colb + g * 4);
    f32x4_t acc0 = {bv.x, bv.y, bv.z, bv.w};
    f32x4_t acc1 = acc0;
    const ushort* wp = qkvT_l + (size_t)(m * DD + colb + c) * DD + g * 8;
#pragma unroll
    for (int kt = 0; kt < 4; kt++) {
      BF8 b; b.u = *(const ushort8_t*)(wp + kt * 32);
      acc0 = __builtin_amdgcn_mfma_f32_16x16x32_bf16(b.b, a[0][kt].b, acc0, 0, 0, 0);
      acc1 = __builtin_amdgcn_mfma_f32_16x16x32_bf16(b.b, a[1][kt].b, acc1, 0, 0, 0);
    }
    ushort* out = (m == 0 ? q : (m == 1 ? kk : v));
    int n0 = nb + c;
    if (n0 < NN) {
      ushort4 o; o.x = f2bf(acc0[0]); o.y = f2bf(acc0[1]); o.z = f2bf(acc0[2]); o.w = f2bf(acc0[3]);
      *(ushort4*)(out + (size_t)n0 * DD + colb + g * 4) = o;
    }
    int n1 = nb + 16 + c;
    if (n1 < NN) {
      ushort4 o; o.x = f2bf(acc1[0]); o.y = f2bf(acc1[1]); o.z = f2bf(acc1[2]); o.w = f2bf(acc1[3]);
      *(ushort4*)(out + (size_t)n1 * DD + colb + g * 4) = o;
    }
  }
}

// FUSED curvature + scores + softmax, 64 lanes/node.
__global__ __launch_bounds__(256) void k_scores_sm(const int* __restrict__ src_s,
    const int* __restrict__ rowstart_t, const int* __restrict__ eid_t,
    const ushort* __restrict__ q, const ushort* __restrict__ k,
    const float* __restrict__ sim, const float* __restrict__ dist,
    const float* __restrict__ bp_g,
    const float* __restrict__ slope_l, const float* __restrict__ inter_l,
    float* __restrict__ escore) {
  __shared__ float lsl[NSEG * HH], lin[NSEG * HH], bp[DD];
  int tid = threadIdx.x;
  for (int idx = tid; idx < NSEG * HH; idx += 256) { lsl[idx] = slope_l[idx]; lin[idx] = inter_l[idx]; }
  if (tid < DD) bp[tid] = bp_g[tid];
  __syncthreads();
  int node = blockIdx.x * 4 + (tid >> 6);
  if (node >= NN) return;
  int lane = tid & 63;
  int rs = rowstart_t[node], re = rowstart_t[node + 1];
  // ---- Phase A: aggv (all 64 lanes)
  float msim = -3.4e38f;
  for (int i = rs + lane; i < re; i += 64) msim = fmaxf(msim, sim[eid_t[i]]);
#pragma unroll
  for (int off = 1; off <= 32; off <<= 1) msim = fmaxf(msim, __shfl_xor(msim, off, 64));
  float den = 0.f, nd = 0.f;
  for (int i = rs + lane; i < re; i += 64) {
    int e = eid_t[i];
    float ev = expf(sim[e] - msim);
    den += ev;
    nd = fmaf(ev, dist[e], nd);
  }
#pragma unroll
  for (int off = 1; off <= 32; off <<= 1) {
    den += __shfl_xor(den, off, 64);
    nd  += __shfl_xor(nd,  off, 64);
  }
  float av = den > 0.f ? nd / den : 0.f;
  // ---- Phase B: raw scores + online (m, sum)
  int hh = lane & 7;
  int eidx = lane >> 3;
  const ushort8_t* kp = (const ushort8_t*)(k + (size_t)node * DD + hh * DHH);
  ushort8_t k0 = kp[0], k1 = kp[1];
  float m = -3.4e38f, ssum = 0.f;
  for (int i = rs + eidx; i < re; i += 8) {
    int e = eid_t[i];
    int s = src_s[e];
    float dd = dist[e];
    const ushort8_t* qp = (const ushort8_t*)(q + (size_t)s * DD + hh * DHH);
    ushort8_t q0 = qp[0], q1 = qp[1];
    float curv = 1.0f - av / fmaxf(dd, 1e-6f);
    int lo = 0, hi = DD;
    while (lo < hi) { int mid = (lo + hi) >> 1; if (bp[mid] < curv) lo = mid + 1; else hi = mid; }
    float bias = fmaf(lsl[lo * HH + hh], curv, lin[lo * HH + hh]);
    float dot = 0.f;
#pragma unroll
    for (int jj = 0; jj < 8; jj++) dot = fmaf(bf2f(q0[jj]), bf2f(k0[jj]), dot);
#pragma unroll
    for (int jj = 0; jj < 8; jj++) dot = fmaf(bf2f(q1[jj]), bf2f(k1[jj]), dot);
    float sc = dot * 0.25f + bias;   // 1/sqrt(16)
    escore[e * HH + hh] = sc;
    float mn = fmaxf(m, sc);
    ssum = ssum * expf(m - mn) + expf(sc - mn);
    m = mn;
  }
  // ---- Phase C: combine (m, s) across the 8 edge-lane groups
#pragma unroll
  for (int off = 8; off <= 32; off <<= 1) {
    float m2 = __shfl_xor(m, off, 64);
    float s2 = __shfl_xor(ssum, off, 64);
    float M = fmaxf(m, m2);
    ssum = ssum * expf(m - M) + s2 * expf(m2 - M);
    m = M;
  }
  float inv = ssum > 0.f ? 1.0f / ssum : 0.f;
  // ---- Phase D: rewrite own raw scores as final probabilities
  for (int i = rs + eidx; i < re; i += 8) {
    size_t idx = (size_t)eid_t[i] * HH + hh;
    float sc = escore[idx];
    escore[idx] = expf(sc - m) * inv;
  }
}

// CSR-gather message aggregation: one wave per src node, 2 dims/lane -> bf16 out.
__global__ __launch_bounds__(256) void k_agg(const int* __restrict__ tgt_s,
    const int* __restrict__ rowstart,
    const float* __restrict__ escore,
    const ushort* __restrict__ v, ushort* __restrict__ aggmb) {
  int wave = (blockIdx.x * 256 + threadIdx.x) >> 6;
  int lane = threadIdx.x & 63;
  int rs = rowstart[wave], re = rowstart[wave + 1];
  int hh = lane >> 3;
  int d = lane * 2;
  float a0 = 0.f, a1 = 0.f;
  int i = rs;
  for (; i + 4 <= re; i += 4) {
    int t0 = tgt_s[i], t1 = tgt_s[i + 1], t2 = tgt_s[i + 2], t3 = tgt_s[i + 3];
    float p0 = escore[(i    ) * HH + hh];
    float p1 = escore[(i + 1) * HH + hh];
    float p2 = escore[(i + 2) * HH + hh];
    float p3 = escore[(i + 3) * HH + hh];
    ushort2 v0 = *(const ushort2*)(v + (size_t)t0 * DD + d);
    ushort2 v1 = *(const ushort2*)(v + (size_t)t1 * DD + d);
    ushort2 v2 = *(const ushort2*)(v + (size_t)t2 * DD + d);
    ushort2 v3 = *(const ushort2*)(v + (size_t)t3 * DD + d);
    a0 = fmaf(p0, bf2f(v0.x), a0); a1 = fmaf(p0, bf2f(v0.y), a1);
    a0 = fmaf(p1, bf2f(v1.x), a0); a1 = fmaf(p1, bf2f(v1.y), a1);
    a0 = fmaf(p2, bf2f(v2.x), a0); a1 = fmaf(p2, bf2f(v2.y), a1);
    a0 = fmaf(p3, bf2f(v3.x), a0); a1 = fmaf(p3, bf2f(v3.y), a1);
  }
  for (; i < re; i++) {
    int t = tgt_s[i];
    float prob = escore[i * HH + hh];
    ushort2 vv = *(const ushort2*)(v + (size_t)t * DD + d);
    a0 = fmaf(prob, bf2f(vv.x), a0);
    a1 = fmaf(prob, bf2f(vv.y), a1);
  }
  ushort2 o; o.x = f2bf(a0); o.y = f2bf(a1);
  *(ushort2*)(aggmb + (size_t)wave * DD + d) = o;
}

// FUSED: h' = h + aggm@oW + ob -> LN2 -> FFN -> h = h' + FFN, then stage-5 QKV.
// r23: 256 threads / 32 nodes per block (was 512/64). Grid 1563, LDS 25KB ->
// ~6 blocks/CU so independent blocks' load/MFMA phases interleave (attacks the
// 875GB/s phase-gap). Per-element MFMA/fma chain order unchanged -> bit-exact.
__global__ __launch_bounds__(256) void k_attn_ffn(const ushort* __restrict__ aggmb,
    const ushort* __restrict__ oT_l, const float* __restrict__ ob_l,
    const float* __restrict__ n2s_l, const float* __restrict__ n2b_l,
    const ushort* __restrict__ f1T_l, const float* __restrict__ f1b_l,
    const ushort* __restrict__ f2T_l, const float* __restrict__ f2b_l,
    float* __restrict__ h,
    int do_qkv,
    const float* __restrict__ n1s_n, const float* __restrict__ n1b_n,
    const ushort* __restrict__ qkvT_n,
    const float* __restrict__ qb_n, const float* __restrict__ kb_n, const float* __restrict__ vb_n,
    ushort* __restrict__ q, ushort* __restrict__ kk, ushort* __restrict__ v) {
  __shared__ float hL[32 * HLP];                      // 16.5 KB
  __shared__ __align__(16) char ubuf[32 * 128 * 2];   // 8 KB union: xbf / tbf / xbf(qkv)
  char* xb = ubuf;
  char* tb = ubuf;
  int nb = blockIdx.x * 32;
  int tid = threadIdx.x;
  int lane = tid & 63, w = tid >> 6;       // w = 0..3
  int g = lane >> 4, c = lane & 15;
  int xr = (c & 7) << 4;
  int colb0 = (w * 2) * 16, colb1 = (w * 2 + 1) * 16;
  // ---- Stage 1: O-projection + residual -> hL (2 col-tiles x 2 node-tiles per wave)
#pragma unroll
  for (int ti = 0; ti < 2; ti++) {
    int colb = (w * 2 + ti) * 16;
    float4 obv = *(const float4*)(ob_l + colb + g * 4);
    const ushort* wp = oT_l + (size_t)(colb + c) * DD + g * 8;
    BF8 b0, b1, b2, b3;
    b0.u = *(const ushort8_t*)(wp);
    b1.u = *(const ushort8_t*)(wp + 32);
    b2.u = *(const ushort8_t*)(wp + 64);
    b3.u = *(const ushort8_t*)(wp + 96);
#pragma unroll
    for (int nt = 0; nt < 2; nt++) {
      int node = nb + nt * 16 + c;
      int na = node < NN ? node : NN - 1;
      const ushort* ap = aggmb + (size_t)na * DD + g * 8;
      BF8 a0, a1, a2, a3;
      a0.u = *(const ushort8_t*)(ap);
      a1.u = *(const ushort8_t*)(ap + 32);
      a2.u = *(const ushort8_t*)(ap + 64);
      a3.u = *(const ushort8_t*)(ap + 96);
      f32x4_t acc = {obv.x, obv.y, obv.z, obv.w};
      acc = __builtin_amdgcn_mfma_f32_16x16x32_bf16(b0.b, a0.b, acc, 0, 0, 0);
      acc = __builtin_amdgcn_mfma_f32_16x16x32_bf16(b1.b, a1.b, acc, 0, 0, 0);
      acc = __builtin_amdgcn_mfma_f32_16x16x32_bf16(b2.b, a2.b, acc, 0, 0, 0);
      acc = __builtin_amdgcn_mfma_f32_16x16x32_bf16(b3.b, a3.b, acc, 0, 0, 0);
      float4 hv = *(const float4*)(h + (size_t)na * DD + colb + g * 4);
      hv.x += acc[0]; hv.y += acc[1]; hv.z += acc[2]; hv.w += acc[3];
      *(float4*)&hL[(nt * 16 + c) * HLP + colb + g * 4] = hv;
    }
  }
  __syncthreads();
  // ---- Stage 2: LN2 from hL -> xbf (32 rows, 16 rows/pass)
  {
    int l16 = tid & 15;
    int d0 = l16 * 8;
    float4 s0 = *(const float4*)(n2s_l + d0), s1 = *(const float4*)(n2s_l + d0 + 4);
    float4 bb0 = *(const float4*)(n2b_l + d0), bb1 = *(const float4*)(n2b_l + d0 + 4);
#pragma unroll
    for (int p = 0; p < 2; p++) {
      int r = p * 16 + (tid >> 4);
      const float* hp = &hL[r * HLP + d0];
      float4 a0 = *(const float4*)hp;
      float4 a1 = *(const float4*)(hp + 4);
      float sum = a0.x + a0.y + a0.z + a0.w + a1.x + a1.y + a1.z + a1.w;
      float sq  = a0.x*a0.x + a0.y*a0.y + a0.z*a0.z + a0.w*a0.w
                + a1.x*a1.x + a1.y*a1.y + a1.z*a1.z + a1.w*a1.w;
#pragma unroll
      for (int off = 8; off >= 1; off >>= 1) {
        sum += __shfl_xor(sum, off, 64);
        sq  += __shfl_xor(sq,  off, 64);
      }
      float mu   = sum * (1.0f / DD);
      float var  = sq * (1.0f / DD) - mu * mu;
      float rstd = rsqrtf(var + LN_EPS);
      ushort8_t u;
      u[0] = f2bf((a0.x - mu) * rstd * s0.x + bb0.x);
      u[1] = f2bf((a0.y - mu) * rstd * s0.y + bb0.y);
      u[2] = f2bf((a0.z - mu) * rstd * s0.z + bb0.z);
      u[3] = f2bf((a0.w - mu) * rstd * s0.w + bb0.w);
      u[4] = f2bf((a1.x - mu) * rstd * s1.x + bb1.x);
      u[5] = f2bf((a1.y - mu) * rstd * s1.y + bb1.y);
      u[6] = f2bf((a1.z - mu) * rstd * s1.z + bb1.z);
      u[7] = f2bf((a1.w - mu) * rstd * s1.w + bb1.w);
      int off = (r * 256 + l16 * 16) ^ ((r & 7) << 4);
      *(ushort8_t*)(xb + off) = u;
    }
  }
  __syncthreads();
  // A-frags from xbf (registers)
  BF8 a[2][4];
#pragma unroll
  for (int nt = 0; nt < 2; nt++)
#pragma unroll
    for (int kt = 0; kt < 4; kt++)
      a[nt][kt].u = *(ushort8_t*)(xb + (((nt * 16 + c) * 256 + kt * 64 + g * 16) ^ xr));
  __syncthreads();   // xbf dead; ubuf becomes tbf
  // ---- Stage 3: FFN, 4 chunks of 128 cols (tbf row stride 256B)
  float4 bv20 = *(const float4*)(f2b_l + colb0 + g * 4);
  float4 bv21 = *(const float4*)(f2b_l + colb1 + g * 4);
  f32x4_t o00 = {bv20.x, bv20.y, bv20.z, bv20.w};
  f32x4_t o01 = o00;
  f32x4_t o10 = {bv21.x, bv21.y, bv21.z, bv21.w};
  f32x4_t o11 = o10;
#pragma unroll
  for (int ch = 0; ch < 4; ch++) {
    if (ch) __syncthreads();           // tbf reuse: wait for prev-chunk reads
#pragma unroll
    for (int ti = 0; ti < 2; ti++) {
      int col = ch * 128 + (w * 2 + ti) * 16;
      float4 bv = *(const float4*)(f1b_l + col + g * 4);
      f32x4_t ac0 = {bv.x, bv.y, bv.z, bv.w};
      f32x4_t ac1 = ac0;
      const ushort* wp = f1T_l + (size_t)(col + c) * DD + g * 8;
#pragma unroll
      for (int kt = 0; kt < 4; kt++) {
        BF8 b; b.u = *(const ushort8_t*)(wp + kt * 32);
        ac0 = __builtin_amdgcn_mfma_f32_16x16x32_bf16(b.b, a[0][kt].b, ac0, 0, 0, 0);
        ac1 = __builtin_amdgcn_mfma_f32_16x16x32_bf16(b.b, a[1][kt].b, ac1, 0, 0, 0);
      }
      int colL = ((w * 2 + ti) * 16 + g * 4) * 2;
      {
        int row = c;
        ushort4 o4; o4.x = f2bf(fmaxf(ac0[0], 0.f)); o4.y = f2bf(fmaxf(ac0[1], 0.f));
        o4.z = f2bf(fmaxf(ac0[2], 0.f)); o4.w = f2bf(fmaxf(ac0[3], 0.f));
        *(ushort4*)(tb + ((row * 256 + colL) ^ ((row & 7) << 4))) = o4;
      }
      {
        int row = 16 + c;
        ushort4 o4; o4.x = f2bf(fmaxf(ac1[0], 0.f)); o4.y = f2bf(fmaxf(ac1[1], 0.f));
        o4.z = f2bf(fmaxf(ac1[2], 0.f)); o4.w = f2bf(fmaxf(ac1[3], 0.f));
        *(ushort4*)(tb + ((row * 256 + colL) ^ ((row & 7) << 4))) = o4;
      }
    }
    __syncthreads();
    const ushort* wp20 = f2T_l + (size_t)(colb0 + c) * 512 + ch * 128 + g * 8;
    const ushort* wp21 = f2T_l + (size_t)(colb1 + c) * 512 + ch * 128 + g * 8;
#pragma unroll
    for (int kt = 0; kt < 4; kt++) {
      BF8 t0; t0.u = *(ushort8_t*)(tb + (((c) * 256 + kt * 64 + g * 16) ^ xr));
      BF8 t1; t1.u = *(ushort8_t*)(tb + (((16 + c) * 256 + kt * 64 + g * 16) ^ xr));
      BF8 bA; bA.u = *(const ushort8_t*)(wp20 + kt * 32);
      o00 = __builtin_amdgcn_mfma_f32_16x16x32_bf16(bA.b, t0.b, o00, 0, 0, 0);
      o01 = __builtin_amdgcn_mfma_f32_16x16x32_bf16(bA.b, t1.b, o01, 0, 0, 0);
      BF8 bB; bB.u = *(const ushort8_t*)(wp21 + kt * 32);
      o10 = __builtin_amdgcn_mfma_f32_16x16x32_bf16(bB.b, t0.b, o10, 0, 0, 0);
      o11 = __builtin_amdgcn_mfma_f32_16x16x32_bf16(bB.b, t1.b, o11, 0, 0, 0);
    }
  }
  // ---- Stage 4: final residual from hL -> global h (and back into hL for stage 5)
  {
    float* lp = &hL[c * HLP + colb0 + g * 4];
    float4 hv = *(const float4*)lp;
    hv.x += o00[0]; hv.y += o00[1]; hv.z += o00[2]; hv.w += o00[3];
    *(float4*)lp = hv;
    int node = nb + c;
    if (node < NN) *(float4*)(h + (size_t)node * DD + colb0 + g * 4) = hv;
  }
  {
    float* lp = &hL[(16 + c) * HLP + colb0 + g * 4];
    float4 hv = *(const float4*)lp;
    hv.x += o01[0]; hv.y += o01[1]; hv.z += o01[2]; hv.w += o01[3];
    *(float4*)lp = hv;
    int node = nb + 16 + c;
    if (node < NN) *(float4*)(h + (size_t)node * DD + colb0 + g * 4) = hv;
  }
  {
    float* lp = &hL[c * HLP + colb1 + g * 4];
    float4 hv = *(const float4*)lp;
    hv.x += o10[0]; hv.y += o10[1]; hv.z += o10[2]; hv.w += o10[3];
    *(float4*)lp = hv;
    int node = nb + c;
    if (node < NN) *(float4*)(h + (size_t)node * DD + colb1 + g * 4) = hv;
  }
  {
    float* lp = &hL[(16 + c) * HLP + colb1 + g * 4];
    float4 hv = *(const float4*)lp;
    hv.x += o11[0]; hv.y += o11[1]; hv.z += o11[2]; hv.w += o11[3];
    *(float4*)lp = hv;
    int node = nb + 16 + c;
    if (node < NN) *(float4*)(h + (size_t)node * DD + colb1 + g * 4) = hv;
  }
  if (!do_qkv) return;
  __syncthreads();   // hL final visible; tbf reads done -> ubuf becomes xbf again
  // ---- Stage 5: LN1(next layer) from hL -> xbf
  {
    int l16 = tid & 15;
    int d0 = l16 * 8;
    float4 s0 = *(const float4*)(n1s_n + d0), s1 = *(const float4*)(n1s_n + d0 + 4);
    float4 bb0 = *(const float4*)(n1b_n + d0), bb1 = *(const float4*)(n1b_n + d0 + 4);
#pragma unroll
    for (int p = 0; p < 2; p++) {
      int r = p * 16 + (tid >> 4);
      const float* hp = &hL[r * HLP + d0];
      float4 a0 = *(const float4*)hp;
      float4 a1 = *(const float4*)(hp + 4);
      float sum = a0.x + a0.y + a0.z + a0.w + a1.x + a1.y + a1.z + a1.w;
      float sq  = a0.x*a0.x + a0.y*a0.y + a0.z*a0.z + a0.w*a0.w
                + a1.x*a1.x + a1.y*a1.y + a1.z*a1.z + a1.w*a1.w;
#pragma unroll
      for (int off = 8; off >= 1; off >>= 1) {
        sum += __shfl_xor(sum, off, 64);
        sq  += __shfl_xor(sq,  off, 64);
      }
      float mu   = sum * (1.0f / DD);
      float var  = sq * (1.0f / DD) - mu * mu;
      float rstd = rsqrtf(var + LN_EPS);
      ushort8_t u;
      u[0] = f2bf((a0.x - mu) * rstd * s0.x + bb0.x);
      u[1] = f2bf((a0.y - mu) * rstd * s0.y + bb0.y);
      u[2] = f2bf((a0.z - mu) * rstd * s0.z + bb0.z);
      u[3] = f2bf((a0.w - mu) * rstd * s0.w + bb0.w);
      u[4] = f2bf((a1.x - mu) * rstd * s1.x + bb1.x);
      u[5] = f2bf((a1.y - mu) * rstd * s1.y + bb1.y);
      u[6] = f2bf((a1.z - mu) * rstd * s1.z + bb1.z);
      u[7] = f2bf((a1.w - mu) * rstd * s1.w + bb1.w);
      int off = (r * 256 + l16 * 16) ^ ((r & 7) << 4);
      *(ushort8_t*)(xb + off) = u;
    }
  }
  __syncthreads();
  BF8 aq[2][4];
#pragma unroll
  for (int nt = 0; nt < 2; nt++)
#pragma unroll
    for (int kt = 0; kt < 4; kt++)
      aq[nt][kt].u = *(ushort8_t*)(xb + (((nt * 16 + c) * 256 + kt * 64 + g * 16) ^ xr));
#pragma unroll
  for (int ti = 0; ti < 6; ti++) {
    int t = w * 6 + ti;                // 0..23
    int m = t >> 3;                    // 0=q 1=k 2=v
    int colq = (t & 7) * 16;
    const float* bias = (m == 0 ? qb_n : (m == 1 ? kb_n : vb_n));
    float4 bv = *(const float4*)(bias + colq + g * 4);
    f32x4_t ac0 = {bv.x, bv.y, bv.z, bv.w};
    f32x4_t ac1 = ac0;
    const ushort* wp = qkvT_n + (size_t)(m * DD + colq + c) * DD + g * 8;
#pragma unroll
    for (int kt = 0; kt < 4; kt++) {
      BF8 b; b.u = *(const ushort8_t*)(wp + kt * 32);
      ac0 = __builtin_amdgcn_mfma_f32_16x16x32_bf16(b.b, aq[0][kt].b, ac0, 0, 0, 0);
      ac1 = __builtin_amdgcn_mfma_f32_16x16x32_bf16(b.b, aq[1][kt].b, ac1, 0, 0, 0);
    }
    ushort* out = (m == 0 ? q : (m == 1 ? kk : v));
    {
      int node = nb + c;
      if (node < NN) {
        ushort4 o; o.x = f2bf(ac0[0]); o.y = f2bf(ac0[1]); o.z = f2bf(ac0[2]); o.w = f2bf(ac0[3]);
        *(ushort4*)(out + (size_t)node * DD + colq + g * 4) = o;
      }
    }
    {
      int node = nb + 16 + c;
      if (node < NN) {
        ushort4 o; o.x = f2bf(ac1[0]); o.y = f2bf(ac1[1]); o.z = f2bf(ac1[2]); o.w = f2bf(ac1[3]);
        *(ushort4*)(out + (size_t)node * DD + colq + g * 4) = o;
      }
    }
  }
}

// ---------- once-per-call setup kernels ----------
// Zero scratch + compute per-graph bounds (absorbs old k_bounds; absent-graph
// stale bounds provably don't change k_head's output since gpool rows are 0).
__global__ __launch_bounds__(256) void k_zero(int* __restrict__ cnt, int* __restrict__ cur,
                                              int* __restrict__ cnt_t, int* __restrict__ cur_t,
                                              const int* __restrict__ batch,
                                              int* __restrict__ gstart, int* __restrict__ gend,
                                              float* __restrict__ gpool) {
  int i = blockIdx.x * 256 + threadIdx.x;
  if (i < NN) {
    cnt[i] = 0; cur[i] = 0; cnt_t[i] = 0; cur_t[i] = 0;
    int b = batch[i];
    if (i == 0 || batch[i - 1] != b) gstart[b] = i;
    if (i == NN - 1 || batch[i + 1] != b) gend[b] = i + 1;
  }
  if (i < NG * DD) gpool[i] = 0.f;
}

// Both histograms in one edge pass (tgt histogram is permutation-invariant).
__global__ void k_hist2(const int* __restrict__ src, const int* __restrict__ tgt,
                        int* __restrict__ cnt, int* __restrict__ cnt_t) {
  int e = blockIdx.x * 256 + threadIdx.x;
  if (e < NE) {
    atomicAdd(cnt + src[e], 1);
    atomicAdd(cnt_t + tgt[e], 1);
  }
}

// Fused scans: blocks [0,NBS) handle cnt->bsum, [NBS,2*NBS) handle cnt_t->bsum_t.
__global__ __launch_bounds__(256) void k_scan_blk2(const int* __restrict__ cnt,
                                                   const int* __restrict__ cnt_t,
                                                   int* __restrict__ bsum, int* __restrict__ bsum_t) {
  __shared__ int red[256];
  int arr = blockIdx.x >= NBS ? 1 : 0;
  int b = blockIdx.x - arr * NBS;
  const int* c = arr ? cnt_t : cnt;
  int* bs = arr ? bsum_t : bsum;
  int tid = threadIdx.x;
  int idx = b * 256 + tid;
  red[tid] = (idx < NN) ? c[idx] : 0;
  __syncthreads();
  for (int off = 128; off >= 1; off >>= 1) {
    if (tid < off) red[tid] += red[tid + off];
    __syncthreads();
  }
  if (tid == 0) bs[b] = red[0];
}

__global__ __launch_bounds__(256) void k_scan_top2(const int* __restrict__ bsum,
                                                   const int* __restrict__ bsum_t,
                                                   int* __restrict__ boff, int* __restrict__ boff_t,
                                                   int* __restrict__ rowstart, int* __restrict__ rowstart_t) {
  __shared__ int ps[256];
  int arr = blockIdx.x;
  const int* bs = arr ? bsum_t : bsum;
  int* bo = arr ? boff_t : boff;
  int* rsN = arr ? rowstart_t : rowstart;
  int t = threadIdx.x;
  int v = (t < NBS) ? bs[t] : 0;
  ps[t] = v;
  __syncthreads();
  for (int off = 1; off < 256; off <<= 1) {
    int x = (t >= off) ? ps[t - off] : 0;
    __syncthreads();
    ps[t] += x;
    __syncthreads();
  }
  bo[t] = ps[t] - v;                 // exclusive prefix of block sums
  if (t == 255) rsN[NN] = ps[255];
}

__global__ __launch_bounds__(256) void k_scan_fin2(const int* __restrict__ cnt,
                                                   const int* __restrict__ cnt_t,
                                                   const int* __restrict__ boff, const int* __restrict__ boff_t,
                                                   int* __restrict__ rowstart, int* __restrict__ rowstart_t) {
  __shared__ int ps[256];
  int arr = blockIdx.x >= NBS ? 1 : 0;
  int b = blockIdx.x - arr * NBS;
  const int* c = arr ? cnt_t : cnt;
  const int* bo = arr ? boff_t : boff;
  int* rs = arr ? rowstart_t : rowstart;
  int t = threadIdx.x;
  int idx = b * 256 + t;
  int v = (idx < NN) ? c[idx] : 0;
  ps[t] = v;
  __syncthreads();
  for (int off = 1; off < 256; off <<= 1) {
    int x = (t >= off) ? ps[t - off] : 0;
    __syncthreads();
    ps[t] += x;
    __syncthreads();
  }
  if (idx < NN) rs[idx] = bo[b] + ps[t] - v;
}

// scatter edges into src-sorted order
__global__ void k_fill(const int* __restrict__ src, const int* __restrict__ tgt,
                       const int* __restrict__ rowstart,
                       int* __restrict__ cur, int* __restrict__ src_s, int* __restrict__ tgt_s) {
  int e = blockIdx.x * 256 + threadIdx.x;
  if (e >= NE) return;
  int s = src[e];
  int p = atomicAdd(cur + s, 1);
  int pos = rowstart[s] + p;
  src_s[pos] = s;
  tgt_s[pos] = tgt[e];
}

// tgt-CSR: list of src-sorted edge ids per tgt node
__global__ void k_fill_t(const int* __restrict__ tgt_s, const int* __restrict__ rowstart_t,
                         int* __restrict__ cur_t, int* __restrict__ eid_t) {
  int i = blockIdx.x * 256 + threadIdx.x;
  if (i >= NE) return;
  int t = tgt_s[i];
  int p = atomicAdd(cur_t + t, 1);
  eid_t[rowstart_t[t] + p] = i;
}

// All six weight transposes (fp32 [K][C] -> bf16 [C][K]) in one launch.
__device__ __forceinline__ void wt_one(const float* __restrict__ W, ushort* __restrict__ WT,
                                       int idx, int K, int C, int dstride) {
  int mi = idx / (K * C), rem = idx - mi * (K * C);
  int cc = rem / K, kk2 = rem - cc * K;
  WT[(size_t)mi * dstride + cc * K + kk2] = f2bf(W[(size_t)mi * K * C + (size_t)kk2 * C + cc]);
}
__global__ __launch_bounds__(256) void k_wt_all(const float* __restrict__ qW, const float* __restrict__ kW,
                                                const float* __restrict__ vW, const float* __restrict__ oW,
                                                const float* __restrict__ f1W, const float* __restrict__ f2W,
                                                ushort* __restrict__ qkvT, ushort* __restrict__ oT,
                                                ushort* __restrict__ f1T, ushort* __restrict__ f2T) {
  int idx = blockIdx.x * 256 + threadIdx.x;
  const int SZ1 = NL * DD * DD;      // 65536
  const int SZF = NL * DD * 512;     // 262144
  if (idx < SZ1) { wt_one(qW, qkvT, idx, DD, DD, 3 * DD * DD); return; }
  idx -= SZ1;
  if (idx < SZ1) { wt_one(kW, qkvT + DD * DD, idx, DD, DD, 3 * DD * DD); return; }
  idx -= SZ1;
  if (idx < SZ1) { wt_one(vW, qkvT + 2 * DD * DD, idx, DD, DD, 3 * DD * DD); return; }
  idx -= SZ1;
  if (idx < SZ1) { wt_one(oW, oT, idx, DD, DD, DD * DD); return; }
  idx -= SZ1;
  if (idx < SZF) { wt_one(f1W, f1T, idx, DD, 512, DD * 512); return; }
  idx -= SZF;
  if (idx < SZF) { wt_one(f2W, f2T, idx, 512, DD, 512 * DD); return; }
}

// M[l][d][hh] = Sum_k cW2[d][k]*bW[l][k][hh]. One block per (l,d).
__global__ __launch_bounds__(64) void k_mbias_par(const float* __restrict__ cW2, const float* __restrict__ cb2,
                                                  const float* __restrict__ bW, const float* __restrict__ bb,
                                                  float* __restrict__ M, float* __restrict__ base) {
  int bid = blockIdx.x;
  int l = bid >> 7, d = bid & 127;
  int lane = threadIdx.x;
  int hh = lane >> 3, j0 = lane & 7;
  const float* bWl = bW + (size_t)l * DD * HH;
  float acc = 0.f;
#pragma unroll
  for (int t = 0; t < 16; t++) {
    int k = j0 + t * 8;
    acc = fmaf(cW2[d * DD + k], bWl[k * HH + hh], acc);
  }
#pragma unroll
  for (int off = 1; off <= 4; off <<= 1) acc += __shfl_xor(acc, off, 64);
  if (j0 == 0) M[(size_t)l * DD * HH + d * HH + hh] = acc;
  if (d == 0) {
    float bacc = 0.f;
#pragma unroll
    for (int t = 0; t < 16; t++) {
      int k = j0 + t * 8;
      bacc = fmaf(cb2[k], bWl[k * HH + hh], bacc);
    }
#pragma unroll
    for (int off = 1; off <= 4; off <<= 1) bacc += __shfl_xor(bacc, off, 64);
    if (j0 == 0) base[l * HH + hh] = bacc + bb[l * HH + hh];
  }
}

// sorted breakpoints + ranks — cW1/cb1 are layer-INDEPENDENT, computed once.
__global__ __launch_bounds__(128) void k_bp(const float* __restrict__ cW1, const float* __restrict__ cb1,
                                            float* __restrict__ bpg, int* __restrict__ posg) {
  __shared__ float x[DD], bp[DD];
  int tid = threadIdx.x;
  float c1v = cW1[tid], cbv = cb1[tid];
  x[tid] = (c1v == 0.f) ? __builtin_inff() : (-cbv / c1v);
  __syncthreads();
  float xv = x[tid]; int p = 0;
  for (int j = 0; j < DD; j++) {
    float xj = x[j];
    if (xj < xv || (xj == xv && j < tid)) p++;
  }
  bp[p] = xv;
  posg[tid] = p;
  __syncthreads();
  bpg[tid] = bp[tid];
}

// PWL table, wave-parallel: one block per (l, segment).
__global__ __launch_bounds__(64) void k_pwl_tab(const float* __restrict__ cW1, const float* __restrict__ cb1,
    const int* __restrict__ posg, const float* __restrict__ Mb, const float* __restrict__ basel,
    float* __restrict__ slopeg, float* __restrict__ interg) {
  int bid = blockIdx.x;
  int l = bid / NSEG, s = bid - l * NSEG;
  int lane = threadIdx.x;
  int hh = lane >> 3, j0 = lane & 7;
  const float* M = Mb + (size_t)l * DD * HH;
  float sl = 0.f, in = 0.f;
#pragma unroll
  for (int t = 0; t < 16; t++) {
    int d = j0 + t * 8;
    float cv = cW1[d], cbv = cb1[d];
    int p = posg[d];
    bool act = (cv == 0.f) ? (cbv > 0.f) : ((cv > 0.f) ? (p < s) : (p >= s));
    float m = act ? M[d * HH + hh] : 0.f;
    sl = fmaf(cv, m, sl);
    in = fmaf(cbv, m, in);
  }
#pragma unroll
  for (int off = 1; off <= 4; off <<= 1) {
    sl += __shfl_xor(sl, off, 64);
    in += __shfl_xor(in, off, 64);
  }
  if (j0 == 0) {
    size_t o = (size_t)l * NSEG * HH + s * HH + hh;
    slopeg[o] = sl;
    interg[o] = in + basel[l * HH + hh];
  }
}

// parallel pool: 256 nodes/block, running sums flushed at graph boundaries
__global__ __launch_bounds__(256) void k_pool_part(const float* __restrict__ h,
    const int* __restrict__ batch, float* __restrict__ gpool) {
  int tid = threadIdx.x;
  int d = tid & 127, sub = tid >> 7;
  int n0 = blockIdx.x * 256;
  int nend = n0 + 256; if (nend > NN) nend = NN;
  float run = 0.f; int gcur = -1;
  for (int n = n0 + sub; n < nend; n += 2) {
    int g = batch[n];
    if (g != gcur) {
      if (gcur >= 0) atomicAdd(gpool + (size_t)gcur * DD + d, run);
      run = 0.f; gcur = g;
    }
    run += h[(size_t)n * DD + d];
  }
  if (gcur >= 0) atomicAdd(gpool + (size_t)gcur * DD + d, run);
}

__global__ __launch_bounds__(256) void k_head(const float* __restrict__ gpool,
    const int* __restrict__ gstart, const int* __restrict__ gend,
    const float* __restrict__ W1, const float* __restrict__ b1,
    const float* __restrict__ W2, const float* __restrict__ b2, float* __restrict__ out) {
  __shared__ float mid[NG * 64];
  int tid = threadIdx.x;
  for (int idx = tid; idx < NG * 64; idx += 256) {
    int g = idx >> 6, j = idx & 63;
    int cnt = gend[g] - gstart[g]; if (cnt < 1) cnt = 1;
    float rc = 1.0f / (float)cnt;
    float acc = 0.f;
    for (int d = 0; d < DD; d++) acc = fmaf(gpool[g * DD + d], W1[d * 64 + j], acc);
    mid[idx] = fmaxf(fmaf(acc, rc, b1[j]), 0.f);
  }
  __syncthreads();
  if (tid < NG) {
    float acc = b2[0];
    for (int j = 0; j < 64; j++) acc = fmaf(mid[tid * 64 + j], W2[j], acc);
    out[tid] = acc;
  }
}

// ---------- launch ----------
extern "C" void kernel_launch(void* const* d_in, const int* in_sizes, int n_in,
                              void* d_out, int out_size, void* d_ws, size_t ws_size,
                              hipStream_t stream) {
  const float* x      = (const float*)d_in[0];
  const int*   ei     = (const int*)d_in[1];
  const int*   batch  = (const int*)d_in[2];
  const float* node_W = (const float*)d_in[3];
  const float* node_b = (const float*)d_in[4];
  const float* cW1    = (const float*)d_in[5];
  const float* cb1    = (const float*)d_in[6];
  const float* cW2    = (const float*)d_in[7];
  const float* cb2    = (const float*)d_in[8];
  const float* qW     = (const float*)d_in[9];
  const float* qb     = (const float*)d_in[10];
  const float* kW     = (const float*)d_in[11];
  const float* kb     = (const float*)d_in[12];
  const float* vW     = (const float*)d_in[13];
  const float* vb     = (const float*)d_in[14];
  const float* oW     = (const float*)d_in[15];
  const float* ob     = (const float*)d_in[16];
  const float* bW     = (const float*)d_in[17];
  const float* bb     = (const float*)d_in[18];
  const float* f1W    = (const float*)d_in[19];
  const float* f1b    = (const float*)d_in[20];
  const float* f2W    = (const float*)d_in[21];
  const float* f2b    = (const float*)d_in[22];
  const float* n1s    = (const float*)d_in[23];
  const float* n1b    = (const float*)d_in[24];
  const float* n2s    = (const float*)d_in[25];
  const float* n2b    = (const float*)d_in[26];
  const float* outW1  = (const float*)d_in[27];
  const float* outb1  = (const float*)d_in[28];
  const float* outW2  = (const float*)d_in[29];
  const float* outb2  = (const float*)d_in[30];

  const int* src = ei;
  const int* tgt = ei + NE;

  char* wp = (char*)d_ws;
  auto alloc = [&](size_t bytes) { void* p = (void*)wp; wp += (bytes + 255) & ~(size_t)255; return p; };
  float*    h       = (float*)alloc((size_t)NN * DD * 4);
  ushort*   q       = (ushort*)alloc((size_t)NN * DD * 2);
  ushort*   kk      = (ushort*)alloc((size_t)NN * DD * 2);
  ushort*   v       = (ushort*)alloc((size_t)NN * DD * 2);
  ushort*   aggmb   = (ushort*)alloc((size_t)NN * DD * 2);
  float*    sim     = (float*)alloc((size_t)NE * 4);
  float*    dist    = (float*)alloc((size_t)NE * 4);
  float*    escore  = (float*)alloc((size_t)NE * HH * 4);
  float*    Mb      = (float*)alloc((size_t)NL * DD * HH * 4);
  float*    basel   = (float*)alloc((size_t)NL * HH * 4);
  float*    bpg     = (float*)alloc((size_t)DD * 4);
  int*      posg    = (int*)alloc((size_t)DD * 4);
  float*    slopeg  = (float*)alloc((size_t)NL * NSEG * HH * 4);
  float*    interg  = (float*)alloc((size_t)NL * NSEG * HH * 4);
  int*      rowstart= (int*)alloc((size_t)(NN + 1) * 4);
  int*      rowstart_t = (int*)alloc((size_t)(NN + 1) * 4);
  int*      eid_t   = (int*)alloc((size_t)NE * 4);
  int*      src_s   = (int*)alloc((size_t)NE * 4);
  int*      tgt_s   = (int*)alloc((size_t)NE * 4);
  int*      cnt     = (int*)alloc((size_t)NN * 4);
  int*      cur     = (int*)alloc((size_t)NN * 4);
  int*      cnt_t   = (int*)alloc((size_t)NN * 4);
  int*      cur_t   = (int*)alloc((size_t)NN * 4);
  int*      bsum    = (int*)alloc((size_t)NBS * 4);
  int*      bsum_t  = (int*)alloc((size_t)NBS * 4);
  int*      boff    = (int*)alloc((size_t)256 * 4);
  int*      boff_t  = (int*)alloc((size_t)256 * 4);
  int*      gstart  = (int*)alloc((size_t)NG * 4);
  int*      gend    = (int*)alloc((size_t)NG * 4);
  float*    gpool   = (float*)alloc((size_t)NG * DD * 4);
  ushort*   qkvT    = (ushort*)alloc((size_t)NL * 3 * DD * DD * 2);
  ushort*   oT      = (ushort*)alloc((size_t)NL * DD * DD * 2);
  ushort*   f1T     = (ushort*)alloc((size_t)NL * DD * 512 * 2);
  ushort*   f2T     = (ushort*)alloc((size_t)NL * 512 * DD * 2);
  (void)in_sizes; (void)n_in; (void)out_size; (void)ws_size;

  // once-per-call setup (13 dispatches)
  k_zero<<<NBS, 256, 0, stream>>>(cnt, cur, cnt_t, cur_t, batch, gstart, gend, gpool);
  k_hist2<<<(NE + 255) / 256, 256, 0, stream>>>(src, tgt, cnt, cnt_t);
  k_scan_blk2<<<2 * NBS, 256, 0, stream>>>(cnt, cnt_t, bsum, bsum_t);
  k_scan_top2<<<2, 256, 0, stream>>>(bsum, bsum_t, boff, boff_t, rowstart, rowstart_t);
  k_scan_fin2<<<2 * NBS, 256, 0, stream>>>(cnt, cnt_t, boff, boff_t, rowstart, rowstart_t);
  k_fill<<<(NE + 255) / 256, 256, 0, stream>>>(src, tgt, rowstart, cur, src_s, tgt_s);
  k_fill_t<<<(NE + 255) / 256, 256, 0, stream>>>(tgt_s, rowstart_t, cur_t, eid_t);
  k_mbias_par<<<NL * DD, 64, 0, stream>>>(cW2, cb2, bW, bb, Mb, basel);
  k_bp<<<1, 128, 0, stream>>>(cW1, cb1, bpg, posg);
  k_pwl_tab<<<NL * NSEG, 64, 0, stream>>>(cW1, cb1, posg, Mb, basel, slopeg, interg);
  k_wt_all<<<(4 * NL * DD * DD + 2 * NL * DD * 512 + 255) / 256, 256, 0, stream>>>(
      qW, kW, vW, oW, f1W, f2W, qkvT, oT, f1T, f2T);
  k_node_proj<<<NT32, 256, 0, stream>>>(x, node_W, node_b, h);
  // layer-0 qkv from standalone LN1+QKV
  k_ln_qkv<<<NT32, 512, 0, stream>>>(h, n1s, n1b, qkvT, qb, kb, vb, q, kk, v);

  for (int l = 0; l < NL; l++) {
    k_edge1<<<(NE * 8 + 255) / 256, 256, 0, stream>>>(src_s, tgt_s, h, sim, dist);
    k_scores_sm<<<NT4, 256, 0, stream>>>(src_s, rowstart_t, eid_t, q, kk,
        sim, dist, bpg,
        slopeg + (size_t)l * NSEG * HH, interg + (size_t)l * NSEG * HH,
        escore);
    k_agg<<<NN / 4, 256, 0, stream>>>(tgt_s, rowstart, escore, v, aggmb);
    int ln = l < NL - 1 ? l + 1 : l;   // next-layer params (unused when do_qkv=0)
    k_attn_ffn<<<NT32, 256, 0, stream>>>(aggmb, oT + (size_t)l * DD * DD, ob + l * DD,
        n2s + l * DD, n2b + l * DD,
        f1T + (size_t)l * DD * 512, f1b + (size_t)l * 4 * DD,
        f2T + (size_t)l * 512 * DD, f2b + l * DD, h,
        (l < NL - 1) ? 1 : 0,
        n1s + ln * DD, n1b + ln * DD,
        qkvT + (size_t)ln * 3 * DD * DD,
        qb + ln * DD, kb + ln * DD, vb + ln * DD,
        q, kk, v);
  }
  k_pool_part<<<(NN + 255) / 256, 256, 0, stream>>>(h, batch, gpool);
  k_head<<<1, 256, 0, stream>>>(gpool, gstart, gend, outW1, outb1, outW2, outb2, (float*)d_out);
}